// Round 8
// baseline (347.560 us; speedup 1.0000x reference)
//
#include <hip/hip_runtime.h>
#include <cstdint>
#include <cstddef>

#define MEAN_C 0.1307f
#define SIGMA_C 0.3081f
#define SIG_SCALE_C 5.0f

typedef __bf16 bf16_t;
typedef __bf16 bf16x8 __attribute__((ext_vector_type(8)));
typedef __bf16 bf16x4 __attribute__((ext_vector_type(4)));
typedef float f32x4 __attribute__((ext_vector_type(4)));

__device__ __forceinline__ f32x4 mfma16(bf16x8 a, bf16x8 b, f32x4 c) {
    return __builtin_amdgcn_mfma_f32_16x16x32_bf16(a, b, c, 0, 0, 0);
}

typedef const __attribute__((address_space(1))) void* gvp;
typedef __attribute__((address_space(3))) void* lvp;
__device__ __forceinline__ void g2l16(const void* g, void* l) {
    __builtin_amdgcn_global_load_lds((gvp)g, (lvp)l, 16, 0, 0);
}

// swizzled bf16 operand layout: 16x32 tiles (1KB); chunk index within tile =
// lane = (k-chunk)*16 + row  (16B each). offset(r,k), K = ktiles*32.
__device__ __forceinline__ size_t swz(int r, int k, int ktiles) {
    return (((size_t)(r >> 4) * ktiles + (k >> 5)) << 9)
         + (((k >> 3) & 3) << 7) + ((r & 15) << 3) + (k & 7);
}

#define KTILES 64   // K = 2048

// ---------------- device helpers ----------------

__device__ __forceinline__ float sigmoidf_(float x) {
    if (x >= 0.f) { float e = __expf(-x); return 1.f / (1.f + e); }
    float e = __expf(x); return e / (1.f + e);
}

__device__ __forceinline__ float spu_f(float x) {
    return (x >= 0.f) ? (x * x - 0.5f) : (sigmoidf_(-x) - 1.f);
}

__device__ __forceinline__ float wave_sum(float a) {
    #pragma unroll
    for (int o = 32; o > 0; o >>= 1) a += __shfl_xor(a, o, 64);
    return a;
}

// full analyze_spu for one neuron i, given clamp bounds (iUi, iLi) and the
// back-substituted chain values vU (upper row) / vL (lower row).
__device__ __forceinline__ void spu_body(int i, int n,
        float iUi, float iLi, float vU, float vL,
        float* __restrict__ us, float* __restrict__ ui,
        float* __restrict__ ls, float* __restrict__ li,
        float* __restrict__ pU, float* __restrict__ pL) {
    float ux = fminf(iUi, vU);
    float lx = fmaxf(iLi, vL);
    float uy = spu_f(ux), ly = spu_f(lx);
    float new_ub = fmaxf(uy, ly);
    float sj = (uy - ly) / (ux - lx);
    float ij = uy - sj * ux;
    bool right = lx > 0.f;
    bool left = ux <= 0.f;
    float mid = 0.5f * (ux + lx);
    float sp = 2.f * mid, ip = -mid * mid - 0.5f;
    float sm = sigmoidf_(mid);
    float ssm = -sm * (1.f - sm);
    float ism = -sm - ssm * mid;
    bool crossing = (!left) && (!right);
    float new_lb = crossing ? -0.5f : fminf(uy, ly);
    float spu_s = 2.f * ux, ipu = -ux * ux - 0.5f;
    float limit = spu_s * lx + ipu;
    float clm = (fabsf(lx) > ux) ? 1.f : 0.f;
    float clp = sigmoidf_((clm - 0.5f) * 2.f * SIG_SCALE_C) * (ly - limit) + limit;
    bool ptm = clp < -0.5f;
    float D = 4.f * lx * lx - 4.f * clp - 2.f;
    float x2 = (2.f * lx + sqrtf(fmaxf(D, 0.f))) * 0.5f;
    float spt = 2.f * x2, ipt = -x2 * x2 - 0.5f;
    float sjn = (clp + 0.5f) / lx;
    float ijn = -0.5f;
    float s_cl = ptm ? spt : sjn;
    float i_cl = ptm ? ipt : ijn;
    float sl = sigmoidf_(lx);
    float ssl = -sl * (1.f - sl);
    float isl = -sl - ssl * lx;
    float stv = ssl * ux + isl - uy;
    float Lb = lx, Rb = 0.f;
    #pragma unroll
    for (int t = 0; t < 10; ++t) {
        float mm = 0.5f * (Lb + Rb);
        float smm = sigmoidf_(mm);
        float sms = -smm * (1.f - smm);
        float smi = -smm - sms * mm;
        bool mask = (sms * ux + smi - uy) > 0.f;
        Lb = mask ? mm : Lb;
        Rb = mask ? Rb : mm;
    }
    float scp = sigmoidf_(-SIG_SCALE_C) * (Lb - lx) + lx;
    float sc = sigmoidf_(scp);
    float ssc = -sc * (1.f - sc);
    float isc = -sc - ssc * scp;
    bool up = stv > 0.f;
    float s_cu = up ? ssc : sj;
    float i_cu = up ? isc : ij;
    float usv, uiv, lsv, liv;
    if (right)      { usv = sj;   uiv = ij;   lsv = sp;   liv = ip;   }
    else if (left)  { usv = ssm;  uiv = ism;  lsv = sj;   liv = ij;   }
    else            { usv = s_cu; uiv = i_cu; lsv = s_cl; liv = i_cl; }
    us[i] = usv; ui[i] = uiv; ls[i] = lsv; li[i] = liv;
    float vu = (usv >= 0.f) ? vU : vL;
    float vl = (lsv >= 0.f) ? vL : vU;
    pU[i] = fminf(new_ub, usv * vu + uiv);
    pL[i] = fmaxf(new_lb, lsv * vl + liv);
}

// ---------------- bf16 producers ----------------

// merged: transpose/convert/swizzle of W1,W2,W3 + input-bounds side block +
// FULL LAYER 1 (z=3 slice: interval bound + spu, bounds computed inline from
// x/eps so there is no dependency on the bounds side-block). Also zeroes the
// red-fusion counters each frame.
__global__ __launch_bounds__(256) void k_wT3(
        const float* __restrict__ W1, const float* __restrict__ W2,
        const float* __restrict__ W3,
        bf16_t* __restrict__ W1t, bf16_t* __restrict__ W2t, bf16_t* __restrict__ W3t,
        const float* __restrict__ x, const float* __restrict__ eps,
        float* __restrict__ ubn, float* __restrict__ lbn,
        const float* __restrict__ b1,
        float* __restrict__ us1, float* __restrict__ ui1,
        float* __restrict__ ls1, float* __restrict__ li1,
        float* __restrict__ pU1, float* __restrict__ pL1,
        int* __restrict__ cnt2, int* __restrict__ cnt3) {
    __shared__ bf16_t t[64 * 65];
    int z = blockIdx.z;
    int tid = threadIdx.x;
    const float* W; int N, ldw; bf16_t* Wt;
    if (z == 0)      { W = W2; N = 2048; ldw = 2048; Wt = W2t; }
    else if (z == 1) { W = W3; N = 2048; ldw = 2048; Wt = W3t; }
    else if (z == 3) {
        // ---- layer 1: wave-per-row interval bound + spu (inline bounds) ----
        int bid = (int)(blockIdx.y * 32 + blockIdx.x);
        if (bid >= 512) return;
        int w = tid >> 6, lane = tid & 63;
        int r = bid * 4 + w;                     // 0..2047
        const f32x4* Wr = (const f32x4*)(W1 + (size_t)r * 784);
        const f32x4* X4 = (const f32x4*)x;
        float e = eps[0];
        float au = 0.f, al = 0.f;
        for (int j = lane; j < 196; j += 64) {   // 784/4 == 196
            f32x4 wv = Wr[j], xv = X4[j];
            #pragma unroll
            for (int u = 0; u < 4; ++u) {
                float xb = xv[u];
                float ub = (fminf(xb + e, 1.f) - MEAN_C) / SIGMA_C;
                float lb = (fmaxf(xb - e, 0.f) - MEAN_C) / SIGMA_C;
                float wgt = wv[u];
                float hi = (wgt > 0.f) ? ub : lb;
                float lo2 = (wgt > 0.f) ? lb : ub;
                au = fmaf(wgt, hi, au);
                al = fmaf(wgt, lo2, al);
            }
        }
        au = wave_sum(au); al = wave_sum(al);
        if (lane == 0) {
            float vU = au + b1[r], vL = al + b1[r];
            spu_body(r, 2048, vU, vL, vU, vL, us1, ui1, ls1, li1, pU1, pL1);
        }
        return;
    }
    else {
        W = W1; N = 784; ldw = 784; Wt = W1t;
        if (blockIdx.y >= 14) {
            if (blockIdx.y == 14 && blockIdx.x == 0) {
                if (tid == 0) { cnt2[0] = 0; cnt3[0] = 0; }
                for (int i = tid; i < 896; i += 256) {
                    if (i >= 784) { ubn[i] = 0.f; lbn[i] = 0.f; }
                    else {
                        float e = eps[0];
                        float ub = fminf(x[i] + e, 1.f);
                        float lb = fmaxf(x[i] - e, 0.f);
                        ubn[i] = (ub - MEAN_C) / SIGMA_C;
                        lbn[i] = (lb - MEAN_C) / SIGMA_C;
                    }
                }
            }
            return;
        }
    }
    int k0 = blockIdx.x * 64, n0 = blockIdx.y * 64;
    int rg = tid >> 4;            // 0..15 row sub-index
    int cg = (tid & 15) * 4;      // column start (f32x4)
    bool fast = (n0 + 64 <= N);
    #pragma unroll
    for (int it = 0; it < 4; ++it) {
        int row = it * 16 + rg;   // local k
        const float* Wr = W + (size_t)(k0 + row) * ldw + n0 + cg;
        float v0, v1, v2, v3;
        if (fast) {
            f32x4 vv = *(const f32x4*)Wr;
            v0 = vv[0]; v1 = vv[1]; v2 = vv[2]; v3 = vv[3];
        } else {
            v0 = (n0 + cg + 0 < N) ? Wr[0] : 0.f;
            v1 = (n0 + cg + 1 < N) ? Wr[1] : 0.f;
            v2 = (n0 + cg + 2 < N) ? Wr[2] : 0.f;
            v3 = (n0 + cg + 3 < N) ? Wr[3] : 0.f;
        }
        t[(cg + 0) * 65 + row] = (bf16_t)v0;
        t[(cg + 1) * 65 + row] = (bf16_t)v1;
        t[(cg + 2) * 65 + row] = (bf16_t)v2;
        t[(cg + 3) * 65 + row] = (bf16_t)v3;
    }
    __syncthreads();
    #pragma unroll
    for (int p = 0; p < 2; ++p) {
        int c = tid + p * 256;
        int lr = c & 63, lq = c >> 6;
        bf16x8 v;
        #pragma unroll
        for (int u = 0; u < 8; ++u) v[u] = t[lr * 65 + lq * 8 + u];
        *(bf16x8*)(Wt + swz(n0 + lr, k0 + lq * 8, KTILES)) = v;
    }
}

// prep (fused interval-affine)
__global__ __launch_bounds__(256) void k_prep16(
        const float* __restrict__ W, const float* __restrict__ b, int n,
        const float* __restrict__ cus, const float* __restrict__ cui,
        const float* __restrict__ cls, const float* __restrict__ cli,
        const float* __restrict__ bvec,
        const float* __restrict__ U, const float* __restrict__ L,
        bf16_t* __restrict__ Ab, float* __restrict__ av,
        float* __restrict__ iU, float* __restrict__ iL) {
    int rt = blockIdx.x;
    int tid = threadIdx.x, lane = tid & 63, wid = tid >> 6;
    int mrow = lane & 15, q = lane >> 4;
    int r = rt * 16 + mrow;
    bool act = r < 2 * n;
    bool isU = r < n;
    int i = act ? (isU ? r : r - n) : 0;
    float gate = act ? 1.f : 0.f;
    const float* Wr = W + (size_t)i * 2048;
    const float* ps = isU ? cus : cls;
    const float* ns = isU ? cls : cus;
    const float* yi = isU ? cui : cli;
    const float* zi = isU ? cli : cui;
    const float* hi = isU ? U : L;
    const float* lo = isU ? L : U;
    float a = 0.f, a2 = 0.f;
    bf16_t* Abase = Ab + ((size_t)rt * KTILES) * 512 + lane * 8;
    for (int kt = wid; kt < KTILES; kt += 4) {
        int k0 = kt * 32 + q * 8;
        bf16x8 ov;
        #pragma unroll
        for (int h = 0; h < 2; ++h) {
            int kb = k0 + 4 * h;
            f32x4 wv = *(const f32x4*)(Wr + kb);
            f32x4 p0 = *(const f32x4*)(ps + kb);
            f32x4 q0 = *(const f32x4*)(ns + kb);
            f32x4 y0 = *(const f32x4*)(yi + kb);
            f32x4 z0 = *(const f32x4*)(zi + kb);
            f32x4 c0 = *(const f32x4*)(bvec + kb);
            f32x4 h0 = *(const f32x4*)(hi + kb);
            f32x4 l0 = *(const f32x4*)(lo + kb);
            #pragma unroll
            for (int u = 0; u < 4; ++u) {
                float w = gate * wv[u];
                float pos = fmaxf(w, 0.f), neg = fminf(w, 0.f);
                float mx = pos * p0[u] + neg * q0[u];
                ov[4 * h + u] = (bf16_t)mx;
                a += pos * y0[u] + neg * z0[u] + mx * c0[u];
                a2 += pos * h0[u] + neg * l0[u];   // interval dot
            }
        }
        *(bf16x8*)(Abase + (size_t)kt * 512) = ov;
    }
    a += __shfl_xor(a, 16, 64);  a += __shfl_xor(a, 32, 64);
    a2 += __shfl_xor(a2, 16, 64); a2 += __shfl_xor(a2, 32, 64);
    __shared__ float sh[2][4][16];
    if (lane < 16) { sh[0][wid][lane] = a; sh[1][wid][lane] = a2; }
    __syncthreads();
    if (tid < 16) {
        int r2 = rt * 16 + tid;
        float ta = sh[0][0][tid] + sh[0][1][tid] + sh[0][2][tid] + sh[0][3][tid];
        float tb = sh[1][0][tid] + sh[1][1][tid] + sh[1][2][tid] + sh[1][3][tid];
        if (r2 < 2 * n) {
            bool isU2 = r2 < n;
            int i2 = isU2 ? r2 : r2 - n;
            av[r2] = ta + b[i2];
            if (isU2) iU[i2] = tb + b[i2];
            else      iL[i2] = tb + b[i2];
        } else {
            av[r2] = 0.f;
        }
    }
}

// colmix (layer-4 small-M chains): bf16 split slabs -> swizzled bf16 Ab
__global__ __launch_bounds__(256) void k_colmix16(
        const bf16_t* __restrict__ Cb, int ldc, int splits, size_t sstride, int n,
        int tpb,
        const float* __restrict__ cus, const float* __restrict__ cui,
        const float* __restrict__ cls, const float* __restrict__ cli,
        const float* __restrict__ bvec,
        bf16_t* __restrict__ Ab, float* __restrict__ av) {
    int rt = blockIdx.x;
    int kt0 = blockIdx.y * tpb;
    int tid = threadIdx.x, lane = tid & 63, wid = tid >> 6;
    int mrow = lane & 15, q = lane >> 4;
    int r = rt * 16 + mrow;
    bool isU = r < n;
    const bf16_t* Cr = Cb + (size_t)r * ldc;
    const float* ps = isU ? cus : cls;
    const float* ns = isU ? cls : cus;
    const float* yi = isU ? cui : cli;
    const float* zi = isU ? cli : cui;
    float a = 0.f;
    bf16_t* Abase = Ab + ((size_t)rt * KTILES) * 512 + lane * 8;
    for (int kt = kt0 + wid; kt < kt0 + tpb; kt += 4) {
        int k0 = kt * 32 + q * 8;
        float wsum[8] = {0.f, 0.f, 0.f, 0.f, 0.f, 0.f, 0.f, 0.f};
        for (int s = 0; s < splits; ++s) {
            bf16x8 v = *(const bf16x8*)(Cr + s * sstride + k0);
            #pragma unroll
            for (int u = 0; u < 8; ++u) wsum[u] += (float)v[u];
        }
        f32x4 p0 = *(const f32x4*)(ps + k0), p1 = *(const f32x4*)(ps + k0 + 4);
        f32x4 q0 = *(const f32x4*)(ns + k0), q1 = *(const f32x4*)(ns + k0 + 4);
        f32x4 y0 = *(const f32x4*)(yi + k0), y1 = *(const f32x4*)(yi + k0 + 4);
        f32x4 z0 = *(const f32x4*)(zi + k0), z1 = *(const f32x4*)(zi + k0 + 4);
        f32x4 c0 = *(const f32x4*)(bvec + k0), c1 = *(const f32x4*)(bvec + k0 + 4);
        bf16x8 ov;
        #pragma unroll
        for (int u = 0; u < 4; ++u) {
            float w = wsum[u];
            float pos = fmaxf(w, 0.f), neg = fminf(w, 0.f);
            float mx = pos * p0[u] + neg * q0[u];
            ov[u] = (bf16_t)mx;
            a += pos * y0[u] + neg * z0[u] + mx * c0[u];
        }
        #pragma unroll
        for (int u = 0; u < 4; ++u) {
            float w = wsum[4 + u];
            float pos = fmaxf(w, 0.f), neg = fminf(w, 0.f);
            float mx = pos * p1[u] + neg * q1[u];
            ov[4 + u] = (bf16_t)mx;
            a += pos * y1[u] + neg * z1[u] + mx * c1[u];
        }
        *(bf16x8*)(Abase + (size_t)kt * 512) = ov;
    }
    a += __shfl_xor(a, 16, 64);
    a += __shfl_xor(a, 32, 64);
    __shared__ float sh[4][16];
    if (lane < 16) sh[wid][lane] = a;
    __syncthreads();
    if (tid < 16) {
        float tot = sh[0][tid] + sh[1][tid] + sh[2][tid] + sh[3][tid];
        atomicAdd(&av[rt * 16 + tid], tot);
    }
}

// final c0 step + min, fused, single block of 10 waves (one wave per L row).
__global__ __launch_bounds__(640) void k_reduce16f(
        const bf16_t* __restrict__ Cb, int ldc, int m, int n,
        int splits, size_t sstride,
        const float* __restrict__ av,
        const float* __restrict__ ubn, const float* __restrict__ lbn,
        const float* __restrict__ iL,
        float* __restrict__ out) {
    __shared__ float sbl[16];
    int tid = threadIdx.x, lane = tid & 63, wv = tid >> 6;   // 10 waves
    int nch = m >> 3;   // m % 8 == 0
    int i = wv;          // 0..9 == DOUT rows
    int r = n + i;       // L rows only
    const bf16_t* Cr = Cb + (size_t)r * ldc;
    const float* p = lbn;
    const float* q = ubn;
    float a = 0.f;
    for (int c = lane; c < nch; c += 64) {
        float wsum[8] = {0.f, 0.f, 0.f, 0.f, 0.f, 0.f, 0.f, 0.f};
        for (int s = 0; s < splits; ++s) {
            bf16x8 v = *(const bf16x8*)(Cr + s * sstride + c * 8);
            #pragma unroll
            for (int u = 0; u < 8; ++u) wsum[u] += (float)v[u];
        }
        f32x4 p0 = *(const f32x4*)(p + c * 8), p1 = *(const f32x4*)(p + c * 8 + 4);
        f32x4 q0 = *(const f32x4*)(q + c * 8), q1 = *(const f32x4*)(q + c * 8 + 4);
        #pragma unroll
        for (int u = 0; u < 4; ++u) {
            a += fmaxf(wsum[u], 0.f) * p0[u] + fminf(wsum[u], 0.f) * q0[u];
            a += fmaxf(wsum[4 + u], 0.f) * p1[u] + fminf(wsum[4 + u], 0.f) * q1[u];
        }
    }
    a = wave_sum(a);
    if (lane == 0) sbl[i] = fmaxf(iL[i], a + av[r]);
    __syncthreads();
    if (tid < 64) {
        float v = 3.4e38f;
        for (int j = lane; j < n; j += 64) v = fminf(v, sbl[j]);
        #pragma unroll
        for (int o = 32; o > 0; o >>= 1) v = fminf(v, __shfl_down(v, o, 64));
        if (lane == 0) out[0] = v;
    }
}

// ---- 256-thr BK=64 mid-barrier distance-2 pipe (L4 split-K GEMM) ----
#define GEMM_PIPE()                                                            \
    int tid = threadIdx.x, lane = tid & 63, w = tid >> 6;                      \
    int wm = w & 1, wn = w >> 1;                                               \
    f32x4 acc[4][4];                                                           \
    _Pragma("unroll")                                                          \
    for (int i = 0; i < 4; ++i)                                                \
        _Pragma("unroll")                                                      \
        for (int j = 0; j < 4; ++j) acc[i][j] = (f32x4){0.f, 0.f, 0.f, 0.f};   \
    auto stage = [&](int kk) {                                                 \
        int b = kk & 1;                                                        \
        size_t go = (size_t)kk * 1024;                                         \
        bf16_t* la = &As2[b * 8192 + w * 1024];                                \
        bf16_t* lb = &Bs2[b * 8192 + w * 1024];                                \
        g2l16(a0 + go, la);          g2l16(a0 + go + 512, la + 512);           \
        g2l16(a1 + go, la + 4096);   g2l16(a1 + go + 512, la + 4608);          \
        g2l16(b0 + go, lb);          g2l16(b0 + go + 512, lb + 512);           \
        g2l16(b1 + go, lb + 4096);   g2l16(b1 + go + 512, lb + 4608);          \
    };                                                                         \
    stage(0); stage(1);                                                        \
    asm volatile("s_waitcnt vmcnt(8)" ::: "memory");                           \
    __builtin_amdgcn_s_barrier();                                              \
    for (int kk = 0; kk < nk; ++kk) {                                          \
        const bf16_t* cA = &As2[(kk & 1) * 8192];                              \
        const bf16_t* cB = &Bs2[(kk & 1) * 8192];                              \
        bf16x8 af0[4], af1[4], bq0[4], bq1[4];                                 \
        _Pragma("unroll")                                                      \
        for (int i = 0; i < 4; ++i) {                                          \
            af0[i] = *(const bf16x8*)(cA + (wm * 4 + i) * 1024 + lane * 8);    \
            af1[i] = *(const bf16x8*)(cA + (wm * 4 + i) * 1024 + 512 + lane * 8); \
            bq0[i] = *(const bf16x8*)(cB + (wn * 4 + i) * 1024 + lane * 8);    \
            bq1[i] = *(const bf16x8*)(cB + (wn * 4 + i) * 1024 + 512 + lane * 8); \
        }                                                                      \
        asm volatile("s_waitcnt lgkmcnt(0)" ::: "memory");                     \
        __builtin_amdgcn_s_barrier();                                          \
        if (kk + 2 < nk) stage(kk + 2);                                        \
        _Pragma("unroll")                                                      \
        for (int i = 0; i < 4; ++i)                                            \
            _Pragma("unroll")                                                  \
            for (int j = 0; j < 4; ++j)                                        \
                acc[i][j] = mfma16(bq0[j], af0[i], acc[i][j]);                 \
        _Pragma("unroll")                                                      \
        for (int i = 0; i < 4; ++i)                                            \
            _Pragma("unroll")                                                  \
            for (int j = 0; j < 4; ++j)                                        \
                acc[i][j] = mfma16(bq1[j], af1[i], acc[i][j]);                 \
        if (kk + 2 < nk) asm volatile("s_waitcnt vmcnt(8)" ::: "memory");      \
        else             asm volatile("s_waitcnt vmcnt(0)" ::: "memory");      \
        __builtin_amdgcn_s_barrier();                                          \
    }

// split-K slab-output GEMM (layer 4)
__global__ __launch_bounds__(256) void k_gemm16(
        const bf16_t* __restrict__ A, const bf16_t* __restrict__ Bt,
        bf16_t* __restrict__ C, int ldc, size_t sstride, int nk) {
    __shared__ __align__(16) bf16_t As2[16384];
    __shared__ __align__(16) bf16_t Bs2[16384];
    int tr0 = blockIdx.y * 8, tc0 = blockIdx.x * 8;
    int kt0 = blockIdx.z * nk * 2;
    int wtmp = threadIdx.x >> 6, ltmp = threadIdx.x & 63;
    const bf16_t* a0 = A + (((size_t)(tr0 + wtmp)     * KTILES + kt0) << 9) + ltmp * 8;
    const bf16_t* a1 = A + (((size_t)(tr0 + wtmp + 4) * KTILES + kt0) << 9) + ltmp * 8;
    const bf16_t* b0 = Bt + (((size_t)(tc0 + wtmp)     * KTILES + kt0) << 9) + ltmp * 8;
    const bf16_t* b1 = Bt + (((size_t)(tc0 + wtmp + 4) * KTILES + kt0) << 9) + ltmp * 8;
    GEMM_PIPE()
    bf16_t* Cz = C + (size_t)blockIdx.z * sstride;
    int orow = lane & 15, ocol = (lane >> 4) * 4;
    size_t row0 = (size_t)blockIdx.y * 128;
    size_t col0 = (size_t)blockIdx.x * 128;
    #pragma unroll
    for (int i = 0; i < 4; ++i) {
        size_t gr = row0 + wm * 64 + i * 16 + orow;
        #pragma unroll
        for (int j = 0; j < 4; ++j) {
            size_t gc = col0 + wn * 64 + j * 16 + ocol;
            bf16x4 v;
            #pragma unroll
            for (int rg = 0; rg < 4; ++rg) v[rg] = (bf16_t)acc[i][j][rg];
            *(bf16x4*)(Cz + gr * (size_t)ldc + gc) = v;
        }
    }
}

// ---- 512-thr 8-wave BK=64 mid-barrier distance-2 pipe (128x128 tile) ----
#define GEMM_PIPE8()                                                           \
    int tid = threadIdx.x, lane = tid & 63, w = tid >> 6;      /* 0..7 */      \
    int wm = w >> 2, wn = w & 3;                                               \
    f32x4 acc[4][2];                                                           \
    _Pragma("unroll")                                                          \
    for (int i = 0; i < 4; ++i)                                                \
        _Pragma("unroll")                                                      \
        for (int j = 0; j < 2; ++j) acc[i][j] = (f32x4){0.f, 0.f, 0.f, 0.f};   \
    auto stage = [&](int kk) {                                                 \
        int b = kk & 1;                                                        \
        size_t go = (size_t)kk * 1024;                                         \
        bf16_t* la = &As2[b * 8192 + w * 1024];                                \
        bf16_t* lb = &Bs2[b * 8192 + w * 1024];                                \
        g2l16(a0 + go, la);   g2l16(a0 + go + 512, la + 512);                  \
        g2l16(b0 + go, lb);   g2l16(b0 + go + 512, lb + 512);                  \
    };                                                                         \
    stage(0); stage(1);                                                        \
    asm volatile("s_waitcnt vmcnt(4)" ::: "memory");                           \
    __builtin_amdgcn_s_barrier();                                              \
    for (int kk = 0; kk < nk; ++kk) {                                          \
        const bf16_t* cA = &As2[(kk & 1) * 8192];                              \
        const bf16_t* cB = &Bs2[(kk & 1) * 8192];                              \
        bf16x8 af0[4], af1[4], bq0[2], bq1[2];                                 \
        _Pragma("unroll")                                                      \
        for (int i = 0; i < 4; ++i) {                                          \
            af0[i] = *(const bf16x8*)(cA + (wm * 4 + i) * 1024 + lane * 8);    \
            af1[i] = *(const bf16x8*)(cA + (wm * 4 + i) * 1024 + 512 + lane * 8); \
        }                                                                      \
        _Pragma("unroll")                                                      \
        for (int j = 0; j < 2; ++j) {                                          \
            bq0[j] = *(const bf16x8*)(cB + (wn * 2 + j) * 1024 + lane * 8);    \
            bq1[j] = *(const bf16x8*)(cB + (wn * 2 + j) * 1024 + 512 + lane * 8); \
        }                                                                      \
        asm volatile("s_waitcnt lgkmcnt(0)" ::: "memory");                     \
        __builtin_amdgcn_s_barrier();                                          \
        if (kk + 2 < nk) stage(kk + 2);                                        \
        _Pragma("unroll")                                                      \
        for (int i = 0; i < 4; ++i)                                            \
            _Pragma("unroll")                                                  \
            for (int j = 0; j < 2; ++j)                                        \
                acc[i][j] = mfma16(bq0[j], af0[i], acc[i][j]);                 \
        _Pragma("unroll")                                                      \
        for (int i = 0; i < 4; ++i)                                            \
            _Pragma("unroll")                                                  \
            for (int j = 0; j < 2; ++j)                                        \
                acc[i][j] = mfma16(bq1[j], af1[i], acc[i][j]);                 \
        if (kk + 2 < nk) asm volatile("s_waitcnt vmcnt(4)" ::: "memory");      \
        else             asm volatile("s_waitcnt vmcnt(0)" ::: "memory");      \
        __builtin_amdgcn_s_barrier();                                          \
    }

// GEMM + fused colmix epilogue (splits=1, M=2n rows, N=2048 cols).
// 8x8 XCD tile-patch swizzle; 512 threads, 8 waves.
__global__ __launch_bounds__(512, 4) void k_gemm16_mix(
        const bf16_t* __restrict__ A, const bf16_t* __restrict__ Bt, int n,
        const float* __restrict__ cus, const float* __restrict__ cui,
        const float* __restrict__ cls, const float* __restrict__ cli,
        const float* __restrict__ bvec,
        bf16_t* __restrict__ Ab2, float* __restrict__ av, int nk) {
    __shared__ __align__(16) bf16_t As2[16384];
    __shared__ __align__(16) bf16_t Bs2[16384];
    __shared__ float asum[4][128];
    int wg = (int)(blockIdx.y * gridDim.x + blockIdx.x);   // 0..511
    int xcd = wg & 7, idx = wg >> 3;                       // 64 blocks/XCD
    int bm = (xcd & 3) * 8 + (idx & 7);                    // 0..31 M-tile
    int bn = (xcd >> 2) * 8 + (idx >> 3);                  // 0..15 N-tile
    int tr0 = bm * 8, tc0 = bn * 8;
    int wtmp = threadIdx.x >> 6, ltmp = threadIdx.x & 63;
    const bf16_t* a0 = A + (((size_t)(tr0 + wtmp) * KTILES) << 9) + ltmp * 8;
    const bf16_t* b0 = Bt + (((size_t)(tc0 + wtmp) * KTILES) << 9) + ltmp * 8;
    GEMM_PIPE8()
    // ---- fused colmix epilogue ----
    size_t row0 = (size_t)bm * 128;
    size_t col0 = (size_t)bn * 128;
    bool isU = (int)row0 < n;            // row0 multiple of 128, n multiple of 128
    const float* ps = isU ? cus : cls;
    const float* ns = isU ? cls : cus;
    const float* yi = isU ? cui : cli;
    const float* zi = isU ? cli : cui;
    int orow = lane & 15, ocol = (lane >> 4) * 4;
    #pragma unroll
    for (int i = 0; i < 4; ++i) {
        int gr = (int)row0 + wm * 64 + i * 16 + orow;
        float ra = 0.f;
        #pragma unroll
        for (int j = 0; j < 2; ++j) {
            int gc = (int)col0 + wn * 32 + j * 16 + ocol;
            f32x4 p0 = *(const f32x4*)(ps + gc);
            f32x4 q0 = *(const f32x4*)(ns + gc);
            f32x4 y0 = *(const f32x4*)(yi + gc);
            f32x4 z0 = *(const f32x4*)(zi + gc);
            f32x4 c0 = *(const f32x4*)(bvec + gc);
            bf16x4 ov;
            #pragma unroll
            for (int rg = 0; rg < 4; ++rg) {
                float v = acc[i][j][rg];
                float pos = fmaxf(v, 0.f), neg = fminf(v, 0.f);
                float mx = pos * p0[rg] + neg * q0[rg];
                ov[rg] = (bf16_t)mx;
                ra += pos * y0[rg] + neg * z0[rg] + mx * c0[rg];
            }
            *(bf16x4*)(Ab2 + swz(gr, gc, KTILES)) = ov;
        }
        ra += __shfl_xor(ra, 16, 64);
        ra += __shfl_xor(ra, 32, 64);
        if (lane < 16) asum[wn][wm * 64 + i * 16 + lane] = ra;
    }
    __syncthreads();
    if (tid < 128)
        atomicAdd(&av[row0 + tid],
                  asum[0][tid] + asum[1][tid] + asum[2][tid] + asum[3][tid]);
}

// GEMM + fused final c0-reduce epilogue (splits=1, N = 896 padded) +
// LAST-BLOCK SPU TAIL: after all 224 blocks' av atomics are at the coherence
// point (the epilogue __syncthreads drains each wave's vmcnt before barrier),
// each block bumps a device counter; the 224th block runs the full 2048-neuron
// spu in-kernel, reading av with device-scope atomic loads (cross-XCD safe).
__global__ __launch_bounds__(512, 4) void k_gemm16_red(
        const bf16_t* __restrict__ A, const bf16_t* __restrict__ Bt, int n,
        const float* __restrict__ ubn, const float* __restrict__ lbn,
        float* __restrict__ av, int nk,
        int* __restrict__ cnt,
        const float* __restrict__ iU, const float* __restrict__ iL,
        float* __restrict__ us, float* __restrict__ ui,
        float* __restrict__ ls, float* __restrict__ li,
        float* __restrict__ pU, float* __restrict__ pL) {
    __shared__ __align__(16) bf16_t As2[16384];
    __shared__ __align__(16) bf16_t Bs2[16384];
    __shared__ float asum[4][128];
    __shared__ int lastf;
    int wg = (int)(blockIdx.y * gridDim.x + blockIdx.x);   // 0..223
    int id = (wg & 7) * 28 + (wg >> 3);                    // bijective
    int bm = id / 7, bn = id % 7;                          // 4x7 patch/XCD
    int tr0 = bm * 8, tc0 = bn * 8;
    int wtmp = threadIdx.x >> 6, ltmp = threadIdx.x & 63;
    const bf16_t* a0 = A + (((size_t)(tr0 + wtmp) * KTILES) << 9) + ltmp * 8;
    const bf16_t* b0 = Bt + (((size_t)(tc0 + wtmp) * KTILES) << 9) + ltmp * 8;
    GEMM_PIPE8()
    // ---- fused c0-reduce epilogue ----
    size_t row0 = (size_t)bm * 128;
    size_t col0 = (size_t)bn * 128;
    bool isU = (int)row0 < n;
    const float* p = isU ? ubn : lbn;
    const float* q = isU ? lbn : ubn;
    int ocol = (lane >> 4) * 4;
    #pragma unroll
    for (int i = 0; i < 4; ++i) {
        float ra = 0.f;
        #pragma unroll
        for (int j = 0; j < 2; ++j) {
            int gc = (int)col0 + wn * 32 + j * 16 + ocol;
            f32x4 p0 = *(const f32x4*)(p + gc);
            f32x4 q0 = *(const f32x4*)(q + gc);
            #pragma unroll
            for (int rg = 0; rg < 4; ++rg) {
                float v = acc[i][j][rg];
                ra += fmaxf(v, 0.f) * p0[rg] + fminf(v, 0.f) * q0[rg];
            }
        }
        ra += __shfl_xor(ra, 16, 64);
        ra += __shfl_xor(ra, 32, 64);
        if (lane < 16) asum[wn][wm * 64 + i * 16 + lane] = ra;
    }
    __syncthreads();
    if (tid < 128)
        atomicAdd(&av[row0 + tid],
                  asum[0][tid] + asum[1][tid] + asum[2][tid] + asum[3][tid]);
    // ---- last-block spu tail ----
    __syncthreads();   // drains this block's av atomics (vmcnt 0) + sync
    if (tid == 0) {
        int old = atomicAdd(cnt, 1);
        lastf = (old == (int)(gridDim.x * gridDim.y) - 1) ? 1 : 0;
    }
    __syncthreads();
    if (lastf) {
        for (int i = tid; i < n; i += 512) {
            float vU = __hip_atomic_load(&av[i], __ATOMIC_RELAXED,
                                         __HIP_MEMORY_SCOPE_AGENT);
            float vL = __hip_atomic_load(&av[n + i], __ATOMIC_RELAXED,
                                         __HIP_MEMORY_SCOPE_AGENT);
            spu_body(i, n, iU[i], iL[i], vU, vL, us, ui, ls, li, pU, pL);
        }
    }
}

// ---------------- host launch ----------------

extern "C" void kernel_launch(void* const* d_in, const int* in_sizes, int n_in,
                              void* d_out, int out_size, void* d_ws, size_t ws_size,
                              hipStream_t stream) {
    (void)in_sizes; (void)n_in; (void)out_size; (void)ws_size;
    const float* x   = (const float*)d_in[0];
    const float* eps = (const float*)d_in[1];
    const float* W1  = (const float*)d_in[2];
    const float* B1  = (const float*)d_in[3];
    const float* W2  = (const float*)d_in[4];
    const float* B2  = (const float*)d_in[5];
    const float* W3  = (const float*)d_in[6];
    const float* B3  = (const float*)d_in[7];
    const float* W4  = (const float*)d_in[8];
    const float* B4  = (const float*)d_in[9];
    float* out = (float*)d_out;

    const int H = 2048, DIN = 784, DOUT = 10;
    const int NP1 = 896;           // DIN padded to x128
    const int MP4 = 128;           // layer-4 row pad

    float* ws = (float*)d_ws;
    size_t off = 0;
    auto alloc = [&](size_t nf) -> float* {
        float* p = ws + off;
        off += (nf + 3) & ~(size_t)3;
        return p;
    };
    float* ubn = alloc(NP1);
    float* lbn = alloc(NP1);
    float* us1 = alloc(H); float* ui1 = alloc(H); float* ls1 = alloc(H); float* li1 = alloc(H);
    float* pU1 = alloc(H); float* pL1 = alloc(H);
    float* iU2 = alloc(H); float* iL2 = alloc(H);
    float* us2 = alloc(H); float* ui2 = alloc(H); float* ls2 = alloc(H); float* li2 = alloc(H);
    float* pU2 = alloc(H); float* pL2 = alloc(H);
    float* iU3 = alloc(H); float* iL3 = alloc(H);
    float* us3 = alloc(H); float* ui3 = alloc(H); float* ls3 = alloc(H); float* li3 = alloc(H);
    float* pU3 = alloc(H); float* pL3 = alloc(H);
    float* iU4 = alloc(32); float* iL4 = alloc(32);
    float* av  = alloc(2 * H);
    int* cnt2 = (int*)alloc(4);
    int* cnt3 = (int*)alloc(4);
    bf16_t* Ab  = (bf16_t*)alloc((size_t)2 * H * H / 2);       // 4096 x 2048 bf16 swz
    bf16_t* Ab2 = (bf16_t*)alloc((size_t)2 * H * H / 2);       // second operand buffer
    bf16_t* W1t = (bf16_t*)alloc((size_t)NP1 * H / 2);
    bf16_t* W2t = (bf16_t*)alloc((size_t)H * H / 2);
    bf16_t* W3t = (bf16_t*)alloc((size_t)H * H / 2);
    bf16_t* Cs  = (bf16_t*)alloc((size_t)16 * MP4 * H / 2);    // L4 split-16 slabs (bf16)

    dim3 blk(256);

    // weight transpose/convert/swizzle + input bounds + FULL LAYER 1 (z=3)
    k_wT3<<<dim3(32, 32, 4), blk, 0, stream>>>(W1, W2, W3, W1t, W2t, W3t,
        x, eps, ubn, lbn, B1, us1, ui1, ls1, li1, pU1, pL1, cnt2, cnt3);

    size_t ss4H = (size_t)MP4 * H;          // layer-4 N=H slab
    size_t ss4N = (size_t)MP4 * NP1;        // layer-4 N=NP1 slab

    // ======== Layer 2 ========
    k_prep16<<<dim3(2 * H / 16), blk, 0, stream>>>(W2, B2, H,
        us1, ui1, ls1, li1, B1, pU1, pL1, Ab, av, iU2, iL2);
    k_gemm16_red<<<dim3(2 * H / 128, NP1 / 128), dim3(512), 0, stream>>>(Ab, W1t, H,
        ubn, lbn, av, KTILES / 2,
        cnt2, iU2, iL2, us2, ui2, ls2, li2, pU2, pL2);

    // ======== Layer 3 ========
    k_prep16<<<dim3(2 * H / 16), blk, 0, stream>>>(W3, B3, H,
        us2, ui2, ls2, li2, B2, pU2, pL2, Ab, av, iU3, iL3);
    k_gemm16_mix<<<dim3(2 * H / 128, H / 128), dim3(512), 0, stream>>>(Ab, W2t, H,
        us1, ui1, ls1, li1, B1, Ab2, av, KTILES / 2);
    k_gemm16_red<<<dim3(2 * H / 128, NP1 / 128), dim3(512), 0, stream>>>(Ab2, W1t, H,
        ubn, lbn, av, KTILES / 2,
        cnt3, iU3, iL3, us3, ui3, ls3, li3, pU3, pL3);

    // ======== Layer 4 (M = 20 padded to 128, split-K 16, colmix k-split 8) ========
    k_prep16<<<dim3(MP4 / 16), blk, 0, stream>>>(W4, B4, DOUT,
        us3, ui3, ls3, li3, B3, pU3, pL3, Ab, av, iU4, iL4);
    k_gemm16<<<dim3(H / 128, MP4 / 128, 16), blk, 0, stream>>>(Ab, W3t, Cs, H, ss4H, 2);
    k_colmix16<<<dim3(MP4 / 16, 8), blk, 0, stream>>>(Cs, H, 16, ss4H, DOUT, KTILES / 8,
        us2, ui2, ls2, li2, B2, Ab2, av);
    k_gemm16<<<dim3(H / 128, MP4 / 128, 16), blk, 0, stream>>>(Ab2, W2t, Cs, H, ss4H, 2);
    k_colmix16<<<dim3(MP4 / 16, 8), blk, 0, stream>>>(Cs, H, 16, ss4H, DOUT, KTILES / 8,
        us1, ui1, ls1, li1, B1, Ab, av);
    k_gemm16<<<dim3(NP1 / 128, MP4 / 128, 16), blk, 0, stream>>>(Ab, W1t, Cs, NP1, ss4N, 2);
    k_reduce16f<<<dim3(1), dim3(640), 0, stream>>>(Cs, NP1, DIN, DOUT, 16, ss4N,
        av, ubn, lbn, iL4, out);
}

// Round 9
// 321.928 us; speedup vs baseline: 1.0796x; 1.0796x over previous
//
#include <hip/hip_runtime.h>
#include <cstdint>
#include <cstddef>

#define MEAN_C 0.1307f
#define SIGMA_C 0.3081f
#define SIG_SCALE_C 5.0f

typedef __bf16 bf16_t;
typedef __bf16 bf16x8 __attribute__((ext_vector_type(8)));
typedef __bf16 bf16x4 __attribute__((ext_vector_type(4)));
typedef float f32x4 __attribute__((ext_vector_type(4)));

__device__ __forceinline__ f32x4 mfma16(bf16x8 a, bf16x8 b, f32x4 c) {
    return __builtin_amdgcn_mfma_f32_16x16x32_bf16(a, b, c, 0, 0, 0);
}

typedef const __attribute__((address_space(1))) void* gvp;
typedef __attribute__((address_space(3))) void* lvp;
__device__ __forceinline__ void g2l16(const void* g, void* l) {
    __builtin_amdgcn_global_load_lds((gvp)g, (lvp)l, 16, 0, 0);
}

// swizzled bf16 operand layout: 16x32 tiles (1KB); chunk index within tile =
// lane = (k-chunk)*16 + row  (16B each). offset(r,k), K = ktiles*32.
__device__ __forceinline__ size_t swz(int r, int k, int ktiles) {
    return (((size_t)(r >> 4) * ktiles + (k >> 5)) << 9)
         + (((k >> 3) & 3) << 7) + ((r & 15) << 3) + (k & 7);
}

#define KTILES 64   // K = 2048

// ---------------- device helpers ----------------

__device__ __forceinline__ float sigmoidf_(float x) {
    if (x >= 0.f) { float e = __expf(-x); return 1.f / (1.f + e); }
    float e = __expf(x); return e / (1.f + e);
}

__device__ __forceinline__ float spu_f(float x) {
    return (x >= 0.f) ? (x * x - 0.5f) : (sigmoidf_(-x) - 1.f);
}

__device__ __forceinline__ float wave_sum(float a) {
    #pragma unroll
    for (int o = 32; o > 0; o >>= 1) a += __shfl_xor(a, o, 64);
    return a;
}

// full analyze_spu for one neuron i, given clamp bounds (iUi, iLi) and the
// back-substituted chain values vU (upper row) / vL (lower row).
__device__ __forceinline__ void spu_body(int i, int n,
        float iUi, float iLi, float vU, float vL,
        float* __restrict__ us, float* __restrict__ ui,
        float* __restrict__ ls, float* __restrict__ li,
        float* __restrict__ pU, float* __restrict__ pL) {
    float ux = fminf(iUi, vU);
    float lx = fmaxf(iLi, vL);
    float uy = spu_f(ux), ly = spu_f(lx);
    float new_ub = fmaxf(uy, ly);
    float sj = (uy - ly) / (ux - lx);
    float ij = uy - sj * ux;
    bool right = lx > 0.f;
    bool left = ux <= 0.f;
    float mid = 0.5f * (ux + lx);
    float sp = 2.f * mid, ip = -mid * mid - 0.5f;
    float sm = sigmoidf_(mid);
    float ssm = -sm * (1.f - sm);
    float ism = -sm - ssm * mid;
    bool crossing = (!left) && (!right);
    float new_lb = crossing ? -0.5f : fminf(uy, ly);
    float spu_s = 2.f * ux, ipu = -ux * ux - 0.5f;
    float limit = spu_s * lx + ipu;
    float clm = (fabsf(lx) > ux) ? 1.f : 0.f;
    float clp = sigmoidf_((clm - 0.5f) * 2.f * SIG_SCALE_C) * (ly - limit) + limit;
    bool ptm = clp < -0.5f;
    float D = 4.f * lx * lx - 4.f * clp - 2.f;
    float x2 = (2.f * lx + sqrtf(fmaxf(D, 0.f))) * 0.5f;
    float spt = 2.f * x2, ipt = -x2 * x2 - 0.5f;
    float sjn = (clp + 0.5f) / lx;
    float ijn = -0.5f;
    float s_cl = ptm ? spt : sjn;
    float i_cl = ptm ? ipt : ijn;
    float sl = sigmoidf_(lx);
    float ssl = -sl * (1.f - sl);
    float isl = -sl - ssl * lx;
    float stv = ssl * ux + isl - uy;
    float Lb = lx, Rb = 0.f;
    #pragma unroll
    for (int t = 0; t < 10; ++t) {
        float mm = 0.5f * (Lb + Rb);
        float smm = sigmoidf_(mm);
        float sms = -smm * (1.f - smm);
        float smi = -smm - sms * mm;
        bool mask = (sms * ux + smi - uy) > 0.f;
        Lb = mask ? mm : Lb;
        Rb = mask ? Rb : mm;
    }
    float scp = sigmoidf_(-SIG_SCALE_C) * (Lb - lx) + lx;
    float sc = sigmoidf_(scp);
    float ssc = -sc * (1.f - sc);
    float isc = -sc - ssc * scp;
    bool up = stv > 0.f;
    float s_cu = up ? ssc : sj;
    float i_cu = up ? isc : ij;
    float usv, uiv, lsv, liv;
    if (right)      { usv = sj;   uiv = ij;   lsv = sp;   liv = ip;   }
    else if (left)  { usv = ssm;  uiv = ism;  lsv = sj;   liv = ij;   }
    else            { usv = s_cu; uiv = i_cu; lsv = s_cl; liv = i_cl; }
    us[i] = usv; ui[i] = uiv; ls[i] = lsv; li[i] = liv;
    float vu = (usv >= 0.f) ? vU : vL;
    float vl = (lsv >= 0.f) ? vL : vU;
    pU[i] = fminf(new_ub, usv * vu + uiv);
    pL[i] = fmaxf(new_lb, lsv * vl + liv);
}

// ---------------- small kernels ----------------

// fused layer-1 interval bound + analyze_spu
__global__ __launch_bounds__(256) void k_interval_spu(
        const float* __restrict__ W, const float* __restrict__ b,
        const float* __restrict__ U, const float* __restrict__ L,
        int m, int n,
        float* __restrict__ us, float* __restrict__ ui,
        float* __restrict__ ls, float* __restrict__ li,
        float* __restrict__ pU, float* __restrict__ pL) {
    int r = (blockIdx.x << 2) + (threadIdx.x >> 6);
    if (r >= n) return;
    int lane = threadIdx.x & 63;
    const f32x4* Wr = (const f32x4*)(W + (size_t)r * m);
    const f32x4* U4 = (const f32x4*)U;
    const f32x4* L4 = (const f32x4*)L;
    int nf4 = m >> 2;
    float au = 0.f, al = 0.f;
    for (int j = lane; j < nf4; j += 64) {
        f32x4 wv = Wr[j], uu = U4[j], ll = L4[j];
        #pragma unroll
        for (int u = 0; u < 4; ++u) {
            float w = wv[u];
            float hi = (w > 0.f) ? uu[u] : ll[u];
            float lo2 = (w > 0.f) ? ll[u] : uu[u];
            au = fmaf(w, hi, au);
            al = fmaf(w, lo2, al);
        }
    }
    au = wave_sum(au); al = wave_sum(al);
    if (lane == 0) {
        float vU = au + b[r], vL = al + b[r];
        spu_body(r, n, vU, vL, vU, vL, us, ui, ls, li, pU, pL);
    }
}

// standalone spu (layers 2/3)
__global__ void k_spu2(const float* __restrict__ iU, const float* __restrict__ iL,
                       const float* __restrict__ vraw, int n,
                       float* __restrict__ us, float* __restrict__ ui,
                       float* __restrict__ ls, float* __restrict__ li,
                       float* __restrict__ pU, float* __restrict__ pL) {
    int i = blockIdx.x * blockDim.x + threadIdx.x;
    if (i >= n) return;
    spu_body(i, n, iU[i], iL[i], vraw[i], vraw[n + i], us, ui, ls, li, pU, pL);
}

// ---------------- bf16 producers ----------------

// merged transpose/convert/swizzle of W1,W2,W3 + input-bounds side block.
__global__ __launch_bounds__(256) void k_wT3(
        const float* __restrict__ W1, const float* __restrict__ W2,
        const float* __restrict__ W3,
        bf16_t* __restrict__ W1t, bf16_t* __restrict__ W2t, bf16_t* __restrict__ W3t,
        const float* __restrict__ x, const float* __restrict__ eps,
        float* __restrict__ ubn, float* __restrict__ lbn) {
    __shared__ bf16_t t[64 * 65];
    int z = blockIdx.z;
    const float* W; int N, ldw; bf16_t* Wt;
    if (z == 0)      { W = W2; N = 2048; ldw = 2048; Wt = W2t; }
    else if (z == 1) { W = W3; N = 2048; ldw = 2048; Wt = W3t; }
    else {
        W = W1; N = 784; ldw = 784; Wt = W1t;
        if (blockIdx.y >= 14) {
            if (blockIdx.y == 14 && blockIdx.x == 0) {
                for (int i = threadIdx.x; i < 896; i += 256) {
                    if (i >= 784) { ubn[i] = 0.f; lbn[i] = 0.f; }
                    else {
                        float e = eps[0];
                        float ub = fminf(x[i] + e, 1.f);
                        float lb = fmaxf(x[i] - e, 0.f);
                        ubn[i] = (ub - MEAN_C) / SIGMA_C;
                        lbn[i] = (lb - MEAN_C) / SIGMA_C;
                    }
                }
            }
            return;
        }
    }
    int k0 = blockIdx.x * 64, n0 = blockIdx.y * 64;
    int tid = threadIdx.x;
    int rg = tid >> 4;            // 0..15 row sub-index
    int cg = (tid & 15) * 4;      // column start (f32x4)
    bool fast = (n0 + 64 <= N);
    #pragma unroll
    for (int it = 0; it < 4; ++it) {
        int row = it * 16 + rg;   // local k
        const float* Wr = W + (size_t)(k0 + row) * ldw + n0 + cg;
        float v0, v1, v2, v3;
        if (fast) {
            f32x4 vv = *(const f32x4*)Wr;
            v0 = vv[0]; v1 = vv[1]; v2 = vv[2]; v3 = vv[3];
        } else {
            v0 = (n0 + cg + 0 < N) ? Wr[0] : 0.f;
            v1 = (n0 + cg + 1 < N) ? Wr[1] : 0.f;
            v2 = (n0 + cg + 2 < N) ? Wr[2] : 0.f;
            v3 = (n0 + cg + 3 < N) ? Wr[3] : 0.f;
        }
        t[(cg + 0) * 65 + row] = (bf16_t)v0;
        t[(cg + 1) * 65 + row] = (bf16_t)v1;
        t[(cg + 2) * 65 + row] = (bf16_t)v2;
        t[(cg + 3) * 65 + row] = (bf16_t)v3;
    }
    __syncthreads();
    #pragma unroll
    for (int p = 0; p < 2; ++p) {
        int c = tid + p * 256;
        int lr = c & 63, lq = c >> 6;
        bf16x8 v;
        #pragma unroll
        for (int u = 0; u < 8; ++u) v[u] = t[lr * 65 + lq * 8 + u];
        *(bf16x8*)(Wt + swz(n0 + lr, k0 + lq * 8, KTILES)) = v;
    }
}

// prep (fused interval-affine)
__global__ __launch_bounds__(256) void k_prep16(
        const float* __restrict__ W, const float* __restrict__ b, int n,
        const float* __restrict__ cus, const float* __restrict__ cui,
        const float* __restrict__ cls, const float* __restrict__ cli,
        const float* __restrict__ bvec,
        const float* __restrict__ U, const float* __restrict__ L,
        bf16_t* __restrict__ Ab, float* __restrict__ av,
        float* __restrict__ iU, float* __restrict__ iL) {
    int rt = blockIdx.x;
    int tid = threadIdx.x, lane = tid & 63, wid = tid >> 6;
    int mrow = lane & 15, q = lane >> 4;
    int r = rt * 16 + mrow;
    bool act = r < 2 * n;
    bool isU = r < n;
    int i = act ? (isU ? r : r - n) : 0;
    float gate = act ? 1.f : 0.f;
    const float* Wr = W + (size_t)i * 2048;
    const float* ps = isU ? cus : cls;
    const float* ns = isU ? cls : cus;
    const float* yi = isU ? cui : cli;
    const float* zi = isU ? cli : cui;
    const float* hi = isU ? U : L;
    const float* lo = isU ? L : U;
    float a = 0.f, a2 = 0.f;
    bf16_t* Abase = Ab + ((size_t)rt * KTILES) * 512 + lane * 8;
    for (int kt = wid; kt < KTILES; kt += 4) {
        int k0 = kt * 32 + q * 8;
        bf16x8 ov;
        #pragma unroll
        for (int h = 0; h < 2; ++h) {
            int kb = k0 + 4 * h;
            f32x4 wv = *(const f32x4*)(Wr + kb);
            f32x4 p0 = *(const f32x4*)(ps + kb);
            f32x4 q0 = *(const f32x4*)(ns + kb);
            f32x4 y0 = *(const f32x4*)(yi + kb);
            f32x4 z0 = *(const f32x4*)(zi + kb);
            f32x4 c0 = *(const f32x4*)(bvec + kb);
            f32x4 h0 = *(const f32x4*)(hi + kb);
            f32x4 l0 = *(const f32x4*)(lo + kb);
            #pragma unroll
            for (int u = 0; u < 4; ++u) {
                float w = gate * wv[u];
                float pos = fmaxf(w, 0.f), neg = fminf(w, 0.f);
                float mx = pos * p0[u] + neg * q0[u];
                ov[4 * h + u] = (bf16_t)mx;
                a += pos * y0[u] + neg * z0[u] + mx * c0[u];
                a2 += pos * h0[u] + neg * l0[u];   // interval dot
            }
        }
        *(bf16x8*)(Abase + (size_t)kt * 512) = ov;
    }
    a += __shfl_xor(a, 16, 64);  a += __shfl_xor(a, 32, 64);
    a2 += __shfl_xor(a2, 16, 64); a2 += __shfl_xor(a2, 32, 64);
    __shared__ float sh[2][4][16];
    if (lane < 16) { sh[0][wid][lane] = a; sh[1][wid][lane] = a2; }
    __syncthreads();
    if (tid < 16) {
        int r2 = rt * 16 + tid;
        float ta = sh[0][0][tid] + sh[0][1][tid] + sh[0][2][tid] + sh[0][3][tid];
        float tb = sh[1][0][tid] + sh[1][1][tid] + sh[1][2][tid] + sh[1][3][tid];
        if (r2 < 2 * n) {
            bool isU2 = r2 < n;
            int i2 = isU2 ? r2 : r2 - n;
            av[r2] = ta + b[i2];
            if (isU2) iU[i2] = tb + b[i2];
            else      iL[i2] = tb + b[i2];
        } else {
            av[r2] = 0.f;
        }
    }
}

// colmix (layer-4 small-M chains): bf16 split slabs -> swizzled bf16 Ab
__global__ __launch_bounds__(256) void k_colmix16(
        const bf16_t* __restrict__ Cb, int ldc, int splits, size_t sstride, int n,
        int tpb,
        const float* __restrict__ cus, const float* __restrict__ cui,
        const float* __restrict__ cls, const float* __restrict__ cli,
        const float* __restrict__ bvec,
        bf16_t* __restrict__ Ab, float* __restrict__ av) {
    int rt = blockIdx.x;
    int kt0 = blockIdx.y * tpb;
    int tid = threadIdx.x, lane = tid & 63, wid = tid >> 6;
    int mrow = lane & 15, q = lane >> 4;
    int r = rt * 16 + mrow;
    bool isU = r < n;
    const bf16_t* Cr = Cb + (size_t)r * ldc;
    const float* ps = isU ? cus : cls;
    const float* ns = isU ? cls : cus;
    const float* yi = isU ? cui : cli;
    const float* zi = isU ? cli : cui;
    float a = 0.f;
    bf16_t* Abase = Ab + ((size_t)rt * KTILES) * 512 + lane * 8;
    for (int kt = kt0 + wid; kt < kt0 + tpb; kt += 4) {
        int k0 = kt * 32 + q * 8;
        float wsum[8] = {0.f, 0.f, 0.f, 0.f, 0.f, 0.f, 0.f, 0.f};
        for (int s = 0; s < splits; ++s) {
            bf16x8 v = *(const bf16x8*)(Cr + s * sstride + k0);
            #pragma unroll
            for (int u = 0; u < 8; ++u) wsum[u] += (float)v[u];
        }
        f32x4 p0 = *(const f32x4*)(ps + k0), p1 = *(const f32x4*)(ps + k0 + 4);
        f32x4 q0 = *(const f32x4*)(ns + k0), q1 = *(const f32x4*)(ns + k0 + 4);
        f32x4 y0 = *(const f32x4*)(yi + k0), y1 = *(const f32x4*)(yi + k0 + 4);
        f32x4 z0 = *(const f32x4*)(zi + k0), z1 = *(const f32x4*)(zi + k0 + 4);
        f32x4 c0 = *(const f32x4*)(bvec + k0), c1 = *(const f32x4*)(bvec + k0 + 4);
        bf16x8 ov;
        #pragma unroll
        for (int u = 0; u < 4; ++u) {
            float w = wsum[u];
            float pos = fmaxf(w, 0.f), neg = fminf(w, 0.f);
            float mx = pos * p0[u] + neg * q0[u];
            ov[u] = (bf16_t)mx;
            a += pos * y0[u] + neg * z0[u] + mx * c0[u];
        }
        #pragma unroll
        for (int u = 0; u < 4; ++u) {
            float w = wsum[4 + u];
            float pos = fmaxf(w, 0.f), neg = fminf(w, 0.f);
            float mx = pos * p1[u] + neg * q1[u];
            ov[4 + u] = (bf16_t)mx;
            a += pos * y1[u] + neg * z1[u] + mx * c1[u];
        }
        *(bf16x8*)(Abase + (size_t)kt * 512) = ov;
    }
    a += __shfl_xor(a, 16, 64);
    a += __shfl_xor(a, 32, 64);
    __shared__ float sh[4][16];
    if (lane < 16) sh[wid][lane] = a;
    __syncthreads();
    if (tid < 16) {
        float tot = sh[0][tid] + sh[1][tid] + sh[2][tid] + sh[3][tid];
        atomicAdd(&av[rt * 16 + tid], tot);
    }
}

// final c0 step + min, fused, single block of 10 waves (one wave per L row).
__global__ __launch_bounds__(640) void k_reduce16f(
        const bf16_t* __restrict__ Cb, int ldc, int m, int n,
        int splits, size_t sstride,
        const float* __restrict__ av,
        const float* __restrict__ ubn, const float* __restrict__ lbn,
        const float* __restrict__ iL,
        float* __restrict__ out) {
    __shared__ float sbl[16];
    int tid = threadIdx.x, lane = tid & 63, wv = tid >> 6;   // 10 waves
    int nch = m >> 3;   // m % 8 == 0
    int i = wv;          // 0..9 == DOUT rows
    int r = n + i;       // L rows only
    const bf16_t* Cr = Cb + (size_t)r * ldc;
    const float* p = lbn;
    const float* q = ubn;
    float a = 0.f;
    for (int c = lane; c < nch; c += 64) {
        float wsum[8] = {0.f, 0.f, 0.f, 0.f, 0.f, 0.f, 0.f, 0.f};
        for (int s = 0; s < splits; ++s) {
            bf16x8 v = *(const bf16x8*)(Cr + s * sstride + c * 8);
            #pragma unroll
            for (int u = 0; u < 8; ++u) wsum[u] += (float)v[u];
        }
        f32x4 p0 = *(const f32x4*)(p + c * 8), p1 = *(const f32x4*)(p + c * 8 + 4);
        f32x4 q0 = *(const f32x4*)(q + c * 8), q1 = *(const f32x4*)(q + c * 8 + 4);
        #pragma unroll
        for (int u = 0; u < 4; ++u) {
            a += fmaxf(wsum[u], 0.f) * p0[u] + fminf(wsum[u], 0.f) * q0[u];
            a += fmaxf(wsum[4 + u], 0.f) * p1[u] + fminf(wsum[4 + u], 0.f) * q1[u];
        }
    }
    a = wave_sum(a);
    if (lane == 0) sbl[i] = fmaxf(iL[i], a + av[r]);
    __syncthreads();
    if (tid < 64) {
        float v = 3.4e38f;
        for (int j = lane; j < n; j += 64) v = fminf(v, sbl[j]);
        #pragma unroll
        for (int o = 32; o > 0; o >>= 1) v = fminf(v, __shfl_down(v, o, 64));
        if (lane == 0) out[0] = v;
    }
}

// ---- 256-thr BK=64 mid-barrier distance-2 pipe (L4 split-K GEMM) ----
#define GEMM_PIPE()                                                            \
    int tid = threadIdx.x, lane = tid & 63, w = tid >> 6;                      \
    int wm = w & 1, wn = w >> 1;                                               \
    f32x4 acc[4][4];                                                           \
    _Pragma("unroll")                                                          \
    for (int i = 0; i < 4; ++i)                                                \
        _Pragma("unroll")                                                      \
        for (int j = 0; j < 4; ++j) acc[i][j] = (f32x4){0.f, 0.f, 0.f, 0.f};   \
    auto stage = [&](int kk) {                                                 \
        int b = kk & 1;                                                        \
        size_t go = (size_t)kk * 1024;                                         \
        bf16_t* la = &As2[b * 8192 + w * 1024];                                \
        bf16_t* lb = &Bs2[b * 8192 + w * 1024];                                \
        g2l16(a0 + go, la);          g2l16(a0 + go + 512, la + 512);           \
        g2l16(a1 + go, la + 4096);   g2l16(a1 + go + 512, la + 4608);          \
        g2l16(b0 + go, lb);          g2l16(b0 + go + 512, lb + 512);           \
        g2l16(b1 + go, lb + 4096);   g2l16(b1 + go + 512, lb + 4608);          \
    };                                                                         \
    stage(0); stage(1);                                                        \
    asm volatile("s_waitcnt vmcnt(8)" ::: "memory");                           \
    __builtin_amdgcn_s_barrier();                                              \
    for (int kk = 0; kk < nk; ++kk) {                                          \
        const bf16_t* cA = &As2[(kk & 1) * 8192];                              \
        const bf16_t* cB = &Bs2[(kk & 1) * 8192];                              \
        bf16x8 af0[4], af1[4], bq0[4], bq1[4];                                 \
        _Pragma("unroll")                                                      \
        for (int i = 0; i < 4; ++i) {                                          \
            af0[i] = *(const bf16x8*)(cA + (wm * 4 + i) * 1024 + lane * 8);    \
            af1[i] = *(const bf16x8*)(cA + (wm * 4 + i) * 1024 + 512 + lane * 8); \
            bq0[i] = *(const bf16x8*)(cB + (wn * 4 + i) * 1024 + lane * 8);    \
            bq1[i] = *(const bf16x8*)(cB + (wn * 4 + i) * 1024 + 512 + lane * 8); \
        }                                                                      \
        asm volatile("s_waitcnt lgkmcnt(0)" ::: "memory");                     \
        __builtin_amdgcn_s_barrier();                                          \
        if (kk + 2 < nk) stage(kk + 2);                                        \
        _Pragma("unroll")                                                      \
        for (int i = 0; i < 4; ++i)                                            \
            _Pragma("unroll")                                                  \
            for (int j = 0; j < 4; ++j)                                        \
                acc[i][j] = mfma16(bq0[j], af0[i], acc[i][j]);                 \
        _Pragma("unroll")                                                      \
        for (int i = 0; i < 4; ++i)                                            \
            _Pragma("unroll")                                                  \
            for (int j = 0; j < 4; ++j)                                        \
                acc[i][j] = mfma16(bq1[j], af1[i], acc[i][j]);                 \
        if (kk + 2 < nk) asm volatile("s_waitcnt vmcnt(8)" ::: "memory");      \
        else             asm volatile("s_waitcnt vmcnt(0)" ::: "memory");      \
        __builtin_amdgcn_s_barrier();                                          \
    }

// split-K slab-output GEMM (layer 4)
__global__ __launch_bounds__(256) void k_gemm16(
        const bf16_t* __restrict__ A, const bf16_t* __restrict__ Bt,
        bf16_t* __restrict__ C, int ldc, size_t sstride, int nk) {
    __shared__ __align__(16) bf16_t As2[16384];
    __shared__ __align__(16) bf16_t Bs2[16384];
    int tr0 = blockIdx.y * 8, tc0 = blockIdx.x * 8;
    int kt0 = blockIdx.z * nk * 2;
    int wtmp = threadIdx.x >> 6, ltmp = threadIdx.x & 63;
    const bf16_t* a0 = A + (((size_t)(tr0 + wtmp)     * KTILES + kt0) << 9) + ltmp * 8;
    const bf16_t* a1 = A + (((size_t)(tr0 + wtmp + 4) * KTILES + kt0) << 9) + ltmp * 8;
    const bf16_t* b0 = Bt + (((size_t)(tc0 + wtmp)     * KTILES + kt0) << 9) + ltmp * 8;
    const bf16_t* b1 = Bt + (((size_t)(tc0 + wtmp + 4) * KTILES + kt0) << 9) + ltmp * 8;
    GEMM_PIPE()
    bf16_t* Cz = C + (size_t)blockIdx.z * sstride;
    int orow = lane & 15, ocol = (lane >> 4) * 4;
    size_t row0 = (size_t)blockIdx.y * 128;
    size_t col0 = (size_t)blockIdx.x * 128;
    #pragma unroll
    for (int i = 0; i < 4; ++i) {
        size_t gr = row0 + wm * 64 + i * 16 + orow;
        #pragma unroll
        for (int j = 0; j < 4; ++j) {
            size_t gc = col0 + wn * 64 + j * 16 + ocol;
            bf16x4 v;
            #pragma unroll
            for (int rg = 0; rg < 4; ++rg) v[rg] = (bf16_t)acc[i][j][rg];
            *(bf16x4*)(Cz + gr * (size_t)ldc + gc) = v;
        }
    }
}

// ---- 512-thr 8-wave BK=64 mid-barrier distance-2 pipe (128x128 tile) ----
#define GEMM_PIPE8()                                                           \
    int tid = threadIdx.x, lane = tid & 63, w = tid >> 6;      /* 0..7 */      \
    int wm = w >> 2, wn = w & 3;                                               \
    f32x4 acc[4][2];                                                           \
    _Pragma("unroll")                                                          \
    for (int i = 0; i < 4; ++i)                                                \
        _Pragma("unroll")                                                      \
        for (int j = 0; j < 2; ++j) acc[i][j] = (f32x4){0.f, 0.f, 0.f, 0.f};   \
    auto stage = [&](int kk) {                                                 \
        int b = kk & 1;                                                        \
        size_t go = (size_t)kk * 1024;                                         \
        bf16_t* la = &As2[b * 8192 + w * 1024];                                \
        bf16_t* lb = &Bs2[b * 8192 + w * 1024];                                \
        g2l16(a0 + go, la);   g2l16(a0 + go + 512, la + 512);                  \
        g2l16(b0 + go, lb);   g2l16(b0 + go + 512, lb + 512);                  \
    };                                                                         \
    stage(0); stage(1);                                                        \
    asm volatile("s_waitcnt vmcnt(4)" ::: "memory");                           \
    __builtin_amdgcn_s_barrier();                                              \
    for (int kk = 0; kk < nk; ++kk) {                                          \
        const bf16_t* cA = &As2[(kk & 1) * 8192];                              \
        const bf16_t* cB = &Bs2[(kk & 1) * 8192];                              \
        bf16x8 af0[4], af1[4], bq0[2], bq1[2];                                 \
        _Pragma("unroll")                                                      \
        for (int i = 0; i < 4; ++i) {                                          \
            af0[i] = *(const bf16x8*)(cA + (wm * 4 + i) * 1024 + lane * 8);    \
            af1[i] = *(const bf16x8*)(cA + (wm * 4 + i) * 1024 + 512 + lane * 8); \
        }                                                                      \
        _Pragma("unroll")                                                      \
        for (int j = 0; j < 2; ++j) {                                          \
            bq0[j] = *(const bf16x8*)(cB + (wn * 2 + j) * 1024 + lane * 8);    \
            bq1[j] = *(const bf16x8*)(cB + (wn * 2 + j) * 1024 + 512 + lane * 8); \
        }                                                                      \
        asm volatile("s_waitcnt lgkmcnt(0)" ::: "memory");                     \
        __builtin_amdgcn_s_barrier();                                          \
        if (kk + 2 < nk) stage(kk + 2);                                        \
        _Pragma("unroll")                                                      \
        for (int i = 0; i < 4; ++i)                                            \
            _Pragma("unroll")                                                  \
            for (int j = 0; j < 2; ++j)                                        \
                acc[i][j] = mfma16(bq0[j], af0[i], acc[i][j]);                 \
        _Pragma("unroll")                                                      \
        for (int i = 0; i < 4; ++i)                                            \
            _Pragma("unroll")                                                  \
            for (int j = 0; j < 2; ++j)                                        \
                acc[i][j] = mfma16(bq1[j], af1[i], acc[i][j]);                 \
        if (kk + 2 < nk) asm volatile("s_waitcnt vmcnt(4)" ::: "memory");      \
        else             asm volatile("s_waitcnt vmcnt(0)" ::: "memory");      \
        __builtin_amdgcn_s_barrier();                                          \
    }

// GEMM + fused colmix epilogue (splits=1, M=2n rows, N=2048 cols).
// 8x8 XCD tile-patch swizzle; 512 threads, 8 waves.
__global__ __launch_bounds__(512, 4) void k_gemm16_mix(
        const bf16_t* __restrict__ A, const bf16_t* __restrict__ Bt, int n,
        const float* __restrict__ cus, const float* __restrict__ cui,
        const float* __restrict__ cls, const float* __restrict__ cli,
        const float* __restrict__ bvec,
        bf16_t* __restrict__ Ab2, float* __restrict__ av, int nk) {
    __shared__ __align__(16) bf16_t As2[16384];
    __shared__ __align__(16) bf16_t Bs2[16384];
    __shared__ float asum[4][128];
    int wg = (int)(blockIdx.y * gridDim.x + blockIdx.x);   // 0..511
    int xcd = wg & 7, idx = wg >> 3;                       // 64 blocks/XCD
    int bm = (xcd & 3) * 8 + (idx & 7);                    // 0..31 M-tile
    int bn = (xcd >> 2) * 8 + (idx >> 3);                  // 0..15 N-tile
    int tr0 = bm * 8, tc0 = bn * 8;
    int wtmp = threadIdx.x >> 6, ltmp = threadIdx.x & 63;
    const bf16_t* a0 = A + (((size_t)(tr0 + wtmp) * KTILES) << 9) + ltmp * 8;
    const bf16_t* b0 = Bt + (((size_t)(tc0 + wtmp) * KTILES) << 9) + ltmp * 8;
    GEMM_PIPE8()
    // ---- fused colmix epilogue ----
    size_t row0 = (size_t)bm * 128;
    size_t col0 = (size_t)bn * 128;
    bool isU = (int)row0 < n;            // row0 multiple of 128, n multiple of 128
    const float* ps = isU ? cus : cls;
    const float* ns = isU ? cls : cus;
    const float* yi = isU ? cui : cli;
    const float* zi = isU ? cli : cui;
    int orow = lane & 15, ocol = (lane >> 4) * 4;
    #pragma unroll
    for (int i = 0; i < 4; ++i) {
        int gr = (int)row0 + wm * 64 + i * 16 + orow;
        float ra = 0.f;
        #pragma unroll
        for (int j = 0; j < 2; ++j) {
            int gc = (int)col0 + wn * 32 + j * 16 + ocol;
            f32x4 p0 = *(const f32x4*)(ps + gc);
            f32x4 q0 = *(const f32x4*)(ns + gc);
            f32x4 y0 = *(const f32x4*)(yi + gc);
            f32x4 z0 = *(const f32x4*)(zi + gc);
            f32x4 c0 = *(const f32x4*)(bvec + gc);
            bf16x4 ov;
            #pragma unroll
            for (int rg = 0; rg < 4; ++rg) {
                float v = acc[i][j][rg];
                float pos = fmaxf(v, 0.f), neg = fminf(v, 0.f);
                float mx = pos * p0[rg] + neg * q0[rg];
                ov[rg] = (bf16_t)mx;
                ra += pos * y0[rg] + neg * z0[rg] + mx * c0[rg];
            }
            *(bf16x4*)(Ab2 + swz(gr, gc, KTILES)) = ov;
        }
        ra += __shfl_xor(ra, 16, 64);
        ra += __shfl_xor(ra, 32, 64);
        if (lane < 16) asum[wn][wm * 64 + i * 16 + lane] = ra;
    }
    __syncthreads();
    if (tid < 128)
        atomicAdd(&av[row0 + tid],
                  asum[0][tid] + asum[1][tid] + asum[2][tid] + asum[3][tid]);
}

// GEMM + fused final c0-reduce epilogue, RETILED 64x128 (R8 counters: old
// 128x128/224-block version = 48us, MfmaUtil 10%, 0.875 blocks/CU -> no
// cross-block overlap + 32 idle CUs). New: 448 blocks (1.75/CU), 256 thr /
// 4 waves, LDS 48KB (<=3 blocks/CU by LDS). Wave w: all 64 rows x cols
// [w*32, w*32+32). Stage per wave: A tile (bm*4+w) 2 g2l + B tiles
// (bn*8+2w, +1) 4 g2l = 6 -> vmcnt(6) ladder. 8x7 XCD patch swizzle.
__global__ __launch_bounds__(256) void k_gemm16_red(
        const bf16_t* __restrict__ A, const bf16_t* __restrict__ Bt, int n,
        const float* __restrict__ ubn, const float* __restrict__ lbn,
        float* __restrict__ av, int nk) {
    __shared__ __align__(16) bf16_t As2[8192];    // 2 buf x 4 A-tiles x 1KB
    __shared__ __align__(16) bf16_t Bs2[16384];   // 2 buf x 8 B-tiles x 1KB
    __shared__ float asum[4][64];
    int wg = (int)blockIdx.x;                     // 0..447
    int xcd = wg & 7, idx = wg >> 3;              // 56 blocks/XCD
    int bm = xcd * 8 + idx / 7;                   // 0..63 M-tile (64 rows)
    int bn = idx % 7;                             // 0..6 N-tile (128 cols)
    int tid = threadIdx.x, lane = tid & 63, w = tid >> 6;
    const bf16_t* aw  = A  + (((size_t)(bm * 4 + w)      * KTILES) << 9) + lane * 8;
    const bf16_t* bw0 = Bt + (((size_t)(bn * 8 + 2 * w)  * KTILES) << 9) + lane * 8;
    const bf16_t* bw1 = Bt + (((size_t)(bn * 8 + 2 * w + 1) * KTILES) << 9) + lane * 8;
    f32x4 acc[4][2];
    #pragma unroll
    for (int i = 0; i < 4; ++i)
        #pragma unroll
        for (int j = 0; j < 2; ++j) acc[i][j] = (f32x4){0.f, 0.f, 0.f, 0.f};
    auto stage = [&](int kk) {
        int b = kk & 1;
        size_t go = (size_t)kk * 1024;
        bf16_t* la = &As2[b * 4096 + w * 1024];
        bf16_t* lb = &Bs2[b * 8192 + 2 * w * 1024];
        g2l16(aw + go, la);         g2l16(aw + go + 512, la + 512);
        g2l16(bw0 + go, lb);        g2l16(bw0 + go + 512, lb + 512);
        g2l16(bw1 + go, lb + 1024); g2l16(bw1 + go + 512, lb + 1536);
    };
    stage(0); stage(1);
    asm volatile("s_waitcnt vmcnt(6)" ::: "memory");
    __builtin_amdgcn_s_barrier();
    for (int kk = 0; kk < nk; ++kk) {
        const bf16_t* cA = &As2[(kk & 1) * 4096];
        const bf16_t* cB = &Bs2[(kk & 1) * 8192];
        bf16x8 af0[4], af1[4], bq0[2], bq1[2];
        #pragma unroll
        for (int i = 0; i < 4; ++i) {
            af0[i] = *(const bf16x8*)(cA + i * 1024 + lane * 8);
            af1[i] = *(const bf16x8*)(cA + i * 1024 + 512 + lane * 8);
        }
        #pragma unroll
        for (int j = 0; j < 2; ++j) {
            bq0[j] = *(const bf16x8*)(cB + (2 * w + j) * 1024 + lane * 8);
            bq1[j] = *(const bf16x8*)(cB + (2 * w + j) * 1024 + 512 + lane * 8);
        }
        asm volatile("s_waitcnt lgkmcnt(0)" ::: "memory");
        __builtin_amdgcn_s_barrier();
        if (kk + 2 < nk) stage(kk + 2);
        #pragma unroll
        for (int i = 0; i < 4; ++i)
            #pragma unroll
            for (int j = 0; j < 2; ++j)
                acc[i][j] = mfma16(bq0[j], af0[i], acc[i][j]);
        #pragma unroll
        for (int i = 0; i < 4; ++i)
            #pragma unroll
            for (int j = 0; j < 2; ++j)
                acc[i][j] = mfma16(bq1[j], af1[i], acc[i][j]);
        if (kk + 2 < nk) asm volatile("s_waitcnt vmcnt(6)" ::: "memory");
        else             asm volatile("s_waitcnt vmcnt(0)" ::: "memory");
        __builtin_amdgcn_s_barrier();
    }
    // ---- fused c0-reduce epilogue ----
    size_t row0 = (size_t)bm * 64;
    size_t col0 = (size_t)bn * 128;
    bool isU = (int)row0 < n;   // row0 multiple of 64; n multiple of 64
    const float* p = isU ? ubn : lbn;
    const float* q = isU ? lbn : ubn;
    int ocol = (lane >> 4) * 4;
    #pragma unroll
    for (int i = 0; i < 4; ++i) {
        float ra = 0.f;
        #pragma unroll
        for (int j = 0; j < 2; ++j) {
            int gc = (int)col0 + w * 32 + j * 16 + ocol;
            f32x4 p0 = *(const f32x4*)(p + gc);
            f32x4 q0 = *(const f32x4*)(q + gc);
            #pragma unroll
            for (int rg = 0; rg < 4; ++rg) {
                float v = acc[i][j][rg];
                ra += fmaxf(v, 0.f) * p0[rg] + fminf(v, 0.f) * q0[rg];
            }
        }
        ra += __shfl_xor(ra, 16, 64);
        ra += __shfl_xor(ra, 32, 64);
        if (lane < 16) asum[w][i * 16 + lane] = ra;
    }
    __syncthreads();
    if (tid < 64)
        atomicAdd(&av[row0 + tid],
                  asum[0][tid] + asum[1][tid] + asum[2][tid] + asum[3][tid]);
}

// ---------------- host launch ----------------

extern "C" void kernel_launch(void* const* d_in, const int* in_sizes, int n_in,
                              void* d_out, int out_size, void* d_ws, size_t ws_size,
                              hipStream_t stream) {
    (void)in_sizes; (void)n_in; (void)out_size; (void)ws_size;
    const float* x   = (const float*)d_in[0];
    const float* eps = (const float*)d_in[1];
    const float* W1  = (const float*)d_in[2];
    const float* B1  = (const float*)d_in[3];
    const float* W2  = (const float*)d_in[4];
    const float* B2  = (const float*)d_in[5];
    const float* W3  = (const float*)d_in[6];
    const float* B3  = (const float*)d_in[7];
    const float* W4  = (const float*)d_in[8];
    const float* B4  = (const float*)d_in[9];
    float* out = (float*)d_out;

    const int H = 2048, DIN = 784, DOUT = 10;
    const int NP1 = 896;           // DIN padded to x128
    const int MP4 = 128;           // layer-4 row pad

    float* ws = (float*)d_ws;
    size_t off = 0;
    auto alloc = [&](size_t nf) -> float* {
        float* p = ws + off;
        off += (nf + 3) & ~(size_t)3;
        return p;
    };
    float* ubn = alloc(NP1);
    float* lbn = alloc(NP1);
    float* us1 = alloc(H); float* ui1 = alloc(H); float* ls1 = alloc(H); float* li1 = alloc(H);
    float* pU1 = alloc(H); float* pL1 = alloc(H);
    float* iU2 = alloc(H); float* iL2 = alloc(H);
    float* us2 = alloc(H); float* ui2 = alloc(H); float* ls2 = alloc(H); float* li2 = alloc(H);
    float* pU2 = alloc(H); float* pL2 = alloc(H);
    float* iU3 = alloc(H); float* iL3 = alloc(H);
    float* us3 = alloc(H); float* ui3 = alloc(H); float* ls3 = alloc(H); float* li3 = alloc(H);
    float* pU3 = alloc(H); float* pL3 = alloc(H);
    float* iU4 = alloc(32); float* iL4 = alloc(32);
    float* av  = alloc(2 * H);
    bf16_t* Ab  = (bf16_t*)alloc((size_t)2 * H * H / 2);       // 4096 x 2048 bf16 swz
    bf16_t* Ab2 = (bf16_t*)alloc((size_t)2 * H * H / 2);       // second operand buffer
    bf16_t* W1t = (bf16_t*)alloc((size_t)NP1 * H / 2);
    bf16_t* W2t = (bf16_t*)alloc((size_t)H * H / 2);
    bf16_t* W3t = (bf16_t*)alloc((size_t)H * H / 2);
    bf16_t* Cs  = (bf16_t*)alloc((size_t)16 * MP4 * H / 2);    // L4 split-16 slabs (bf16)

    dim3 blk(256);

    // weight transpose/convert/swizzle (merged) + input bounds side-block
    k_wT3<<<dim3(32, 32, 3), blk, 0, stream>>>(W1, W2, W3, W1t, W2t, W3t,
                                               x, eps, ubn, lbn);

    size_t ss4H = (size_t)MP4 * H;          // layer-4 N=H slab
    size_t ss4N = (size_t)MP4 * NP1;        // layer-4 N=NP1 slab

    // ======== Layer 1 (fused interval + spu) ========
    k_interval_spu<<<dim3(H / 4), blk, 0, stream>>>(W1, B1, ubn, lbn, DIN, H,
        us1, ui1, ls1, li1, pU1, pL1);

    // ======== Layer 2 ========
    k_prep16<<<dim3(2 * H / 16), blk, 0, stream>>>(W2, B2, H,
        us1, ui1, ls1, li1, B1, pU1, pL1, Ab, av, iU2, iL2);
    k_gemm16_red<<<dim3(448), blk, 0, stream>>>(Ab, W1t, H,
        ubn, lbn, av, KTILES / 2);
    k_spu2<<<dim3(H / 64), dim3(64), 0, stream>>>(iU2, iL2, av, H,
        us2, ui2, ls2, li2, pU2, pL2);

    // ======== Layer 3 ========
    k_prep16<<<dim3(2 * H / 16), blk, 0, stream>>>(W3, B3, H,
        us2, ui2, ls2, li2, B2, pU2, pL2, Ab, av, iU3, iL3);
    k_gemm16_mix<<<dim3(2 * H / 128, H / 128), dim3(512), 0, stream>>>(Ab, W2t, H,
        us1, ui1, ls1, li1, B1, Ab2, av, KTILES / 2);
    k_gemm16_red<<<dim3(448), blk, 0, stream>>>(Ab2, W1t, H,
        ubn, lbn, av, KTILES / 2);
    k_spu2<<<dim3(H / 64), dim3(64), 0, stream>>>(iU3, iL3, av, H,
        us3, ui3, ls3, li3, pU3, pL3);

    // ======== Layer 4 (M = 20 padded to 128, split-K 16, colmix k-split 8) ========
    k_prep16<<<dim3(MP4 / 16), blk, 0, stream>>>(W4, B4, DOUT,
        us3, ui3, ls3, li3, B3, pU3, pL3, Ab, av, iU4, iL4);
    k_gemm16<<<dim3(H / 128, MP4 / 128, 16), blk, 0, stream>>>(Ab, W3t, Cs, H, ss4H, 2);
    k_colmix16<<<dim3(MP4 / 16, 8), blk, 0, stream>>>(Cs, H, 16, ss4H, DOUT, KTILES / 8,
        us2, ui2, ls2, li2, B2, Ab2, av);
    k_gemm16<<<dim3(H / 128, MP4 / 128, 16), blk, 0, stream>>>(Ab2, W2t, Cs, H, ss4H, 2);
    k_colmix16<<<dim3(MP4 / 16, 8), blk, 0, stream>>>(Cs, H, 16, ss4H, DOUT, KTILES / 8,
        us1, ui1, ls1, li1, B1, Ab, av);
    k_gemm16<<<dim3(NP1 / 128, MP4 / 128, 16), blk, 0, stream>>>(Ab, W1t, Cs, NP1, ss4N, 2);
    k_reduce16f<<<dim3(1), dim3(640), 0, stream>>>(Cs, NP1, DIN, DOUT, 16, ss4N,
        av, ubn, lbn, iL4, out);
}

// Round 10
// 311.498 us; speedup vs baseline: 1.1158x; 1.0335x over previous
//
#include <hip/hip_runtime.h>
#include <cstdint>
#include <cstddef>

#define MEAN_C 0.1307f
#define SIGMA_C 0.3081f
#define SIG_SCALE_C 5.0f

typedef __bf16 bf16_t;
typedef __bf16 bf16x8 __attribute__((ext_vector_type(8)));
typedef __bf16 bf16x4 __attribute__((ext_vector_type(4)));
typedef float f32x4 __attribute__((ext_vector_type(4)));

__device__ __forceinline__ f32x4 mfma16(bf16x8 a, bf16x8 b, f32x4 c) {
    return __builtin_amdgcn_mfma_f32_16x16x32_bf16(a, b, c, 0, 0, 0);
}

typedef const __attribute__((address_space(1))) void* gvp;
typedef __attribute__((address_space(3))) void* lvp;
__device__ __forceinline__ void g2l16(const void* g, void* l) {
    __builtin_amdgcn_global_load_lds((gvp)g, (lvp)l, 16, 0, 0);
}

// swizzled bf16 operand layout: 16x32 tiles (1KB); chunk index within tile =
// lane = (k-chunk)*16 + row  (16B each). offset(r,k), K = ktiles*32.
__device__ __forceinline__ size_t swz(int r, int k, int ktiles) {
    return (((size_t)(r >> 4) * ktiles + (k >> 5)) << 9)
         + (((k >> 3) & 3) << 7) + ((r & 15) << 3) + (k & 7);
}

#define KTILES 64   // K = 2048

// ---------------- device helpers ----------------

__device__ __forceinline__ float sigmoidf_(float x) {
    if (x >= 0.f) { float e = __expf(-x); return 1.f / (1.f + e); }
    float e = __expf(x); return e / (1.f + e);
}

__device__ __forceinline__ float spu_f(float x) {
    return (x >= 0.f) ? (x * x - 0.5f) : (sigmoidf_(-x) - 1.f);
}

__device__ __forceinline__ float wave_sum(float a) {
    #pragma unroll
    for (int o = 32; o > 0; o >>= 1) a += __shfl_xor(a, o, 64);
    return a;
}

// full analyze_spu for one neuron i, given clamp bounds (iUi, iLi) and the
// back-substituted chain values vU (upper row) / vL (lower row).
__device__ __forceinline__ void spu_body(int i, int n,
        float iUi, float iLi, float vU, float vL,
        float* __restrict__ us, float* __restrict__ ui,
        float* __restrict__ ls, float* __restrict__ li,
        float* __restrict__ pU, float* __restrict__ pL) {
    float ux = fminf(iUi, vU);
    float lx = fmaxf(iLi, vL);
    float uy = spu_f(ux), ly = spu_f(lx);
    float new_ub = fmaxf(uy, ly);
    float sj = (uy - ly) / (ux - lx);
    float ij = uy - sj * ux;
    bool right = lx > 0.f;
    bool left = ux <= 0.f;
    float mid = 0.5f * (ux + lx);
    float sp = 2.f * mid, ip = -mid * mid - 0.5f;
    float sm = sigmoidf_(mid);
    float ssm = -sm * (1.f - sm);
    float ism = -sm - ssm * mid;
    bool crossing = (!left) && (!right);
    float new_lb = crossing ? -0.5f : fminf(uy, ly);
    float spu_s = 2.f * ux, ipu = -ux * ux - 0.5f;
    float limit = spu_s * lx + ipu;
    float clm = (fabsf(lx) > ux) ? 1.f : 0.f;
    float clp = sigmoidf_((clm - 0.5f) * 2.f * SIG_SCALE_C) * (ly - limit) + limit;
    bool ptm = clp < -0.5f;
    float D = 4.f * lx * lx - 4.f * clp - 2.f;
    float x2 = (2.f * lx + sqrtf(fmaxf(D, 0.f))) * 0.5f;
    float spt = 2.f * x2, ipt = -x2 * x2 - 0.5f;
    float sjn = (clp + 0.5f) / lx;
    float ijn = -0.5f;
    float s_cl = ptm ? spt : sjn;
    float i_cl = ptm ? ipt : ijn;
    float sl = sigmoidf_(lx);
    float ssl = -sl * (1.f - sl);
    float isl = -sl - ssl * lx;
    float stv = ssl * ux + isl - uy;
    float Lb = lx, Rb = 0.f;
    #pragma unroll
    for (int t = 0; t < 10; ++t) {
        float mm = 0.5f * (Lb + Rb);
        float smm = sigmoidf_(mm);
        float sms = -smm * (1.f - smm);
        float smi = -smm - sms * mm;
        bool mask = (sms * ux + smi - uy) > 0.f;
        Lb = mask ? mm : Lb;
        Rb = mask ? Rb : mm;
    }
    float scp = sigmoidf_(-SIG_SCALE_C) * (Lb - lx) + lx;
    float sc = sigmoidf_(scp);
    float ssc = -sc * (1.f - sc);
    float isc = -sc - ssc * scp;
    bool up = stv > 0.f;
    float s_cu = up ? ssc : sj;
    float i_cu = up ? isc : ij;
    float usv, uiv, lsv, liv;
    if (right)      { usv = sj;   uiv = ij;   lsv = sp;   liv = ip;   }
    else if (left)  { usv = ssm;  uiv = ism;  lsv = sj;   liv = ij;   }
    else            { usv = s_cu; uiv = i_cu; lsv = s_cl; liv = i_cl; }
    us[i] = usv; ui[i] = uiv; ls[i] = lsv; li[i] = liv;
    float vu = (usv >= 0.f) ? vU : vL;
    float vl = (lsv >= 0.f) ? vL : vU;
    pU[i] = fminf(new_ub, usv * vu + uiv);
    pL[i] = fmaxf(new_lb, lsv * vl + liv);
}

// ---------------- small kernels ----------------

// fused layer-1 interval bound + analyze_spu
__global__ __launch_bounds__(256) void k_interval_spu(
        const float* __restrict__ W, const float* __restrict__ b,
        const float* __restrict__ U, const float* __restrict__ L,
        int m, int n,
        float* __restrict__ us, float* __restrict__ ui,
        float* __restrict__ ls, float* __restrict__ li,
        float* __restrict__ pU, float* __restrict__ pL) {
    int r = (blockIdx.x << 2) + (threadIdx.x >> 6);
    if (r >= n) return;
    int lane = threadIdx.x & 63;
    const f32x4* Wr = (const f32x4*)(W + (size_t)r * m);
    const f32x4* U4 = (const f32x4*)U;
    const f32x4* L4 = (const f32x4*)L;
    int nf4 = m >> 2;
    float au = 0.f, al = 0.f;
    for (int j = lane; j < nf4; j += 64) {
        f32x4 wv = Wr[j], uu = U4[j], ll = L4[j];
        #pragma unroll
        for (int u = 0; u < 4; ++u) {
            float w = wv[u];
            float hi = (w > 0.f) ? uu[u] : ll[u];
            float lo2 = (w > 0.f) ? ll[u] : uu[u];
            au = fmaf(w, hi, au);
            al = fmaf(w, lo2, al);
        }
    }
    au = wave_sum(au); al = wave_sum(al);
    if (lane == 0) {
        float vU = au + b[r], vL = al + b[r];
        spu_body(r, n, vU, vL, vU, vL, us, ui, ls, li, pU, pL);
    }
}

// standalone spu (layers 2/3)
__global__ void k_spu2(const float* __restrict__ iU, const float* __restrict__ iL,
                       const float* __restrict__ vraw, int n,
                       float* __restrict__ us, float* __restrict__ ui,
                       float* __restrict__ ls, float* __restrict__ li,
                       float* __restrict__ pU, float* __restrict__ pL) {
    int i = blockIdx.x * blockDim.x + threadIdx.x;
    if (i >= n) return;
    spu_body(i, n, iU[i], iL[i], vraw[i], vraw[n + i], us, ui, ls, li, pU, pL);
}

// ---------------- bf16 producers ----------------

// merged transpose/convert/swizzle of W1,W2,W3 + input-bounds side block.
__global__ __launch_bounds__(256) void k_wT3(
        const float* __restrict__ W1, const float* __restrict__ W2,
        const float* __restrict__ W3,
        bf16_t* __restrict__ W1t, bf16_t* __restrict__ W2t, bf16_t* __restrict__ W3t,
        const float* __restrict__ x, const float* __restrict__ eps,
        float* __restrict__ ubn, float* __restrict__ lbn) {
    __shared__ bf16_t t[64 * 65];
    int z = blockIdx.z;
    const float* W; int N, ldw; bf16_t* Wt;
    if (z == 0)      { W = W2; N = 2048; ldw = 2048; Wt = W2t; }
    else if (z == 1) { W = W3; N = 2048; ldw = 2048; Wt = W3t; }
    else {
        W = W1; N = 784; ldw = 784; Wt = W1t;
        if (blockIdx.y >= 14) {
            if (blockIdx.y == 14 && blockIdx.x == 0) {
                for (int i = threadIdx.x; i < 896; i += 256) {
                    if (i >= 784) { ubn[i] = 0.f; lbn[i] = 0.f; }
                    else {
                        float e = eps[0];
                        float ub = fminf(x[i] + e, 1.f);
                        float lb = fmaxf(x[i] - e, 0.f);
                        ubn[i] = (ub - MEAN_C) / SIGMA_C;
                        lbn[i] = (lb - MEAN_C) / SIGMA_C;
                    }
                }
            }
            return;
        }
    }
    int k0 = blockIdx.x * 64, n0 = blockIdx.y * 64;
    int tid = threadIdx.x;
    int rg = tid >> 4;            // 0..15 row sub-index
    int cg = (tid & 15) * 4;      // column start (f32x4)
    bool fast = (n0 + 64 <= N);
    #pragma unroll
    for (int it = 0; it < 4; ++it) {
        int row = it * 16 + rg;   // local k
        const float* Wr = W + (size_t)(k0 + row) * ldw + n0 + cg;
        float v0, v1, v2, v3;
        if (fast) {
            f32x4 vv = *(const f32x4*)Wr;
            v0 = vv[0]; v1 = vv[1]; v2 = vv[2]; v3 = vv[3];
        } else {
            v0 = (n0 + cg + 0 < N) ? Wr[0] : 0.f;
            v1 = (n0 + cg + 1 < N) ? Wr[1] : 0.f;
            v2 = (n0 + cg + 2 < N) ? Wr[2] : 0.f;
            v3 = (n0 + cg + 3 < N) ? Wr[3] : 0.f;
        }
        t[(cg + 0) * 65 + row] = (bf16_t)v0;
        t[(cg + 1) * 65 + row] = (bf16_t)v1;
        t[(cg + 2) * 65 + row] = (bf16_t)v2;
        t[(cg + 3) * 65 + row] = (bf16_t)v3;
    }
    __syncthreads();
    #pragma unroll
    for (int p = 0; p < 2; ++p) {
        int c = tid + p * 256;
        int lr = c & 63, lq = c >> 6;
        bf16x8 v;
        #pragma unroll
        for (int u = 0; u < 8; ++u) v[u] = t[lr * 65 + lq * 8 + u];
        *(bf16x8*)(Wt + swz(n0 + lr, k0 + lq * 8, KTILES)) = v;
    }
}

// prep (fused interval-affine)
__global__ __launch_bounds__(256) void k_prep16(
        const float* __restrict__ W, const float* __restrict__ b, int n,
        const float* __restrict__ cus, const float* __restrict__ cui,
        const float* __restrict__ cls, const float* __restrict__ cli,
        const float* __restrict__ bvec,
        const float* __restrict__ U, const float* __restrict__ L,
        bf16_t* __restrict__ Ab, float* __restrict__ av,
        float* __restrict__ iU, float* __restrict__ iL) {
    int rt = blockIdx.x;
    int tid = threadIdx.x, lane = tid & 63, wid = tid >> 6;
    int mrow = lane & 15, q = lane >> 4;
    int r = rt * 16 + mrow;
    bool act = r < 2 * n;
    bool isU = r < n;
    int i = act ? (isU ? r : r - n) : 0;
    float gate = act ? 1.f : 0.f;
    const float* Wr = W + (size_t)i * 2048;
    const float* ps = isU ? cus : cls;
    const float* ns = isU ? cls : cus;
    const float* yi = isU ? cui : cli;
    const float* zi = isU ? cli : cui;
    const float* hi = isU ? U : L;
    const float* lo = isU ? L : U;
    float a = 0.f, a2 = 0.f;
    bf16_t* Abase = Ab + ((size_t)rt * KTILES) * 512 + lane * 8;
    for (int kt = wid; kt < KTILES; kt += 4) {
        int k0 = kt * 32 + q * 8;
        bf16x8 ov;
        #pragma unroll
        for (int h = 0; h < 2; ++h) {
            int kb = k0 + 4 * h;
            f32x4 wv = *(const f32x4*)(Wr + kb);
            f32x4 p0 = *(const f32x4*)(ps + kb);
            f32x4 q0 = *(const f32x4*)(ns + kb);
            f32x4 y0 = *(const f32x4*)(yi + kb);
            f32x4 z0 = *(const f32x4*)(zi + kb);
            f32x4 c0 = *(const f32x4*)(bvec + kb);
            f32x4 h0 = *(const f32x4*)(hi + kb);
            f32x4 l0 = *(const f32x4*)(lo + kb);
            #pragma unroll
            for (int u = 0; u < 4; ++u) {
                float w = gate * wv[u];
                float pos = fmaxf(w, 0.f), neg = fminf(w, 0.f);
                float mx = pos * p0[u] + neg * q0[u];
                ov[4 * h + u] = (bf16_t)mx;
                a += pos * y0[u] + neg * z0[u] + mx * c0[u];
                a2 += pos * h0[u] + neg * l0[u];   // interval dot
            }
        }
        *(bf16x8*)(Abase + (size_t)kt * 512) = ov;
    }
    a += __shfl_xor(a, 16, 64);  a += __shfl_xor(a, 32, 64);
    a2 += __shfl_xor(a2, 16, 64); a2 += __shfl_xor(a2, 32, 64);
    __shared__ float sh[2][4][16];
    if (lane < 16) { sh[0][wid][lane] = a; sh[1][wid][lane] = a2; }
    __syncthreads();
    if (tid < 16) {
        int r2 = rt * 16 + tid;
        float ta = sh[0][0][tid] + sh[0][1][tid] + sh[0][2][tid] + sh[0][3][tid];
        float tb = sh[1][0][tid] + sh[1][1][tid] + sh[1][2][tid] + sh[1][3][tid];
        if (r2 < 2 * n) {
            bool isU2 = r2 < n;
            int i2 = isU2 ? r2 : r2 - n;
            av[r2] = ta + b[i2];
            if (isU2) iU[i2] = tb + b[i2];
            else      iL[i2] = tb + b[i2];
        } else {
            av[r2] = 0.f;
        }
    }
}

// colmix (layer-4 small-M chains): bf16 split slabs -> swizzled bf16 Ab
__global__ __launch_bounds__(256) void k_colmix16(
        const bf16_t* __restrict__ Cb, int ldc, int splits, size_t sstride, int n,
        int tpb,
        const float* __restrict__ cus, const float* __restrict__ cui,
        const float* __restrict__ cls, const float* __restrict__ cli,
        const float* __restrict__ bvec,
        bf16_t* __restrict__ Ab, float* __restrict__ av) {
    int rt = blockIdx.x;
    int kt0 = blockIdx.y * tpb;
    int tid = threadIdx.x, lane = tid & 63, wid = tid >> 6;
    int mrow = lane & 15, q = lane >> 4;
    int r = rt * 16 + mrow;
    bool isU = r < n;
    const bf16_t* Cr = Cb + (size_t)r * ldc;
    const float* ps = isU ? cus : cls;
    const float* ns = isU ? cls : cus;
    const float* yi = isU ? cui : cli;
    const float* zi = isU ? cli : cui;
    float a = 0.f;
    bf16_t* Abase = Ab + ((size_t)rt * KTILES) * 512 + lane * 8;
    for (int kt = kt0 + wid; kt < kt0 + tpb; kt += 4) {
        int k0 = kt * 32 + q * 8;
        float wsum[8] = {0.f, 0.f, 0.f, 0.f, 0.f, 0.f, 0.f, 0.f};
        for (int s = 0; s < splits; ++s) {
            bf16x8 v = *(const bf16x8*)(Cr + s * sstride + k0);
            #pragma unroll
            for (int u = 0; u < 8; ++u) wsum[u] += (float)v[u];
        }
        f32x4 p0 = *(const f32x4*)(ps + k0), p1 = *(const f32x4*)(ps + k0 + 4);
        f32x4 q0 = *(const f32x4*)(ns + k0), q1 = *(const f32x4*)(ns + k0 + 4);
        f32x4 y0 = *(const f32x4*)(yi + k0), y1 = *(const f32x4*)(yi + k0 + 4);
        f32x4 z0 = *(const f32x4*)(zi + k0), z1 = *(const f32x4*)(zi + k0 + 4);
        f32x4 c0 = *(const f32x4*)(bvec + k0), c1 = *(const f32x4*)(bvec + k0 + 4);
        bf16x8 ov;
        #pragma unroll
        for (int u = 0; u < 4; ++u) {
            float w = wsum[u];
            float pos = fmaxf(w, 0.f), neg = fminf(w, 0.f);
            float mx = pos * p0[u] + neg * q0[u];
            ov[u] = (bf16_t)mx;
            a += pos * y0[u] + neg * z0[u] + mx * c0[u];
        }
        #pragma unroll
        for (int u = 0; u < 4; ++u) {
            float w = wsum[4 + u];
            float pos = fmaxf(w, 0.f), neg = fminf(w, 0.f);
            float mx = pos * p1[u] + neg * q1[u];
            ov[4 + u] = (bf16_t)mx;
            a += pos * y1[u] + neg * z1[u] + mx * c1[u];
        }
        *(bf16x8*)(Abase + (size_t)kt * 512) = ov;
    }
    a += __shfl_xor(a, 16, 64);
    a += __shfl_xor(a, 32, 64);
    __shared__ float sh[4][16];
    if (lane < 16) sh[wid][lane] = a;
    __syncthreads();
    if (tid < 16) {
        float tot = sh[0][tid] + sh[1][tid] + sh[2][tid] + sh[3][tid];
        atomicAdd(&av[rt * 16 + tid], tot);
    }
}

// final c0 step + min, fused, single block of 10 waves (one wave per L row).
__global__ __launch_bounds__(640) void k_reduce16f(
        const bf16_t* __restrict__ Cb, int ldc, int m, int n,
        int splits, size_t sstride,
        const float* __restrict__ av,
        const float* __restrict__ ubn, const float* __restrict__ lbn,
        const float* __restrict__ iL,
        float* __restrict__ out) {
    __shared__ float sbl[16];
    int tid = threadIdx.x, lane = tid & 63, wv = tid >> 6;   // 10 waves
    int nch = m >> 3;   // m % 8 == 0
    int i = wv;          // 0..9 == DOUT rows
    int r = n + i;       // L rows only
    const bf16_t* Cr = Cb + (size_t)r * ldc;
    const float* p = lbn;
    const float* q = ubn;
    float a = 0.f;
    for (int c = lane; c < nch; c += 64) {
        float wsum[8] = {0.f, 0.f, 0.f, 0.f, 0.f, 0.f, 0.f, 0.f};
        for (int s = 0; s < splits; ++s) {
            bf16x8 v = *(const bf16x8*)(Cr + s * sstride + c * 8);
            #pragma unroll
            for (int u = 0; u < 8; ++u) wsum[u] += (float)v[u];
        }
        f32x4 p0 = *(const f32x4*)(p + c * 8), p1 = *(const f32x4*)(p + c * 8 + 4);
        f32x4 q0 = *(const f32x4*)(q + c * 8), q1 = *(const f32x4*)(q + c * 8 + 4);
        #pragma unroll
        for (int u = 0; u < 4; ++u) {
            a += fmaxf(wsum[u], 0.f) * p0[u] + fminf(wsum[u], 0.f) * q0[u];
            a += fmaxf(wsum[4 + u], 0.f) * p1[u] + fminf(wsum[4 + u], 0.f) * q1[u];
        }
    }
    a = wave_sum(a);
    if (lane == 0) sbl[i] = fmaxf(iL[i], a + av[r]);
    __syncthreads();
    if (tid < 64) {
        float v = 3.4e38f;
        for (int j = lane; j < n; j += 64) v = fminf(v, sbl[j]);
        #pragma unroll
        for (int o = 32; o > 0; o >>= 1) v = fminf(v, __shfl_down(v, o, 64));
        if (lane == 0) out[0] = v;
    }
}

// ---- L4 small-M GEMM: 32x128 tile, 256 thr / 4 waves, split-K slabs ----
// R9 lesson: L4 at MP4=128 wastes 6.4x on row padding (M=20 real). MP4=32
// quarters A-read + C-write + colmix traffic. Same mid-barrier distance-2
// counted-vmcnt pipe; wave w stages A chunk w (rt=w>>1,h=w&1) + its own two
// B col-tiles (2w,2w+1) = 5 g2l/stage -> vmcnt(5) ladder. acc[2][2].
__global__ __launch_bounds__(256) void k_gemm16s(
        const bf16_t* __restrict__ A, const bf16_t* __restrict__ Bt,
        bf16_t* __restrict__ C, int ldc, size_t sstride, int nk) {
    __shared__ __align__(16) bf16_t As2[8192];    // 2 buf x 4KB (32 rows x BK64)
    __shared__ __align__(16) bf16_t Bs2[32768];   // 2 buf x 16KB (128 cols x BK64)
    int bn = blockIdx.x;
    int kt0 = blockIdx.z * nk * 2;
    int tid = threadIdx.x, lane = tid & 63, w = tid >> 6;
    const bf16_t* aw = A +
        (((size_t)(w >> 1) * KTILES + kt0 + (w & 1)) << 9) + lane * 8;
    const bf16_t* bt0 = Bt +
        (((size_t)(bn * 8 + 2 * w) * KTILES + kt0) << 9) + lane * 8;
    const bf16_t* bt1 = Bt +
        (((size_t)(bn * 8 + 2 * w + 1) * KTILES + kt0) << 9) + lane * 8;
    f32x4 acc[2][2];
    #pragma unroll
    for (int i = 0; i < 2; ++i)
        #pragma unroll
        for (int j = 0; j < 2; ++j) acc[i][j] = (f32x4){0.f, 0.f, 0.f, 0.f};
    auto stage = [&](int kk) {
        int b = kk & 1;
        size_t go = (size_t)kk * 1024;
        g2l16(aw + go,        &As2[b * 4096 + w * 1024]);
        g2l16(bt0 + go,       &Bs2[b * 16384 + (4 * w + 0) * 1024]);
        g2l16(bt0 + go + 512, &Bs2[b * 16384 + (4 * w + 1) * 1024]);
        g2l16(bt1 + go,       &Bs2[b * 16384 + (4 * w + 2) * 1024]);
        g2l16(bt1 + go + 512, &Bs2[b * 16384 + (4 * w + 3) * 1024]);
    };
    stage(0); stage(1);
    asm volatile("s_waitcnt vmcnt(5)" ::: "memory");
    __builtin_amdgcn_s_barrier();
    for (int kk = 0; kk < nk; ++kk) {
        const bf16_t* cA = &As2[(kk & 1) * 4096];
        const bf16_t* cB = &Bs2[(kk & 1) * 16384];
        bf16x8 af[2][2], bq[2][2];
        #pragma unroll
        for (int i = 0; i < 2; ++i)
            #pragma unroll
            for (int h = 0; h < 2; ++h) {
                af[i][h] = *(const bf16x8*)(cA + (i * 2 + h) * 1024 + lane * 8);
                bq[i][h] = *(const bf16x8*)(cB + (4 * w + i * 2 + h) * 1024 + lane * 8);
            }
        asm volatile("s_waitcnt lgkmcnt(0)" ::: "memory");
        __builtin_amdgcn_s_barrier();
        if (kk + 2 < nk) stage(kk + 2);
        #pragma unroll
        for (int h = 0; h < 2; ++h)
            #pragma unroll
            for (int i = 0; i < 2; ++i)
                #pragma unroll
                for (int j = 0; j < 2; ++j)
                    acc[i][j] = mfma16(bq[j][h], af[i][h], acc[i][j]);
        if (kk + 2 < nk) asm volatile("s_waitcnt vmcnt(5)" ::: "memory");
        else             asm volatile("s_waitcnt vmcnt(0)" ::: "memory");
        __builtin_amdgcn_s_barrier();
    }
    bf16_t* Cz = C + (size_t)blockIdx.z * sstride;
    int orow = lane & 15, ocol = (lane >> 4) * 4;
    #pragma unroll
    for (int i = 0; i < 2; ++i) {
        int gr = i * 16 + orow;
        #pragma unroll
        for (int j = 0; j < 2; ++j) {
            int gc = bn * 128 + w * 32 + j * 16 + ocol;
            bf16x4 v;
            #pragma unroll
            for (int rg = 0; rg < 4; ++rg) v[rg] = (bf16_t)acc[i][j][rg];
            *(bf16x4*)(Cz + (size_t)gr * ldc + gc) = v;
        }
    }
}

// ---- 512-thr 8-wave BK=64 mid-barrier distance-2 pipe (128x128 tile) ----
#define GEMM_PIPE8()                                                           \
    int tid = threadIdx.x, lane = tid & 63, w = tid >> 6;      /* 0..7 */      \
    int wm = w >> 2, wn = w & 3;                                               \
    f32x4 acc[4][2];                                                           \
    _Pragma("unroll")                                                          \
    for (int i = 0; i < 4; ++i)                                                \
        _Pragma("unroll")                                                      \
        for (int j = 0; j < 2; ++j) acc[i][j] = (f32x4){0.f, 0.f, 0.f, 0.f};   \
    auto stage = [&](int kk) {                                                 \
        int b = kk & 1;                                                        \
        size_t go = (size_t)kk * 1024;                                         \
        bf16_t* la = &As2[b * 8192 + w * 1024];                                \
        bf16_t* lb = &Bs2[b * 8192 + w * 1024];                                \
        g2l16(a0 + go, la);   g2l16(a0 + go + 512, la + 512);                  \
        g2l16(b0 + go, lb);   g2l16(b0 + go + 512, lb + 512);                  \
    };                                                                         \
    stage(0); stage(1);                                                        \
    asm volatile("s_waitcnt vmcnt(4)" ::: "memory");                           \
    __builtin_amdgcn_s_barrier();                                              \
    for (int kk = 0; kk < nk; ++kk) {                                          \
        const bf16_t* cA = &As2[(kk & 1) * 8192];                              \
        const bf16_t* cB = &Bs2[(kk & 1) * 8192];                              \
        bf16x8 af0[4], af1[4], bq0[2], bq1[2];                                 \
        _Pragma("unroll")                                                      \
        for (int i = 0; i < 4; ++i) {                                          \
            af0[i] = *(const bf16x8*)(cA + (wm * 4 + i) * 1024 + lane * 8);    \
            af1[i] = *(const bf16x8*)(cA + (wm * 4 + i) * 1024 + 512 + lane * 8); \
        }                                                                      \
        _Pragma("unroll")                                                      \
        for (int j = 0; j < 2; ++j) {                                          \
            bq0[j] = *(const bf16x8*)(cB + (wn * 2 + j) * 1024 + lane * 8);    \
            bq1[j] = *(const bf16x8*)(cB + (wn * 2 + j) * 1024 + 512 + lane * 8); \
        }                                                                      \
        asm volatile("s_waitcnt lgkmcnt(0)" ::: "memory");                     \
        __builtin_amdgcn_s_barrier();                                          \
        if (kk + 2 < nk) stage(kk + 2);                                        \
        _Pragma("unroll")                                                      \
        for (int i = 0; i < 4; ++i)                                            \
            _Pragma("unroll")                                                  \
            for (int j = 0; j < 2; ++j)                                        \
                acc[i][j] = mfma16(bq0[j], af0[i], acc[i][j]);                 \
        _Pragma("unroll")                                                      \
        for (int i = 0; i < 4; ++i)                                            \
            _Pragma("unroll")                                                  \
            for (int j = 0; j < 2; ++j)                                        \
                acc[i][j] = mfma16(bq1[j], af1[i], acc[i][j]);                 \
        if (kk + 2 < nk) asm volatile("s_waitcnt vmcnt(4)" ::: "memory");      \
        else             asm volatile("s_waitcnt vmcnt(0)" ::: "memory");      \
        __builtin_amdgcn_s_barrier();                                          \
    }

// GEMM + fused colmix epilogue (splits=1, M=2n rows, N=2048 cols).
// 8x8 XCD tile-patch swizzle; 512 threads, 8 waves.
__global__ __launch_bounds__(512, 4) void k_gemm16_mix(
        const bf16_t* __restrict__ A, const bf16_t* __restrict__ Bt, int n,
        const float* __restrict__ cus, const float* __restrict__ cui,
        const float* __restrict__ cls, const float* __restrict__ cli,
        const float* __restrict__ bvec,
        bf16_t* __restrict__ Ab2, float* __restrict__ av, int nk) {
    __shared__ __align__(16) bf16_t As2[16384];
    __shared__ __align__(16) bf16_t Bs2[16384];
    __shared__ float asum[4][128];
    int wg = (int)(blockIdx.y * gridDim.x + blockIdx.x);   // 0..511
    int xcd = wg & 7, idx = wg >> 3;                       // 64 blocks/XCD
    int bm = (xcd & 3) * 8 + (idx & 7);                    // 0..31 M-tile
    int bn = (xcd >> 2) * 8 + (idx >> 3);                  // 0..15 N-tile
    int tr0 = bm * 8, tc0 = bn * 8;
    int wtmp = threadIdx.x >> 6, ltmp = threadIdx.x & 63;
    const bf16_t* a0 = A + (((size_t)(tr0 + wtmp) * KTILES) << 9) + ltmp * 8;
    const bf16_t* b0 = Bt + (((size_t)(tc0 + wtmp) * KTILES) << 9) + ltmp * 8;
    GEMM_PIPE8()
    // ---- fused colmix epilogue ----
    size_t row0 = (size_t)bm * 128;
    size_t col0 = (size_t)bn * 128;
    bool isU = (int)row0 < n;            // row0 multiple of 128, n multiple of 128
    const float* ps = isU ? cus : cls;
    const float* ns = isU ? cls : cus;
    const float* yi = isU ? cui : cli;
    const float* zi = isU ? cli : cui;
    int orow = lane & 15, ocol = (lane >> 4) * 4;
    #pragma unroll
    for (int i = 0; i < 4; ++i) {
        int gr = (int)row0 + wm * 64 + i * 16 + orow;
        float ra = 0.f;
        #pragma unroll
        for (int j = 0; j < 2; ++j) {
            int gc = (int)col0 + wn * 32 + j * 16 + ocol;
            f32x4 p0 = *(const f32x4*)(ps + gc);
            f32x4 q0 = *(const f32x4*)(ns + gc);
            f32x4 y0 = *(const f32x4*)(yi + gc);
            f32x4 z0 = *(const f32x4*)(zi + gc);
            f32x4 c0 = *(const f32x4*)(bvec + gc);
            bf16x4 ov;
            #pragma unroll
            for (int rg = 0; rg < 4; ++rg) {
                float v = acc[i][j][rg];
                float pos = fmaxf(v, 0.f), neg = fminf(v, 0.f);
                float mx = pos * p0[rg] + neg * q0[rg];
                ov[rg] = (bf16_t)mx;
                ra += pos * y0[rg] + neg * z0[rg] + mx * c0[rg];
            }
            *(bf16x4*)(Ab2 + swz(gr, gc, KTILES)) = ov;
        }
        ra += __shfl_xor(ra, 16, 64);
        ra += __shfl_xor(ra, 32, 64);
        if (lane < 16) asum[wn][wm * 64 + i * 16 + lane] = ra;
    }
    __syncthreads();
    if (tid < 128)
        atomicAdd(&av[row0 + tid],
                  asum[0][tid] + asum[1][tid] + asum[2][tid] + asum[3][tid]);
}

// GEMM + fused final c0-reduce epilogue, 64x128 tile (R9: 448 blocks,
// 1.75/CU, 256 thr / 4 waves, LDS 48KB). 8x7 XCD patch swizzle.
__global__ __launch_bounds__(256) void k_gemm16_red(
        const bf16_t* __restrict__ A, const bf16_t* __restrict__ Bt, int n,
        const float* __restrict__ ubn, const float* __restrict__ lbn,
        float* __restrict__ av, int nk) {
    __shared__ __align__(16) bf16_t As2[8192];    // 2 buf x 4 A-tiles x 1KB
    __shared__ __align__(16) bf16_t Bs2[16384];   // 2 buf x 8 B-tiles x 1KB
    __shared__ float asum[4][64];
    int wg = (int)blockIdx.x;                     // 0..447
    int xcd = wg & 7, idx = wg >> 3;              // 56 blocks/XCD
    int bm = xcd * 8 + idx / 7;                   // 0..63 M-tile (64 rows)
    int bn = idx % 7;                             // 0..6 N-tile (128 cols)
    int tid = threadIdx.x, lane = tid & 63, w = tid >> 6;
    const bf16_t* aw  = A  + (((size_t)(bm * 4 + w)      * KTILES) << 9) + lane * 8;
    const bf16_t* bw0 = Bt + (((size_t)(bn * 8 + 2 * w)  * KTILES) << 9) + lane * 8;
    const bf16_t* bw1 = Bt + (((size_t)(bn * 8 + 2 * w + 1) * KTILES) << 9) + lane * 8;
    f32x4 acc[4][2];
    #pragma unroll
    for (int i = 0; i < 4; ++i)
        #pragma unroll
        for (int j = 0; j < 2; ++j) acc[i][j] = (f32x4){0.f, 0.f, 0.f, 0.f};
    auto stage = [&](int kk) {
        int b = kk & 1;
        size_t go = (size_t)kk * 1024;
        bf16_t* la = &As2[b * 4096 + w * 1024];
        bf16_t* lb = &Bs2[b * 8192 + 2 * w * 1024];
        g2l16(aw + go, la);         g2l16(aw + go + 512, la + 512);
        g2l16(bw0 + go, lb);        g2l16(bw0 + go + 512, lb + 512);
        g2l16(bw1 + go, lb + 1024); g2l16(bw1 + go + 512, lb + 1536);
    };
    stage(0); stage(1);
    asm volatile("s_waitcnt vmcnt(6)" ::: "memory");
    __builtin_amdgcn_s_barrier();
    for (int kk = 0; kk < nk; ++kk) {
        const bf16_t* cA = &As2[(kk & 1) * 4096];
        const bf16_t* cB = &Bs2[(kk & 1) * 8192];
        bf16x8 af0[4], af1[4], bq0[2], bq1[2];
        #pragma unroll
        for (int i = 0; i < 4; ++i) {
            af0[i] = *(const bf16x8*)(cA + i * 1024 + lane * 8);
            af1[i] = *(const bf16x8*)(cA + i * 1024 + 512 + lane * 8);
        }
        #pragma unroll
        for (int j = 0; j < 2; ++j) {
            bq0[j] = *(const bf16x8*)(cB + (2 * w + j) * 1024 + lane * 8);
            bq1[j] = *(const bf16x8*)(cB + (2 * w + j) * 1024 + 512 + lane * 8);
        }
        asm volatile("s_waitcnt lgkmcnt(0)" ::: "memory");
        __builtin_amdgcn_s_barrier();
        if (kk + 2 < nk) stage(kk + 2);
        #pragma unroll
        for (int i = 0; i < 4; ++i)
            #pragma unroll
            for (int j = 0; j < 2; ++j)
                acc[i][j] = mfma16(bq0[j], af0[i], acc[i][j]);
        #pragma unroll
        for (int i = 0; i < 4; ++i)
            #pragma unroll
            for (int j = 0; j < 2; ++j)
                acc[i][j] = mfma16(bq1[j], af1[i], acc[i][j]);
        if (kk + 2 < nk) asm volatile("s_waitcnt vmcnt(6)" ::: "memory");
        else             asm volatile("s_waitcnt vmcnt(0)" ::: "memory");
        __builtin_amdgcn_s_barrier();
    }
    // ---- fused c0-reduce epilogue ----
    size_t row0 = (size_t)bm * 64;
    size_t col0 = (size_t)bn * 128;
    bool isU = (int)row0 < n;   // row0 multiple of 64; n multiple of 64
    const float* p = isU ? ubn : lbn;
    const float* q = isU ? lbn : ubn;
    int ocol = (lane >> 4) * 4;
    #pragma unroll
    for (int i = 0; i < 4; ++i) {
        float ra = 0.f;
        #pragma unroll
        for (int j = 0; j < 2; ++j) {
            int gc = (int)col0 + w * 32 + j * 16 + ocol;
            f32x4 p0 = *(const f32x4*)(p + gc);
            f32x4 q0 = *(const f32x4*)(q + gc);
            #pragma unroll
            for (int rg = 0; rg < 4; ++rg) {
                float v = acc[i][j][rg];
                ra += fmaxf(v, 0.f) * p0[rg] + fminf(v, 0.f) * q0[rg];
            }
        }
        ra += __shfl_xor(ra, 16, 64);
        ra += __shfl_xor(ra, 32, 64);
        if (lane < 16) asum[w][i * 16 + lane] = ra;
    }
    __syncthreads();
    if (tid < 64)
        atomicAdd(&av[row0 + tid],
                  asum[0][tid] + asum[1][tid] + asum[2][tid] + asum[3][tid]);
}

// ---------------- host launch ----------------

extern "C" void kernel_launch(void* const* d_in, const int* in_sizes, int n_in,
                              void* d_out, int out_size, void* d_ws, size_t ws_size,
                              hipStream_t stream) {
    (void)in_sizes; (void)n_in; (void)out_size; (void)ws_size;
    const float* x   = (const float*)d_in[0];
    const float* eps = (const float*)d_in[1];
    const float* W1  = (const float*)d_in[2];
    const float* B1  = (const float*)d_in[3];
    const float* W2  = (const float*)d_in[4];
    const float* B2  = (const float*)d_in[5];
    const float* W3  = (const float*)d_in[6];
    const float* B3  = (const float*)d_in[7];
    const float* W4  = (const float*)d_in[8];
    const float* B4  = (const float*)d_in[9];
    float* out = (float*)d_out;

    const int H = 2048, DIN = 784, DOUT = 10;
    const int NP1 = 896;           // DIN padded to x128
    const int MP4 = 32;            // layer-4 row pad (20 real rows)

    float* ws = (float*)d_ws;
    size_t off = 0;
    auto alloc = [&](size_t nf) -> float* {
        float* p = ws + off;
        off += (nf + 3) & ~(size_t)3;
        return p;
    };
    float* ubn = alloc(NP1);
    float* lbn = alloc(NP1);
    float* us1 = alloc(H); float* ui1 = alloc(H); float* ls1 = alloc(H); float* li1 = alloc(H);
    float* pU1 = alloc(H); float* pL1 = alloc(H);
    float* iU2 = alloc(H); float* iL2 = alloc(H);
    float* us2 = alloc(H); float* ui2 = alloc(H); float* ls2 = alloc(H); float* li2 = alloc(H);
    float* pU2 = alloc(H); float* pL2 = alloc(H);
    float* iU3 = alloc(H); float* iL3 = alloc(H);
    float* us3 = alloc(H); float* ui3 = alloc(H); float* ls3 = alloc(H); float* li3 = alloc(H);
    float* pU3 = alloc(H); float* pL3 = alloc(H);
    float* iU4 = alloc(32); float* iL4 = alloc(32);
    float* av  = alloc(2 * H);
    bf16_t* Ab  = (bf16_t*)alloc((size_t)2 * H * H / 2);       // 4096 x 2048 bf16 swz
    bf16_t* Ab2 = (bf16_t*)alloc((size_t)2 * H * H / 2);       // second operand buffer
    bf16_t* W1t = (bf16_t*)alloc((size_t)NP1 * H / 2);
    bf16_t* W2t = (bf16_t*)alloc((size_t)H * H / 2);
    bf16_t* W3t = (bf16_t*)alloc((size_t)H * H / 2);
    bf16_t* Cs  = (bf16_t*)alloc((size_t)16 * MP4 * H / 2);    // L4 split-16 slabs (bf16)

    dim3 blk(256);

    // weight transpose/convert/swizzle (merged) + input bounds side-block
    k_wT3<<<dim3(32, 32, 3), blk, 0, stream>>>(W1, W2, W3, W1t, W2t, W3t,
                                               x, eps, ubn, lbn);

    size_t ss4H = (size_t)MP4 * H;          // layer-4 N=H slab (32 x 2048)
    size_t ss4N = (size_t)MP4 * NP1;        // layer-4 N=NP1 slab (32 x 896)

    // ======== Layer 1 (fused interval + spu) ========
    k_interval_spu<<<dim3(H / 4), blk, 0, stream>>>(W1, B1, ubn, lbn, DIN, H,
        us1, ui1, ls1, li1, pU1, pL1);

    // ======== Layer 2 ========
    k_prep16<<<dim3(2 * H / 16), blk, 0, stream>>>(W2, B2, H,
        us1, ui1, ls1, li1, B1, pU1, pL1, Ab, av, iU2, iL2);
    k_gemm16_red<<<dim3(448), blk, 0, stream>>>(Ab, W1t, H,
        ubn, lbn, av, KTILES / 2);
    k_spu2<<<dim3(H / 64), dim3(64), 0, stream>>>(iU2, iL2, av, H,
        us2, ui2, ls2, li2, pU2, pL2);

    // ======== Layer 3 ========
    k_prep16<<<dim3(2 * H / 16), blk, 0, stream>>>(W3, B3, H,
        us2, ui2, ls2, li2, B2, pU2, pL2, Ab, av, iU3, iL3);
    k_gemm16_mix<<<dim3(2 * H / 128, H / 128), dim3(512), 0, stream>>>(Ab, W2t, H,
        us1, ui1, ls1, li1, B1, Ab2, av, KTILES / 2);
    k_gemm16_red<<<dim3(448), blk, 0, stream>>>(Ab2, W1t, H,
        ubn, lbn, av, KTILES / 2);
    k_spu2<<<dim3(H / 64), dim3(64), 0, stream>>>(iU3, iL3, av, H,
        us3, ui3, ls3, li3, pU3, pL3);

    // ======== Layer 4 (M = 20 padded to 32, split-K 16, colmix k-split 8) ========
    k_prep16<<<dim3(MP4 / 16), blk, 0, stream>>>(W4, B4, DOUT,
        us3, ui3, ls3, li3, B3, pU3, pL3, Ab, av, iU4, iL4);
    k_gemm16s<<<dim3(H / 128, 1, 16), blk, 0, stream>>>(Ab, W3t, Cs, H, ss4H, 2);
    k_colmix16<<<dim3(MP4 / 16, 8), blk, 0, stream>>>(Cs, H, 16, ss4H, DOUT, KTILES / 8,
        us2, ui2, ls2, li2, B2, Ab2, av);
    k_gemm16s<<<dim3(H / 128, 1, 16), blk, 0, stream>>>(Ab2, W2t, Cs, H, ss4H, 2);
    k_colmix16<<<dim3(MP4 / 16, 8), blk, 0, stream>>>(Cs, H, 16, ss4H, DOUT, KTILES / 8,
        us1, ui1, ls1, li1, B1, Ab, av);
    k_gemm16s<<<dim3(NP1 / 128, 1, 16), blk, 0, stream>>>(Ab, W1t, Cs, NP1, ss4N, 2);
    k_reduce16f<<<dim3(1), dim3(640), 0, stream>>>(Cs, NP1, DIN, DOUT, 16, ss4N,
        av, ubn, lbn, iL4, out);
}

// Round 11
// 301.886 us; speedup vs baseline: 1.1513x; 1.0318x over previous
//
#include <hip/hip_runtime.h>
#include <cstdint>
#include <cstddef>

#define MEAN_C 0.1307f
#define SIGMA_C 0.3081f
#define SIG_SCALE_C 5.0f

typedef __bf16 bf16_t;
typedef __bf16 bf16x8 __attribute__((ext_vector_type(8)));
typedef __bf16 bf16x4 __attribute__((ext_vector_type(4)));
typedef float f32x4 __attribute__((ext_vector_type(4)));

__device__ __forceinline__ f32x4 mfma16(bf16x8 a, bf16x8 b, f32x4 c) {
    return __builtin_amdgcn_mfma_f32_16x16x32_bf16(a, b, c, 0, 0, 0);
}

typedef const __attribute__((address_space(1))) void* gvp;
typedef __attribute__((address_space(3))) void* lvp;
__device__ __forceinline__ void g2l16(const void* g, void* l) {
    __builtin_amdgcn_global_load_lds((gvp)g, (lvp)l, 16, 0, 0);
}

// swizzled bf16 operand layout: 16x32 tiles (1KB); chunk index within tile =
// lane = (k-chunk)*16 + row  (16B each). offset(r,k), K = ktiles*32.
__device__ __forceinline__ size_t swz(int r, int k, int ktiles) {
    return (((size_t)(r >> 4) * ktiles + (k >> 5)) << 9)
         + (((k >> 3) & 3) << 7) + ((r & 15) << 3) + (k & 7);
}

#define KTILES 64   // K = 2048

// ---------------- device helpers ----------------

__device__ __forceinline__ float sigmoidf_(float x) {
    if (x >= 0.f) { float e = __expf(-x); return 1.f / (1.f + e); }
    float e = __expf(x); return e / (1.f + e);
}

__device__ __forceinline__ float spu_f(float x) {
    return (x >= 0.f) ? (x * x - 0.5f) : (sigmoidf_(-x) - 1.f);
}

__device__ __forceinline__ float wave_sum(float a) {
    #pragma unroll
    for (int o = 32; o > 0; o >>= 1) a += __shfl_xor(a, o, 64);
    return a;
}

// full analyze_spu for one neuron i, given clamp bounds (iUi, iLi) and the
// back-substituted chain values vU (upper row) / vL (lower row).
__device__ __forceinline__ void spu_body(int i, int n,
        float iUi, float iLi, float vU, float vL,
        float* __restrict__ us, float* __restrict__ ui,
        float* __restrict__ ls, float* __restrict__ li,
        float* __restrict__ pU, float* __restrict__ pL) {
    float ux = fminf(iUi, vU);
    float lx = fmaxf(iLi, vL);
    float uy = spu_f(ux), ly = spu_f(lx);
    float new_ub = fmaxf(uy, ly);
    float sj = (uy - ly) / (ux - lx);
    float ij = uy - sj * ux;
    bool right = lx > 0.f;
    bool left = ux <= 0.f;
    float mid = 0.5f * (ux + lx);
    float sp = 2.f * mid, ip = -mid * mid - 0.5f;
    float sm = sigmoidf_(mid);
    float ssm = -sm * (1.f - sm);
    float ism = -sm - ssm * mid;
    bool crossing = (!left) && (!right);
    float new_lb = crossing ? -0.5f : fminf(uy, ly);
    float spu_s = 2.f * ux, ipu = -ux * ux - 0.5f;
    float limit = spu_s * lx + ipu;
    float clm = (fabsf(lx) > ux) ? 1.f : 0.f;
    float clp = sigmoidf_((clm - 0.5f) * 2.f * SIG_SCALE_C) * (ly - limit) + limit;
    bool ptm = clp < -0.5f;
    float D = 4.f * lx * lx - 4.f * clp - 2.f;
    float x2 = (2.f * lx + sqrtf(fmaxf(D, 0.f))) * 0.5f;
    float spt = 2.f * x2, ipt = -x2 * x2 - 0.5f;
    float sjn = (clp + 0.5f) / lx;
    float ijn = -0.5f;
    float s_cl = ptm ? spt : sjn;
    float i_cl = ptm ? ipt : ijn;
    float sl = sigmoidf_(lx);
    float ssl = -sl * (1.f - sl);
    float isl = -sl - ssl * lx;
    float stv = ssl * ux + isl - uy;
    float Lb = lx, Rb = 0.f;
    #pragma unroll
    for (int t = 0; t < 10; ++t) {
        float mm = 0.5f * (Lb + Rb);
        float smm = sigmoidf_(mm);
        float sms = -smm * (1.f - smm);
        float smi = -smm - sms * mm;
        bool mask = (sms * ux + smi - uy) > 0.f;
        Lb = mask ? mm : Lb;
        Rb = mask ? Rb : mm;
    }
    float scp = sigmoidf_(-SIG_SCALE_C) * (Lb - lx) + lx;
    float sc = sigmoidf_(scp);
    float ssc = -sc * (1.f - sc);
    float isc = -sc - ssc * scp;
    bool up = stv > 0.f;
    float s_cu = up ? ssc : sj;
    float i_cu = up ? isc : ij;
    float usv, uiv, lsv, liv;
    if (right)      { usv = sj;   uiv = ij;   lsv = sp;   liv = ip;   }
    else if (left)  { usv = ssm;  uiv = ism;  lsv = sj;   liv = ij;   }
    else            { usv = s_cu; uiv = i_cu; lsv = s_cl; liv = i_cl; }
    us[i] = usv; ui[i] = uiv; ls[i] = lsv; li[i] = liv;
    float vu = (usv >= 0.f) ? vU : vL;
    float vl = (lsv >= 0.f) ? vL : vU;
    pU[i] = fminf(new_ub, usv * vu + uiv);
    pL[i] = fmaxf(new_lb, lsv * vl + liv);
}

// ---------------- small kernels ----------------

// fused layer-1 interval bound + analyze_spu
__global__ __launch_bounds__(256) void k_interval_spu(
        const float* __restrict__ W, const float* __restrict__ b,
        const float* __restrict__ U, const float* __restrict__ L,
        int m, int n,
        float* __restrict__ us, float* __restrict__ ui,
        float* __restrict__ ls, float* __restrict__ li,
        float* __restrict__ pU, float* __restrict__ pL) {
    int r = (blockIdx.x << 2) + (threadIdx.x >> 6);
    if (r >= n) return;
    int lane = threadIdx.x & 63;
    const f32x4* Wr = (const f32x4*)(W + (size_t)r * m);
    const f32x4* U4 = (const f32x4*)U;
    const f32x4* L4 = (const f32x4*)L;
    int nf4 = m >> 2;
    float au = 0.f, al = 0.f;
    for (int j = lane; j < nf4; j += 64) {
        f32x4 wv = Wr[j], uu = U4[j], ll = L4[j];
        #pragma unroll
        for (int u = 0; u < 4; ++u) {
            float w = wv[u];
            float hi = (w > 0.f) ? uu[u] : ll[u];
            float lo2 = (w > 0.f) ? ll[u] : uu[u];
            au = fmaf(w, hi, au);
            al = fmaf(w, lo2, al);
        }
    }
    au = wave_sum(au); al = wave_sum(al);
    if (lane == 0) {
        float vU = au + b[r], vL = al + b[r];
        spu_body(r, n, vU, vL, vU, vL, us, ui, ls, li, pU, pL);
    }
}

// standalone spu (layers 2/3)
__global__ void k_spu2(const float* __restrict__ iU, const float* __restrict__ iL,
                       const float* __restrict__ vraw, int n,
                       float* __restrict__ us, float* __restrict__ ui,
                       float* __restrict__ ls, float* __restrict__ li,
                       float* __restrict__ pU, float* __restrict__ pL) {
    int i = blockIdx.x * blockDim.x + threadIdx.x;
    if (i >= n) return;
    spu_body(i, n, iU[i], iL[i], vraw[i], vraw[n + i], us, ui, ls, li, pU, pL);
}

// ---------------- bf16 producers ----------------

// merged transpose/convert/swizzle of W1,W2,W3 + input-bounds side block.
__global__ __launch_bounds__(256) void k_wT3(
        const float* __restrict__ W1, const float* __restrict__ W2,
        const float* __restrict__ W3,
        bf16_t* __restrict__ W1t, bf16_t* __restrict__ W2t, bf16_t* __restrict__ W3t,
        const float* __restrict__ x, const float* __restrict__ eps,
        float* __restrict__ ubn, float* __restrict__ lbn) {
    __shared__ bf16_t t[64 * 65];
    int z = blockIdx.z;
    const float* W; int N, ldw; bf16_t* Wt;
    if (z == 0)      { W = W2; N = 2048; ldw = 2048; Wt = W2t; }
    else if (z == 1) { W = W3; N = 2048; ldw = 2048; Wt = W3t; }
    else {
        W = W1; N = 784; ldw = 784; Wt = W1t;
        if (blockIdx.y >= 14) {
            if (blockIdx.y == 14 && blockIdx.x == 0) {
                for (int i = threadIdx.x; i < 896; i += 256) {
                    if (i >= 784) { ubn[i] = 0.f; lbn[i] = 0.f; }
                    else {
                        float e = eps[0];
                        float ub = fminf(x[i] + e, 1.f);
                        float lb = fmaxf(x[i] - e, 0.f);
                        ubn[i] = (ub - MEAN_C) / SIGMA_C;
                        lbn[i] = (lb - MEAN_C) / SIGMA_C;
                    }
                }
            }
            return;
        }
    }
    int k0 = blockIdx.x * 64, n0 = blockIdx.y * 64;
    int tid = threadIdx.x;
    int rg = tid >> 4;            // 0..15 row sub-index
    int cg = (tid & 15) * 4;      // column start (f32x4)
    bool fast = (n0 + 64 <= N);
    #pragma unroll
    for (int it = 0; it < 4; ++it) {
        int row = it * 16 + rg;   // local k
        const float* Wr = W + (size_t)(k0 + row) * ldw + n0 + cg;
        float v0, v1, v2, v3;
        if (fast) {
            f32x4 vv = *(const f32x4*)Wr;
            v0 = vv[0]; v1 = vv[1]; v2 = vv[2]; v3 = vv[3];
        } else {
            v0 = (n0 + cg + 0 < N) ? Wr[0] : 0.f;
            v1 = (n0 + cg + 1 < N) ? Wr[1] : 0.f;
            v2 = (n0 + cg + 2 < N) ? Wr[2] : 0.f;
            v3 = (n0 + cg + 3 < N) ? Wr[3] : 0.f;
        }
        t[(cg + 0) * 65 + row] = (bf16_t)v0;
        t[(cg + 1) * 65 + row] = (bf16_t)v1;
        t[(cg + 2) * 65 + row] = (bf16_t)v2;
        t[(cg + 3) * 65 + row] = (bf16_t)v3;
    }
    __syncthreads();
    #pragma unroll
    for (int p = 0; p < 2; ++p) {
        int c = tid + p * 256;
        int lr = c & 63, lq = c >> 6;
        bf16x8 v;
        #pragma unroll
        for (int u = 0; u < 8; ++u) v[u] = t[lr * 65 + lq * 8 + u];
        *(bf16x8*)(Wt + swz(n0 + lr, k0 + lq * 8, KTILES)) = v;
    }
}

// prep (fused interval-affine)
__global__ __launch_bounds__(256) void k_prep16(
        const float* __restrict__ W, const float* __restrict__ b, int n,
        const float* __restrict__ cus, const float* __restrict__ cui,
        const float* __restrict__ cls, const float* __restrict__ cli,
        const float* __restrict__ bvec,
        const float* __restrict__ U, const float* __restrict__ L,
        bf16_t* __restrict__ Ab, float* __restrict__ av,
        float* __restrict__ iU, float* __restrict__ iL) {
    int rt = blockIdx.x;
    int tid = threadIdx.x, lane = tid & 63, wid = tid >> 6;
    int mrow = lane & 15, q = lane >> 4;
    int r = rt * 16 + mrow;
    bool act = r < 2 * n;
    bool isU = r < n;
    int i = act ? (isU ? r : r - n) : 0;
    float gate = act ? 1.f : 0.f;
    const float* Wr = W + (size_t)i * 2048;
    const float* ps = isU ? cus : cls;
    const float* ns = isU ? cls : cus;
    const float* yi = isU ? cui : cli;
    const float* zi = isU ? cli : cui;
    const float* hi = isU ? U : L;
    const float* lo = isU ? L : U;
    float a = 0.f, a2 = 0.f;
    bf16_t* Abase = Ab + ((size_t)rt * KTILES) * 512 + lane * 8;
    for (int kt = wid; kt < KTILES; kt += 4) {
        int k0 = kt * 32 + q * 8;
        bf16x8 ov;
        #pragma unroll
        for (int h = 0; h < 2; ++h) {
            int kb = k0 + 4 * h;
            f32x4 wv = *(const f32x4*)(Wr + kb);
            f32x4 p0 = *(const f32x4*)(ps + kb);
            f32x4 q0 = *(const f32x4*)(ns + kb);
            f32x4 y0 = *(const f32x4*)(yi + kb);
            f32x4 z0 = *(const f32x4*)(zi + kb);
            f32x4 c0 = *(const f32x4*)(bvec + kb);
            f32x4 h0 = *(const f32x4*)(hi + kb);
            f32x4 l0 = *(const f32x4*)(lo + kb);
            #pragma unroll
            for (int u = 0; u < 4; ++u) {
                float w = gate * wv[u];
                float pos = fmaxf(w, 0.f), neg = fminf(w, 0.f);
                float mx = pos * p0[u] + neg * q0[u];
                ov[4 * h + u] = (bf16_t)mx;
                a += pos * y0[u] + neg * z0[u] + mx * c0[u];
                a2 += pos * h0[u] + neg * l0[u];   // interval dot
            }
        }
        *(bf16x8*)(Abase + (size_t)kt * 512) = ov;
    }
    a += __shfl_xor(a, 16, 64);  a += __shfl_xor(a, 32, 64);
    a2 += __shfl_xor(a2, 16, 64); a2 += __shfl_xor(a2, 32, 64);
    __shared__ float sh[2][4][16];
    if (lane < 16) { sh[0][wid][lane] = a; sh[1][wid][lane] = a2; }
    __syncthreads();
    if (tid < 16) {
        int r2 = rt * 16 + tid;
        float ta = sh[0][0][tid] + sh[0][1][tid] + sh[0][2][tid] + sh[0][3][tid];
        float tb = sh[1][0][tid] + sh[1][1][tid] + sh[1][2][tid] + sh[1][3][tid];
        if (r2 < 2 * n) {
            bool isU2 = r2 < n;
            int i2 = isU2 ? r2 : r2 - n;
            av[r2] = ta + b[i2];
            if (isU2) iU[i2] = tb + b[i2];
            else      iL[i2] = tb + b[i2];
        } else {
            av[r2] = 0.f;
        }
    }
}

// colmix (layer-4 small-M chains): bf16 split slabs -> swizzled bf16 Ab
__global__ __launch_bounds__(256) void k_colmix16(
        const bf16_t* __restrict__ Cb, int ldc, int splits, size_t sstride, int n,
        int tpb,
        const float* __restrict__ cus, const float* __restrict__ cui,
        const float* __restrict__ cls, const float* __restrict__ cli,
        const float* __restrict__ bvec,
        bf16_t* __restrict__ Ab, float* __restrict__ av) {
    int rt = blockIdx.x;
    int kt0 = blockIdx.y * tpb;
    int tid = threadIdx.x, lane = tid & 63, wid = tid >> 6;
    int mrow = lane & 15, q = lane >> 4;
    int r = rt * 16 + mrow;
    bool isU = r < n;
    const bf16_t* Cr = Cb + (size_t)r * ldc;
    const float* ps = isU ? cus : cls;
    const float* ns = isU ? cls : cus;
    const float* yi = isU ? cui : cli;
    const float* zi = isU ? cli : cui;
    float a = 0.f;
    bf16_t* Abase = Ab + ((size_t)rt * KTILES) * 512 + lane * 8;
    for (int kt = kt0 + wid; kt < kt0 + tpb; kt += 4) {
        int k0 = kt * 32 + q * 8;
        float wsum[8] = {0.f, 0.f, 0.f, 0.f, 0.f, 0.f, 0.f, 0.f};
        for (int s = 0; s < splits; ++s) {
            bf16x8 v = *(const bf16x8*)(Cr + s * sstride + k0);
            #pragma unroll
            for (int u = 0; u < 8; ++u) wsum[u] += (float)v[u];
        }
        f32x4 p0 = *(const f32x4*)(ps + k0), p1 = *(const f32x4*)(ps + k0 + 4);
        f32x4 q0 = *(const f32x4*)(ns + k0), q1 = *(const f32x4*)(ns + k0 + 4);
        f32x4 y0 = *(const f32x4*)(yi + k0), y1 = *(const f32x4*)(yi + k0 + 4);
        f32x4 z0 = *(const f32x4*)(zi + k0), z1 = *(const f32x4*)(zi + k0 + 4);
        f32x4 c0 = *(const f32x4*)(bvec + k0), c1 = *(const f32x4*)(bvec + k0 + 4);
        bf16x8 ov;
        #pragma unroll
        for (int u = 0; u < 4; ++u) {
            float w = wsum[u];
            float pos = fmaxf(w, 0.f), neg = fminf(w, 0.f);
            float mx = pos * p0[u] + neg * q0[u];
            ov[u] = (bf16_t)mx;
            a += pos * y0[u] + neg * z0[u] + mx * c0[u];
        }
        #pragma unroll
        for (int u = 0; u < 4; ++u) {
            float w = wsum[4 + u];
            float pos = fmaxf(w, 0.f), neg = fminf(w, 0.f);
            float mx = pos * p1[u] + neg * q1[u];
            ov[4 + u] = (bf16_t)mx;
            a += pos * y1[u] + neg * z1[u] + mx * c1[u];
        }
        *(bf16x8*)(Abase + (size_t)kt * 512) = ov;
    }
    a += __shfl_xor(a, 16, 64);
    a += __shfl_xor(a, 32, 64);
    __shared__ float sh[4][16];
    if (lane < 16) sh[wid][lane] = a;
    __syncthreads();
    if (tid < 16) {
        float tot = sh[0][tid] + sh[1][tid] + sh[2][tid] + sh[3][tid];
        atomicAdd(&av[rt * 16 + tid], tot);
    }
}

// final c0 step + min, fused, single block of 10 waves (one wave per L row).
__global__ __launch_bounds__(640) void k_reduce16f(
        const bf16_t* __restrict__ Cb, int ldc, int m, int n,
        int splits, size_t sstride,
        const float* __restrict__ av,
        const float* __restrict__ ubn, const float* __restrict__ lbn,
        const float* __restrict__ iL,
        float* __restrict__ out) {
    __shared__ float sbl[16];
    int tid = threadIdx.x, lane = tid & 63, wv = tid >> 6;   // 10 waves
    int nch = m >> 3;   // m % 8 == 0
    int i = wv;          // 0..9 == DOUT rows
    int r = n + i;       // L rows only
    const bf16_t* Cr = Cb + (size_t)r * ldc;
    const float* p = lbn;
    const float* q = ubn;
    float a = 0.f;
    for (int c = lane; c < nch; c += 64) {
        float wsum[8] = {0.f, 0.f, 0.f, 0.f, 0.f, 0.f, 0.f, 0.f};
        for (int s = 0; s < splits; ++s) {
            bf16x8 v = *(const bf16x8*)(Cr + s * sstride + c * 8);
            #pragma unroll
            for (int u = 0; u < 8; ++u) wsum[u] += (float)v[u];
        }
        f32x4 p0 = *(const f32x4*)(p + c * 8), p1 = *(const f32x4*)(p + c * 8 + 4);
        f32x4 q0 = *(const f32x4*)(q + c * 8), q1 = *(const f32x4*)(q + c * 8 + 4);
        #pragma unroll
        for (int u = 0; u < 4; ++u) {
            a += fmaxf(wsum[u], 0.f) * p0[u] + fminf(wsum[u], 0.f) * q0[u];
            a += fmaxf(wsum[4 + u], 0.f) * p1[u] + fminf(wsum[4 + u], 0.f) * q1[u];
        }
    }
    a = wave_sum(a);
    if (lane == 0) sbl[i] = fmaxf(iL[i], a + av[r]);
    __syncthreads();
    if (tid < 64) {
        float v = 3.4e38f;
        for (int j = lane; j < n; j += 64) v = fminf(v, sbl[j]);
        #pragma unroll
        for (int o = 32; o > 0; o >>= 1) v = fminf(v, __shfl_down(v, o, 64));
        if (lane == 0) out[0] = v;
    }
}

// ---- L4 small-M GEMM: 32x128 tile, 256 thr / 4 waves, split-K slabs ----
__global__ __launch_bounds__(256) void k_gemm16s(
        const bf16_t* __restrict__ A, const bf16_t* __restrict__ Bt,
        bf16_t* __restrict__ C, int ldc, size_t sstride, int nk) {
    __shared__ __align__(16) bf16_t As2[8192];    // 2 buf x 4KB (32 rows x BK64)
    __shared__ __align__(16) bf16_t Bs2[32768];   // 2 buf x 16KB (128 cols x BK64)
    int bn = blockIdx.x;
    int kt0 = blockIdx.z * nk * 2;
    int tid = threadIdx.x, lane = tid & 63, w = tid >> 6;
    const bf16_t* aw = A +
        (((size_t)(w >> 1) * KTILES + kt0 + (w & 1)) << 9) + lane * 8;
    const bf16_t* bt0 = Bt +
        (((size_t)(bn * 8 + 2 * w) * KTILES + kt0) << 9) + lane * 8;
    const bf16_t* bt1 = Bt +
        (((size_t)(bn * 8 + 2 * w + 1) * KTILES + kt0) << 9) + lane * 8;
    f32x4 acc[2][2];
    #pragma unroll
    for (int i = 0; i < 2; ++i)
        #pragma unroll
        for (int j = 0; j < 2; ++j) acc[i][j] = (f32x4){0.f, 0.f, 0.f, 0.f};
    auto stage = [&](int kk) {
        int b = kk & 1;
        size_t go = (size_t)kk * 1024;
        g2l16(aw + go,        &As2[b * 4096 + w * 1024]);
        g2l16(bt0 + go,       &Bs2[b * 16384 + (4 * w + 0) * 1024]);
        g2l16(bt0 + go + 512, &Bs2[b * 16384 + (4 * w + 1) * 1024]);
        g2l16(bt1 + go,       &Bs2[b * 16384 + (4 * w + 2) * 1024]);
        g2l16(bt1 + go + 512, &Bs2[b * 16384 + (4 * w + 3) * 1024]);
    };
    stage(0); stage(1);
    asm volatile("s_waitcnt vmcnt(5)" ::: "memory");
    __builtin_amdgcn_s_barrier();
    for (int kk = 0; kk < nk; ++kk) {
        const bf16_t* cA = &As2[(kk & 1) * 4096];
        const bf16_t* cB = &Bs2[(kk & 1) * 16384];
        bf16x8 af[2][2], bq[2][2];
        #pragma unroll
        for (int i = 0; i < 2; ++i)
            #pragma unroll
            for (int h = 0; h < 2; ++h) {
                af[i][h] = *(const bf16x8*)(cA + (i * 2 + h) * 1024 + lane * 8);
                bq[i][h] = *(const bf16x8*)(cB + (4 * w + i * 2 + h) * 1024 + lane * 8);
            }
        asm volatile("s_waitcnt lgkmcnt(0)" ::: "memory");
        __builtin_amdgcn_s_barrier();
        if (kk + 2 < nk) stage(kk + 2);
        #pragma unroll
        for (int h = 0; h < 2; ++h)
            #pragma unroll
            for (int i = 0; i < 2; ++i)
                #pragma unroll
                for (int j = 0; j < 2; ++j)
                    acc[i][j] = mfma16(bq[j][h], af[i][h], acc[i][j]);
        if (kk + 2 < nk) asm volatile("s_waitcnt vmcnt(5)" ::: "memory");
        else             asm volatile("s_waitcnt vmcnt(0)" ::: "memory");
        __builtin_amdgcn_s_barrier();
    }
    bf16_t* Cz = C + (size_t)blockIdx.z * sstride;
    int orow = lane & 15, ocol = (lane >> 4) * 4;
    #pragma unroll
    for (int i = 0; i < 2; ++i) {
        int gr = i * 16 + orow;
        #pragma unroll
        for (int j = 0; j < 2; ++j) {
            int gc = bn * 128 + w * 32 + j * 16 + ocol;
            bf16x4 v;
            #pragma unroll
            for (int rg = 0; rg < 4; ++rg) v[rg] = (bf16_t)acc[i][j][rg];
            *(bf16x4*)(Cz + (size_t)gr * ldc + gc) = v;
        }
    }
}

// ---- 512-thr 8-wave BK=64 mid-barrier distance-2 pipe (128x128 tile) ----
#define GEMM_PIPE8()                                                           \
    int tid = threadIdx.x, lane = tid & 63, w = tid >> 6;      /* 0..7 */      \
    int wm = w >> 2, wn = w & 3;                                               \
    f32x4 acc[4][2];                                                           \
    _Pragma("unroll")                                                          \
    for (int i = 0; i < 4; ++i)                                                \
        _Pragma("unroll")                                                      \
        for (int j = 0; j < 2; ++j) acc[i][j] = (f32x4){0.f, 0.f, 0.f, 0.f};   \
    auto stage = [&](int kk) {                                                 \
        int b = kk & 1;                                                        \
        size_t go = (size_t)kk * 1024;                                         \
        bf16_t* la = &As2[b * 8192 + w * 1024];                                \
        bf16_t* lb = &Bs2[b * 8192 + w * 1024];                                \
        g2l16(a0 + go, la);   g2l16(a0 + go + 512, la + 512);                  \
        g2l16(b0 + go, lb);   g2l16(b0 + go + 512, lb + 512);                  \
    };                                                                         \
    stage(0); stage(1);                                                        \
    asm volatile("s_waitcnt vmcnt(4)" ::: "memory");                           \
    __builtin_amdgcn_s_barrier();                                              \
    for (int kk = 0; kk < nk; ++kk) {                                          \
        const bf16_t* cA = &As2[(kk & 1) * 8192];                              \
        const bf16_t* cB = &Bs2[(kk & 1) * 8192];                              \
        bf16x8 af0[4], af1[4], bq0[2], bq1[2];                                 \
        _Pragma("unroll")                                                      \
        for (int i = 0; i < 4; ++i) {                                          \
            af0[i] = *(const bf16x8*)(cA + (wm * 4 + i) * 1024 + lane * 8);    \
            af1[i] = *(const bf16x8*)(cA + (wm * 4 + i) * 1024 + 512 + lane * 8); \
        }                                                                      \
        _Pragma("unroll")                                                      \
        for (int j = 0; j < 2; ++j) {                                          \
            bq0[j] = *(const bf16x8*)(cB + (wn * 2 + j) * 1024 + lane * 8);    \
            bq1[j] = *(const bf16x8*)(cB + (wn * 2 + j) * 1024 + 512 + lane * 8); \
        }                                                                      \
        asm volatile("s_waitcnt lgkmcnt(0)" ::: "memory");                     \
        __builtin_amdgcn_s_barrier();                                          \
        if (kk + 2 < nk) stage(kk + 2);                                        \
        _Pragma("unroll")                                                      \
        for (int i = 0; i < 4; ++i)                                            \
            _Pragma("unroll")                                                  \
            for (int j = 0; j < 2; ++j)                                        \
                acc[i][j] = mfma16(bq0[j], af0[i], acc[i][j]);                 \
        _Pragma("unroll")                                                      \
        for (int i = 0; i < 4; ++i)                                            \
            _Pragma("unroll")                                                  \
            for (int j = 0; j < 2; ++j)                                        \
                acc[i][j] = mfma16(bq1[j], af1[i], acc[i][j]);                 \
        if (kk + 2 < nk) asm volatile("s_waitcnt vmcnt(4)" ::: "memory");      \
        else             asm volatile("s_waitcnt vmcnt(0)" ::: "memory");      \
        __builtin_amdgcn_s_barrier();                                          \
    }

// GEMM + fused colmix epilogue (splits=1, M=2n rows, N=2048 cols).
// 8x8 XCD tile-patch swizzle; 512 threads, 8 waves.
__global__ __launch_bounds__(512, 4) void k_gemm16_mix(
        const bf16_t* __restrict__ A, const bf16_t* __restrict__ Bt, int n,
        const float* __restrict__ cus, const float* __restrict__ cui,
        const float* __restrict__ cls, const float* __restrict__ cli,
        const float* __restrict__ bvec,
        bf16_t* __restrict__ Ab2, float* __restrict__ av, int nk) {
    __shared__ __align__(16) bf16_t As2[16384];
    __shared__ __align__(16) bf16_t Bs2[16384];
    __shared__ float asum[4][128];
    int wg = (int)(blockIdx.y * gridDim.x + blockIdx.x);   // 0..511
    int xcd = wg & 7, idx = wg >> 3;                       // 64 blocks/XCD
    int bm = (xcd & 3) * 8 + (idx & 7);                    // 0..31 M-tile
    int bn = (xcd >> 2) * 8 + (idx >> 3);                  // 0..15 N-tile
    int tr0 = bm * 8, tc0 = bn * 8;
    int wtmp = threadIdx.x >> 6, ltmp = threadIdx.x & 63;
    const bf16_t* a0 = A + (((size_t)(tr0 + wtmp) * KTILES) << 9) + ltmp * 8;
    const bf16_t* b0 = Bt + (((size_t)(tc0 + wtmp) * KTILES) << 9) + ltmp * 8;
    GEMM_PIPE8()
    // ---- fused colmix epilogue ----
    size_t row0 = (size_t)bm * 128;
    size_t col0 = (size_t)bn * 128;
    bool isU = (int)row0 < n;            // row0 multiple of 128, n multiple of 128
    const float* ps = isU ? cus : cls;
    const float* ns = isU ? cls : cus;
    const float* yi = isU ? cui : cli;
    const float* zi = isU ? cli : cui;
    int orow = lane & 15, ocol = (lane >> 4) * 4;
    #pragma unroll
    for (int i = 0; i < 4; ++i) {
        int gr = (int)row0 + wm * 64 + i * 16 + orow;
        float ra = 0.f;
        #pragma unroll
        for (int j = 0; j < 2; ++j) {
            int gc = (int)col0 + wn * 32 + j * 16 + ocol;
            f32x4 p0 = *(const f32x4*)(ps + gc);
            f32x4 q0 = *(const f32x4*)(ns + gc);
            f32x4 y0 = *(const f32x4*)(yi + gc);
            f32x4 z0 = *(const f32x4*)(zi + gc);
            f32x4 c0 = *(const f32x4*)(bvec + gc);
            bf16x4 ov;
            #pragma unroll
            for (int rg = 0; rg < 4; ++rg) {
                float v = acc[i][j][rg];
                float pos = fmaxf(v, 0.f), neg = fminf(v, 0.f);
                float mx = pos * p0[rg] + neg * q0[rg];
                ov[rg] = (bf16_t)mx;
                ra += pos * y0[rg] + neg * z0[rg] + mx * c0[rg];
            }
            *(bf16x4*)(Ab2 + swz(gr, gc, KTILES)) = ov;
        }
        ra += __shfl_xor(ra, 16, 64);
        ra += __shfl_xor(ra, 32, 64);
        if (lane < 16) asum[wn][wm * 64 + i * 16 + lane] = ra;
    }
    __syncthreads();
    if (tid < 128)
        atomicAdd(&av[row0 + tid],
                  asum[0][tid] + asum[1][tid] + asum[2][tid] + asum[3][tid]);
}

// GEMM + fused final c0-reduce epilogue, RETILED 64x64 (R10 analysis: red at
// 64x128/448 blocks = 1.75 blocks/CU, ~341 TF vs mix 765 at same per-wave
// density -> still supply-limited). New: 896 blocks = 3.5/CU, LDS 32KB
// (4+ resident). Wave w owns rows [w*16,w*16+16) x all 64 cols; stages its
// own A row-tile + B col-tile w: 4 g2l/stage -> vmcnt(4) ladder. acc[4].
// Bijective XCD swizzle: bm = xcd*8+(idx&7) in 0..63, bn = idx>>3 in 0..13.
__global__ __launch_bounds__(256) void k_gemm16_red(
        const bf16_t* __restrict__ A, const bf16_t* __restrict__ Bt, int n,
        const float* __restrict__ ubn, const float* __restrict__ lbn,
        float* __restrict__ av, int nk) {
    __shared__ __align__(16) bf16_t As2[8192];    // 2 buf x 4 row-tiles x 1KB
    __shared__ __align__(16) bf16_t Bs2[8192];    // 2 buf x 4 col-tiles x 1KB
    __shared__ float asum[64];
    int wg = (int)blockIdx.x;                     // 0..895
    int xcd = wg & 7, idx = wg >> 3;              // 112 blocks/XCD
    int bm = xcd * 8 + (idx & 7);                 // 0..63 M-tile (64 rows)
    int bn = idx >> 3;                            // 0..13 N-tile (64 cols)
    int tid = threadIdx.x, lane = tid & 63, w = tid >> 6;
    const bf16_t* aw = A  + (((size_t)(bm * 4 + w) * KTILES) << 9) + lane * 8;
    const bf16_t* bw = Bt + (((size_t)(bn * 4 + w) * KTILES) << 9) + lane * 8;
    f32x4 acc[4];
    #pragma unroll
    for (int j = 0; j < 4; ++j) acc[j] = (f32x4){0.f, 0.f, 0.f, 0.f};
    auto stage = [&](int kk) {
        int b = kk & 1;
        size_t go = (size_t)kk * 1024;
        g2l16(aw + go,       &As2[b * 4096 + w * 1024]);
        g2l16(aw + go + 512, &As2[b * 4096 + w * 1024 + 512]);
        g2l16(bw + go,       &Bs2[b * 4096 + w * 1024]);
        g2l16(bw + go + 512, &Bs2[b * 4096 + w * 1024 + 512]);
    };
    stage(0); stage(1);
    asm volatile("s_waitcnt vmcnt(4)" ::: "memory");
    __builtin_amdgcn_s_barrier();
    for (int kk = 0; kk < nk; ++kk) {
        const bf16_t* cA = &As2[(kk & 1) * 4096];
        const bf16_t* cB = &Bs2[(kk & 1) * 4096];
        bf16x8 af[2], bq[4][2];
        #pragma unroll
        for (int h = 0; h < 2; ++h)
            af[h] = *(const bf16x8*)(cA + w * 1024 + h * 512 + lane * 8);
        #pragma unroll
        for (int j = 0; j < 4; ++j)
            #pragma unroll
            for (int h = 0; h < 2; ++h)
                bq[j][h] = *(const bf16x8*)(cB + j * 1024 + h * 512 + lane * 8);
        asm volatile("s_waitcnt lgkmcnt(0)" ::: "memory");
        __builtin_amdgcn_s_barrier();
        if (kk + 2 < nk) stage(kk + 2);
        #pragma unroll
        for (int h = 0; h < 2; ++h)
            #pragma unroll
            for (int j = 0; j < 4; ++j)
                acc[j] = mfma16(bq[j][h], af[h], acc[j]);
        if (kk + 2 < nk) asm volatile("s_waitcnt vmcnt(4)" ::: "memory");
        else             asm volatile("s_waitcnt vmcnt(0)" ::: "memory");
        __builtin_amdgcn_s_barrier();
    }
    // ---- fused c0-reduce epilogue ----
    size_t row0 = (size_t)bm * 64;
    bool isU = (int)row0 < n;   // row0 multiple of 64; n multiple of 64
    const float* p = isU ? ubn : lbn;
    const float* q = isU ? lbn : ubn;
    int ocol = (lane >> 4) * 4;
    float ra = 0.f;
    #pragma unroll
    for (int j = 0; j < 4; ++j) {
        int gc = bn * 64 + j * 16 + ocol;
        f32x4 p0 = *(const f32x4*)(p + gc);
        f32x4 q0 = *(const f32x4*)(q + gc);
        #pragma unroll
        for (int rg = 0; rg < 4; ++rg) {
            float v = acc[j][rg];
            ra += fmaxf(v, 0.f) * p0[rg] + fminf(v, 0.f) * q0[rg];
        }
    }
    ra += __shfl_xor(ra, 16, 64);
    ra += __shfl_xor(ra, 32, 64);
    if (lane < 16) asum[w * 16 + lane] = ra;
    __syncthreads();
    if (tid < 64) atomicAdd(&av[row0 + tid], asum[tid]);
}

// ---------------- host launch ----------------

extern "C" void kernel_launch(void* const* d_in, const int* in_sizes, int n_in,
                              void* d_out, int out_size, void* d_ws, size_t ws_size,
                              hipStream_t stream) {
    (void)in_sizes; (void)n_in; (void)out_size; (void)ws_size;
    const float* x   = (const float*)d_in[0];
    const float* eps = (const float*)d_in[1];
    const float* W1  = (const float*)d_in[2];
    const float* B1  = (const float*)d_in[3];
    const float* W2  = (const float*)d_in[4];
    const float* B2  = (const float*)d_in[5];
    const float* W3  = (const float*)d_in[6];
    const float* B3  = (const float*)d_in[7];
    const float* W4  = (const float*)d_in[8];
    const float* B4  = (const float*)d_in[9];
    float* out = (float*)d_out;

    const int H = 2048, DIN = 784, DOUT = 10;
    const int NP1 = 896;           // DIN padded to x128
    const int MP4 = 32;            // layer-4 row pad (20 real rows)

    float* ws = (float*)d_ws;
    size_t off = 0;
    auto alloc = [&](size_t nf) -> float* {
        float* p = ws + off;
        off += (nf + 3) & ~(size_t)3;
        return p;
    };
    float* ubn = alloc(NP1);
    float* lbn = alloc(NP1);
    float* us1 = alloc(H); float* ui1 = alloc(H); float* ls1 = alloc(H); float* li1 = alloc(H);
    float* pU1 = alloc(H); float* pL1 = alloc(H);
    float* iU2 = alloc(H); float* iL2 = alloc(H);
    float* us2 = alloc(H); float* ui2 = alloc(H); float* ls2 = alloc(H); float* li2 = alloc(H);
    float* pU2 = alloc(H); float* pL2 = alloc(H);
    float* iU3 = alloc(H); float* iL3 = alloc(H);
    float* us3 = alloc(H); float* ui3 = alloc(H); float* ls3 = alloc(H); float* li3 = alloc(H);
    float* pU3 = alloc(H); float* pL3 = alloc(H);
    float* iU4 = alloc(32); float* iL4 = alloc(32);
    float* av  = alloc(2 * H);
    bf16_t* Ab  = (bf16_t*)alloc((size_t)2 * H * H / 2);       // 4096 x 2048 bf16 swz
    bf16_t* Ab2 = (bf16_t*)alloc((size_t)2 * H * H / 2);       // second operand buffer
    bf16_t* W1t = (bf16_t*)alloc((size_t)NP1 * H / 2);
    bf16_t* W2t = (bf16_t*)alloc((size_t)H * H / 2);
    bf16_t* W3t = (bf16_t*)alloc((size_t)H * H / 2);
    bf16_t* Cs  = (bf16_t*)alloc((size_t)16 * MP4 * H / 2);    // L4 split-16 slabs (bf16)

    dim3 blk(256);

    // weight transpose/convert/swizzle (merged) + input bounds side-block
    k_wT3<<<dim3(32, 32, 3), blk, 0, stream>>>(W1, W2, W3, W1t, W2t, W3t,
                                               x, eps, ubn, lbn);

    size_t ss4H = (size_t)MP4 * H;          // layer-4 N=H slab (32 x 2048)
    size_t ss4N = (size_t)MP4 * NP1;        // layer-4 N=NP1 slab (32 x 896)

    // ======== Layer 1 (fused interval + spu) ========
    k_interval_spu<<<dim3(H / 4), blk, 0, stream>>>(W1, B1, ubn, lbn, DIN, H,
        us1, ui1, ls1, li1, pU1, pL1);

    // ======== Layer 2 ========
    k_prep16<<<dim3(2 * H / 16), blk, 0, stream>>>(W2, B2, H,
        us1, ui1, ls1, li1, B1, pU1, pL1, Ab, av, iU2, iL2);
    k_gemm16_red<<<dim3(896), blk, 0, stream>>>(Ab, W1t, H,
        ubn, lbn, av, KTILES / 2);
    k_spu2<<<dim3(H / 64), dim3(64), 0, stream>>>(iU2, iL2, av, H,
        us2, ui2, ls2, li2, pU2, pL2);

    // ======== Layer 3 ========
    k_prep16<<<dim3(2 * H / 16), blk, 0, stream>>>(W3, B3, H,
        us2, ui2, ls2, li2, B2, pU2, pL2, Ab, av, iU3, iL3);
    k_gemm16_mix<<<dim3(2 * H / 128, H / 128), dim3(512), 0, stream>>>(Ab, W2t, H,
        us1, ui1, ls1, li1, B1, Ab2, av, KTILES / 2);
    k_gemm16_red<<<dim3(896), blk, 0, stream>>>(Ab2, W1t, H,
        ubn, lbn, av, KTILES / 2);
    k_spu2<<<dim3(H / 64), dim3(64), 0, stream>>>(iU3, iL3, av, H,
        us3, ui3, ls3, li3, pU3, pL3);

    // ======== Layer 4 (M = 20 padded to 32, split-K 16, colmix k-split 16) ========
    k_prep16<<<dim3(MP4 / 16), blk, 0, stream>>>(W4, B4, DOUT,
        us3, ui3, ls3, li3, B3, pU3, pL3, Ab, av, iU4, iL4);
    k_gemm16s<<<dim3(H / 128, 1, 16), blk, 0, stream>>>(Ab, W3t, Cs, H, ss4H, 2);
    k_colmix16<<<dim3(MP4 / 16, 16), blk, 0, stream>>>(Cs, H, 16, ss4H, DOUT, KTILES / 16,
        us2, ui2, ls2, li2, B2, Ab2, av);
    k_gemm16s<<<dim3(H / 128, 1, 16), blk, 0, stream>>>(Ab2, W2t, Cs, H, ss4H, 2);
    k_colmix16<<<dim3(MP4 / 16, 16), blk, 0, stream>>>(Cs, H, 16, ss4H, DOUT, KTILES / 16,
        us1, ui1, ls1, li1, B1, Ab, av);
    k_gemm16s<<<dim3(NP1 / 128, 1, 16), blk, 0, stream>>>(Ab, W1t, Cs, NP1, ss4N, 2);
    k_reduce16f<<<dim3(1), dim3(640), 0, stream>>>(Cs, NP1, DIN, DOUT, 16, ss4N,
        av, ubn, lbn, iL4, out);
}

// Round 12
// 295.094 us; speedup vs baseline: 1.1778x; 1.0230x over previous
//
#include <hip/hip_runtime.h>
#include <cstdint>
#include <cstddef>

#define MEAN_C 0.1307f
#define SIGMA_C 0.3081f
#define SIG_SCALE_C 5.0f

typedef __bf16 bf16_t;
typedef __bf16 bf16x8 __attribute__((ext_vector_type(8)));
typedef __bf16 bf16x4 __attribute__((ext_vector_type(4)));
typedef float f32x4 __attribute__((ext_vector_type(4)));

__device__ __forceinline__ f32x4 mfma16(bf16x8 a, bf16x8 b, f32x4 c) {
    return __builtin_amdgcn_mfma_f32_16x16x32_bf16(a, b, c, 0, 0, 0);
}

typedef const __attribute__((address_space(1))) void* gvp;
typedef __attribute__((address_space(3))) void* lvp;
__device__ __forceinline__ void g2l16(const void* g, void* l) {
    __builtin_amdgcn_global_load_lds((gvp)g, (lvp)l, 16, 0, 0);
}

// swizzled bf16 operand layout: 16x32 tiles (1KB); chunk index within tile =
// lane = (k-chunk)*16 + row  (16B each). offset(r,k), K = ktiles*32.
__device__ __forceinline__ size_t swz(int r, int k, int ktiles) {
    return (((size_t)(r >> 4) * ktiles + (k >> 5)) << 9)
         + (((k >> 3) & 3) << 7) + ((r & 15) << 3) + (k & 7);
}

#define KTILES 64   // K = 2048

// ---------------- device helpers ----------------

__device__ __forceinline__ float sigmoidf_(float x) {
    if (x >= 0.f) { float e = __expf(-x); return 1.f / (1.f + e); }
    float e = __expf(x); return e / (1.f + e);
}

__device__ __forceinline__ float spu_f(float x) {
    return (x >= 0.f) ? (x * x - 0.5f) : (sigmoidf_(-x) - 1.f);
}

__device__ __forceinline__ float wave_sum(float a) {
    #pragma unroll
    for (int o = 32; o > 0; o >>= 1) a += __shfl_xor(a, o, 64);
    return a;
}

// full analyze_spu for one neuron i.
__device__ __forceinline__ void spu_body(int i, int n,
        float iUi, float iLi, float vU, float vL,
        float* __restrict__ us, float* __restrict__ ui,
        float* __restrict__ ls, float* __restrict__ li,
        float* __restrict__ pU, float* __restrict__ pL) {
    float ux = fminf(iUi, vU);
    float lx = fmaxf(iLi, vL);
    float uy = spu_f(ux), ly = spu_f(lx);
    float new_ub = fmaxf(uy, ly);
    float sj = (uy - ly) / (ux - lx);
    float ij = uy - sj * ux;
    bool right = lx > 0.f;
    bool left = ux <= 0.f;
    float mid = 0.5f * (ux + lx);
    float sp = 2.f * mid, ip = -mid * mid - 0.5f;
    float sm = sigmoidf_(mid);
    float ssm = -sm * (1.f - sm);
    float ism = -sm - ssm * mid;
    bool crossing = (!left) && (!right);
    float new_lb = crossing ? -0.5f : fminf(uy, ly);
    float spu_s = 2.f * ux, ipu = -ux * ux - 0.5f;
    float limit = spu_s * lx + ipu;
    float clm = (fabsf(lx) > ux) ? 1.f : 0.f;
    float clp = sigmoidf_((clm - 0.5f) * 2.f * SIG_SCALE_C) * (ly - limit) + limit;
    bool ptm = clp < -0.5f;
    float D = 4.f * lx * lx - 4.f * clp - 2.f;
    float x2 = (2.f * lx + sqrtf(fmaxf(D, 0.f))) * 0.5f;
    float spt = 2.f * x2, ipt = -x2 * x2 - 0.5f;
    float sjn = (clp + 0.5f) / lx;
    float ijn = -0.5f;
    float s_cl = ptm ? spt : sjn;
    float i_cl = ptm ? ipt : ijn;
    float sl = sigmoidf_(lx);
    float ssl = -sl * (1.f - sl);
    float isl = -sl - ssl * lx;
    float stv = ssl * ux + isl - uy;
    float Lb = lx, Rb = 0.f;
    #pragma unroll
    for (int t = 0; t < 10; ++t) {
        float mm = 0.5f * (Lb + Rb);
        float smm = sigmoidf_(mm);
        float sms = -smm * (1.f - smm);
        float smi = -smm - sms * mm;
        bool mask = (sms * ux + smi - uy) > 0.f;
        Lb = mask ? mm : Lb;
        Rb = mask ? Rb : mm;
    }
    float scp = sigmoidf_(-SIG_SCALE_C) * (Lb - lx) + lx;
    float sc = sigmoidf_(scp);
    float ssc = -sc * (1.f - sc);
    float isc = -sc - ssc * scp;
    bool up = stv > 0.f;
    float s_cu = up ? ssc : sj;
    float i_cu = up ? isc : ij;
    float usv, uiv, lsv, liv;
    if (right)      { usv = sj;   uiv = ij;   lsv = sp;   liv = ip;   }
    else if (left)  { usv = ssm;  uiv = ism;  lsv = sj;   liv = ij;   }
    else            { usv = s_cu; uiv = i_cu; lsv = s_cl; liv = i_cl; }
    us[i] = usv; ui[i] = uiv; ls[i] = lsv; li[i] = liv;
    float vu = (usv >= 0.f) ? vU : vL;
    float vl = (lsv >= 0.f) ? vL : vU;
    pU[i] = fminf(new_ub, usv * vu + uiv);
    pL[i] = fmaxf(new_lb, lsv * vl + liv);
}

// ---------------- small kernels ----------------

// fused layer-1 interval bound + analyze_spu
__global__ __launch_bounds__(256) void k_interval_spu(
        const float* __restrict__ W, const float* __restrict__ b,
        const float* __restrict__ U, const float* __restrict__ L,
        int m, int n,
        float* __restrict__ us, float* __restrict__ ui,
        float* __restrict__ ls, float* __restrict__ li,
        float* __restrict__ pU, float* __restrict__ pL) {
    int r = (blockIdx.x << 2) + (threadIdx.x >> 6);
    if (r >= n) return;
    int lane = threadIdx.x & 63;
    const f32x4* Wr = (const f32x4*)(W + (size_t)r * m);
    const f32x4* U4 = (const f32x4*)U;
    const f32x4* L4 = (const f32x4*)L;
    int nf4 = m >> 2;
    float au = 0.f, al = 0.f;
    for (int j = lane; j < nf4; j += 64) {
        f32x4 wv = Wr[j], uu = U4[j], ll = L4[j];
        #pragma unroll
        for (int u = 0; u < 4; ++u) {
            float w = wv[u];
            float hi = (w > 0.f) ? uu[u] : ll[u];
            float lo2 = (w > 0.f) ? ll[u] : uu[u];
            au = fmaf(w, hi, au);
            al = fmaf(w, lo2, al);
        }
    }
    au = wave_sum(au); al = wave_sum(al);
    if (lane == 0) {
        float vU = au + b[r], vL = al + b[r];
        spu_body(r, n, vU, vL, vU, vL, us, ui, ls, li, pU, pL);
    }
}

// standalone spu (layers 2/3)
__global__ void k_spu2(const float* __restrict__ iU, const float* __restrict__ iL,
                       const float* __restrict__ vraw, int n,
                       float* __restrict__ us, float* __restrict__ ui,
                       float* __restrict__ ls, float* __restrict__ li,
                       float* __restrict__ pU, float* __restrict__ pL) {
    int i = blockIdx.x * blockDim.x + threadIdx.x;
    if (i >= n) return;
    spu_body(i, n, iU[i], iL[i], vraw[i], vraw[n + i], us, ui, ls, li, pU, pL);
}

// ---------------- bf16 producers ----------------

// merged transpose/convert/swizzle of W1,W2,W3 + input-bounds side block.
__global__ __launch_bounds__(256) void k_wT3(
        const float* __restrict__ W1, const float* __restrict__ W2,
        const float* __restrict__ W3,
        bf16_t* __restrict__ W1t, bf16_t* __restrict__ W2t, bf16_t* __restrict__ W3t,
        const float* __restrict__ x, const float* __restrict__ eps,
        float* __restrict__ ubn, float* __restrict__ lbn) {
    __shared__ bf16_t t[64 * 65];
    int z = blockIdx.z;
    const float* W; int N, ldw; bf16_t* Wt;
    if (z == 0)      { W = W2; N = 2048; ldw = 2048; Wt = W2t; }
    else if (z == 1) { W = W3; N = 2048; ldw = 2048; Wt = W3t; }
    else {
        W = W1; N = 784; ldw = 784; Wt = W1t;
        if (blockIdx.y >= 14) {
            if (blockIdx.y == 14 && blockIdx.x == 0) {
                for (int i = threadIdx.x; i < 896; i += 256) {
                    if (i >= 784) { ubn[i] = 0.f; lbn[i] = 0.f; }
                    else {
                        float e = eps[0];
                        float ub = fminf(x[i] + e, 1.f);
                        float lb = fmaxf(x[i] - e, 0.f);
                        ubn[i] = (ub - MEAN_C) / SIGMA_C;
                        lbn[i] = (lb - MEAN_C) / SIGMA_C;
                    }
                }
            }
            return;
        }
    }
    int k0 = blockIdx.x * 64, n0 = blockIdx.y * 64;
    int tid = threadIdx.x;
    int rg = tid >> 4;            // 0..15 row sub-index
    int cg = (tid & 15) * 4;      // column start (f32x4)
    bool fast = (n0 + 64 <= N);
    #pragma unroll
    for (int it = 0; it < 4; ++it) {
        int row = it * 16 + rg;   // local k
        const float* Wr = W + (size_t)(k0 + row) * ldw + n0 + cg;
        float v0, v1, v2, v3;
        if (fast) {
            f32x4 vv = *(const f32x4*)Wr;
            v0 = vv[0]; v1 = vv[1]; v2 = vv[2]; v3 = vv[3];
        } else {
            v0 = (n0 + cg + 0 < N) ? Wr[0] : 0.f;
            v1 = (n0 + cg + 1 < N) ? Wr[1] : 0.f;
            v2 = (n0 + cg + 2 < N) ? Wr[2] : 0.f;
            v3 = (n0 + cg + 3 < N) ? Wr[3] : 0.f;
        }
        t[(cg + 0) * 65 + row] = (bf16_t)v0;
        t[(cg + 1) * 65 + row] = (bf16_t)v1;
        t[(cg + 2) * 65 + row] = (bf16_t)v2;
        t[(cg + 3) * 65 + row] = (bf16_t)v3;
    }
    __syncthreads();
    #pragma unroll
    for (int p = 0; p < 2; ++p) {
        int c = tid + p * 256;
        int lr = c & 63, lq = c >> 6;
        bf16x8 v;
        #pragma unroll
        for (int u = 0; u < 8; ++u) v[u] = t[lr * 65 + lq * 8 + u];
        *(bf16x8*)(Wt + swz(n0 + lr, k0 + lq * 8, KTILES)) = v;
    }
}

// prep (fused interval-affine)
__global__ __launch_bounds__(256) void k_prep16(
        const float* __restrict__ W, const float* __restrict__ b, int n,
        const float* __restrict__ cus, const float* __restrict__ cui,
        const float* __restrict__ cls, const float* __restrict__ cli,
        const float* __restrict__ bvec,
        const float* __restrict__ U, const float* __restrict__ L,
        bf16_t* __restrict__ Ab, float* __restrict__ av,
        float* __restrict__ iU, float* __restrict__ iL) {
    int rt = blockIdx.x;
    int tid = threadIdx.x, lane = tid & 63, wid = tid >> 6;
    int mrow = lane & 15, q = lane >> 4;
    int r = rt * 16 + mrow;
    bool act = r < 2 * n;
    bool isU = r < n;
    int i = act ? (isU ? r : r - n) : 0;
    float gate = act ? 1.f : 0.f;
    const float* Wr = W + (size_t)i * 2048;
    const float* ps = isU ? cus : cls;
    const float* ns = isU ? cls : cus;
    const float* yi = isU ? cui : cli;
    const float* zi = isU ? cli : cui;
    const float* hi = isU ? U : L;
    const float* lo = isU ? L : U;
    float a = 0.f, a2 = 0.f;
    bf16_t* Abase = Ab + ((size_t)rt * KTILES) * 512 + lane * 8;
    for (int kt = wid; kt < KTILES; kt += 4) {
        int k0 = kt * 32 + q * 8;
        bf16x8 ov;
        #pragma unroll
        for (int h = 0; h < 2; ++h) {
            int kb = k0 + 4 * h;
            f32x4 wv = *(const f32x4*)(Wr + kb);
            f32x4 p0 = *(const f32x4*)(ps + kb);
            f32x4 q0 = *(const f32x4*)(ns + kb);
            f32x4 y0 = *(const f32x4*)(yi + kb);
            f32x4 z0 = *(const f32x4*)(zi + kb);
            f32x4 c0 = *(const f32x4*)(bvec + kb);
            f32x4 h0 = *(const f32x4*)(hi + kb);
            f32x4 l0 = *(const f32x4*)(lo + kb);
            #pragma unroll
            for (int u = 0; u < 4; ++u) {
                float w = gate * wv[u];
                float pos = fmaxf(w, 0.f), neg = fminf(w, 0.f);
                float mx = pos * p0[u] + neg * q0[u];
                ov[4 * h + u] = (bf16_t)mx;
                a += pos * y0[u] + neg * z0[u] + mx * c0[u];
                a2 += pos * h0[u] + neg * l0[u];   // interval dot
            }
        }
        *(bf16x8*)(Abase + (size_t)kt * 512) = ov;
    }
    a += __shfl_xor(a, 16, 64);  a += __shfl_xor(a, 32, 64);
    a2 += __shfl_xor(a2, 16, 64); a2 += __shfl_xor(a2, 32, 64);
    __shared__ float sh[2][4][16];
    if (lane < 16) { sh[0][wid][lane] = a; sh[1][wid][lane] = a2; }
    __syncthreads();
    if (tid < 16) {
        int r2 = rt * 16 + tid;
        float ta = sh[0][0][tid] + sh[0][1][tid] + sh[0][2][tid] + sh[0][3][tid];
        float tb = sh[1][0][tid] + sh[1][1][tid] + sh[1][2][tid] + sh[1][3][tid];
        if (r2 < 2 * n) {
            bool isU2 = r2 < n;
            int i2 = isU2 ? r2 : r2 - n;
            av[r2] = ta + b[i2];
            if (isU2) iU[i2] = tb + b[i2];
            else      iL[i2] = tb + b[i2];
        } else {
            av[r2] = 0.f;
        }
    }
}

// colmix (layer-4 small-M chains): bf16 split slabs -> swizzled bf16 Ab
__global__ __launch_bounds__(256) void k_colmix16(
        const bf16_t* __restrict__ Cb, int ldc, int splits, size_t sstride, int n,
        int tpb,
        const float* __restrict__ cus, const float* __restrict__ cui,
        const float* __restrict__ cls, const float* __restrict__ cli,
        const float* __restrict__ bvec,
        bf16_t* __restrict__ Ab, float* __restrict__ av) {
    int rt = blockIdx.x;
    int kt0 = blockIdx.y * tpb;
    int tid = threadIdx.x, lane = tid & 63, wid = tid >> 6;
    int mrow = lane & 15, q = lane >> 4;
    int r = rt * 16 + mrow;
    bool isU = r < n;
    const bf16_t* Cr = Cb + (size_t)r * ldc;
    const float* ps = isU ? cus : cls;
    const float* ns = isU ? cls : cus;
    const float* yi = isU ? cui : cli;
    const float* zi = isU ? cli : cui;
    float a = 0.f;
    bf16_t* Abase = Ab + ((size_t)rt * KTILES) * 512 + lane * 8;
    for (int kt = kt0 + wid; kt < kt0 + tpb; kt += 4) {
        int k0 = kt * 32 + q * 8;
        float wsum[8] = {0.f, 0.f, 0.f, 0.f, 0.f, 0.f, 0.f, 0.f};
        for (int s = 0; s < splits; ++s) {
            bf16x8 v = *(const bf16x8*)(Cr + s * sstride + k0);
            #pragma unroll
            for (int u = 0; u < 8; ++u) wsum[u] += (float)v[u];
        }
        f32x4 p0 = *(const f32x4*)(ps + k0), p1 = *(const f32x4*)(ps + k0 + 4);
        f32x4 q0 = *(const f32x4*)(ns + k0), q1 = *(const f32x4*)(ns + k0 + 4);
        f32x4 y0 = *(const f32x4*)(yi + k0), y1 = *(const f32x4*)(yi + k0 + 4);
        f32x4 z0 = *(const f32x4*)(zi + k0), z1 = *(const f32x4*)(zi + k0 + 4);
        f32x4 c0 = *(const f32x4*)(bvec + k0), c1 = *(const f32x4*)(bvec + k0 + 4);
        bf16x8 ov;
        #pragma unroll
        for (int u = 0; u < 4; ++u) {
            float w = wsum[u];
            float pos = fmaxf(w, 0.f), neg = fminf(w, 0.f);
            float mx = pos * p0[u] + neg * q0[u];
            ov[u] = (bf16_t)mx;
            a += pos * y0[u] + neg * z0[u] + mx * c0[u];
        }
        #pragma unroll
        for (int u = 0; u < 4; ++u) {
            float w = wsum[4 + u];
            float pos = fmaxf(w, 0.f), neg = fminf(w, 0.f);
            float mx = pos * p1[u] + neg * q1[u];
            ov[4 + u] = (bf16_t)mx;
            a += pos * y1[u] + neg * z1[u] + mx * c1[u];
        }
        *(bf16x8*)(Abase + (size_t)kt * 512) = ov;
    }
    a += __shfl_xor(a, 16, 64);
    a += __shfl_xor(a, 32, 64);
    __shared__ float sh[4][16];
    if (lane < 16) sh[wid][lane] = a;
    __syncthreads();
    if (tid < 16) {
        float tot = sh[0][tid] + sh[1][tid] + sh[2][tid] + sh[3][tid];
        atomicAdd(&av[rt * 16 + tid], tot);
    }
}

// final c0 step + min, fused, single block of 10 waves (one wave per L row).
__global__ __launch_bounds__(640) void k_reduce16f(
        const bf16_t* __restrict__ Cb, int ldc, int m, int n,
        int splits, size_t sstride,
        const float* __restrict__ av,
        const float* __restrict__ ubn, const float* __restrict__ lbn,
        const float* __restrict__ iL,
        float* __restrict__ out) {
    __shared__ float sbl[16];
    int tid = threadIdx.x, lane = tid & 63, wv = tid >> 6;   // 10 waves
    int nch = m >> 3;   // m % 8 == 0
    int i = wv;          // 0..9 == DOUT rows
    int r = n + i;       // L rows only
    const bf16_t* Cr = Cb + (size_t)r * ldc;
    const float* p = lbn;
    const float* q = ubn;
    float a = 0.f;
    for (int c = lane; c < nch; c += 64) {
        float wsum[8] = {0.f, 0.f, 0.f, 0.f, 0.f, 0.f, 0.f, 0.f};
        for (int s = 0; s < splits; ++s) {
            bf16x8 v = *(const bf16x8*)(Cr + s * sstride + c * 8);
            #pragma unroll
            for (int u = 0; u < 8; ++u) wsum[u] += (float)v[u];
        }
        f32x4 p0 = *(const f32x4*)(p + c * 8), p1 = *(const f32x4*)(p + c * 8 + 4);
        f32x4 q0 = *(const f32x4*)(q + c * 8), q1 = *(const f32x4*)(q + c * 8 + 4);
        #pragma unroll
        for (int u = 0; u < 4; ++u) {
            a += fmaxf(wsum[u], 0.f) * p0[u] + fminf(wsum[u], 0.f) * q0[u];
            a += fmaxf(wsum[4 + u], 0.f) * p1[u] + fminf(wsum[4 + u], 0.f) * q1[u];
        }
    }
    a = wave_sum(a);
    if (lane == 0) sbl[i] = fmaxf(iL[i], a + av[r]);
    __syncthreads();
    if (tid < 64) {
        float v = 3.4e38f;
        for (int j = lane; j < n; j += 64) v = fminf(v, sbl[j]);
        #pragma unroll
        for (int o = 32; o > 0; o >>= 1) v = fminf(v, __shfl_down(v, o, 64));
        if (lane == 0) out[0] = v;
    }
}

// ---- L4 small-M GEMM: 32x128 tile, 256 thr / 4 waves, split-K slabs ----
__global__ __launch_bounds__(256) void k_gemm16s(
        const bf16_t* __restrict__ A, const bf16_t* __restrict__ Bt,
        bf16_t* __restrict__ C, int ldc, size_t sstride, int nk) {
    __shared__ __align__(16) bf16_t As2[8192];    // 2 buf x 4KB (32 rows x BK64)
    __shared__ __align__(16) bf16_t Bs2[32768];   // 2 buf x 16KB (128 cols x BK64)
    int bn = blockIdx.x;
    int kt0 = blockIdx.z * nk * 2;
    int tid = threadIdx.x, lane = tid & 63, w = tid >> 6;
    const bf16_t* aw = A +
        (((size_t)(w >> 1) * KTILES + kt0 + (w & 1)) << 9) + lane * 8;
    const bf16_t* bt0 = Bt +
        (((size_t)(bn * 8 + 2 * w) * KTILES + kt0) << 9) + lane * 8;
    const bf16_t* bt1 = Bt +
        (((size_t)(bn * 8 + 2 * w + 1) * KTILES + kt0) << 9) + lane * 8;
    f32x4 acc[2][2];
    #pragma unroll
    for (int i = 0; i < 2; ++i)
        #pragma unroll
        for (int j = 0; j < 2; ++j) acc[i][j] = (f32x4){0.f, 0.f, 0.f, 0.f};
    auto stage = [&](int kk) {
        int b = kk & 1;
        size_t go = (size_t)kk * 1024;
        g2l16(aw + go,        &As2[b * 4096 + w * 1024]);
        g2l16(bt0 + go,       &Bs2[b * 16384 + (4 * w + 0) * 1024]);
        g2l16(bt0 + go + 512, &Bs2[b * 16384 + (4 * w + 1) * 1024]);
        g2l16(bt1 + go,       &Bs2[b * 16384 + (4 * w + 2) * 1024]);
        g2l16(bt1 + go + 512, &Bs2[b * 16384 + (4 * w + 3) * 1024]);
    };
    stage(0); stage(1);
    asm volatile("s_waitcnt vmcnt(5)" ::: "memory");
    __builtin_amdgcn_s_barrier();
    for (int kk = 0; kk < nk; ++kk) {
        const bf16_t* cA = &As2[(kk & 1) * 4096];
        const bf16_t* cB = &Bs2[(kk & 1) * 16384];
        bf16x8 af[2][2], bq[2][2];
        #pragma unroll
        for (int i = 0; i < 2; ++i)
            #pragma unroll
            for (int h = 0; h < 2; ++h) {
                af[i][h] = *(const bf16x8*)(cA + (i * 2 + h) * 1024 + lane * 8);
                bq[i][h] = *(const bf16x8*)(cB + (4 * w + i * 2 + h) * 1024 + lane * 8);
            }
        asm volatile("s_waitcnt lgkmcnt(0)" ::: "memory");
        __builtin_amdgcn_s_barrier();
        if (kk + 2 < nk) stage(kk + 2);
        #pragma unroll
        for (int h = 0; h < 2; ++h)
            #pragma unroll
            for (int i = 0; i < 2; ++i)
                #pragma unroll
                for (int j = 0; j < 2; ++j)
                    acc[i][j] = mfma16(bq[j][h], af[i][h], acc[i][j]);
        if (kk + 2 < nk) asm volatile("s_waitcnt vmcnt(5)" ::: "memory");
        else             asm volatile("s_waitcnt vmcnt(0)" ::: "memory");
        __builtin_amdgcn_s_barrier();
    }
    bf16_t* Cz = C + (size_t)blockIdx.z * sstride;
    int orow = lane & 15, ocol = (lane >> 4) * 4;
    #pragma unroll
    for (int i = 0; i < 2; ++i) {
        int gr = i * 16 + orow;
        #pragma unroll
        for (int j = 0; j < 2; ++j) {
            int gc = bn * 128 + w * 32 + j * 16 + ocol;
            bf16x4 v;
            #pragma unroll
            for (int rg = 0; rg < 4; ++rg) v[rg] = (bf16_t)acc[i][j][rg];
            *(bf16x4*)(Cz + (size_t)gr * ldc + gc) = v;
        }
    }
}

// ---- 512-thr 8-wave BK=64 mid-barrier distance-2 pipe (128x128 tile) ----
#define GEMM_PIPE8()                                                           \
    int tid = threadIdx.x, lane = tid & 63, w = tid >> 6;      /* 0..7 */      \
    int wm = w >> 2, wn = w & 3;                                               \
    f32x4 acc[4][2];                                                           \
    _Pragma("unroll")                                                          \
    for (int i = 0; i < 4; ++i)                                                \
        _Pragma("unroll")                                                      \
        for (int j = 0; j < 2; ++j) acc[i][j] = (f32x4){0.f, 0.f, 0.f, 0.f};   \
    auto stage = [&](int kk) {                                                 \
        int b = kk & 1;                                                        \
        size_t go = (size_t)kk * 1024;                                         \
        bf16_t* la = &As2[b * 8192 + w * 1024];                                \
        bf16_t* lb = &Bs2[b * 8192 + w * 1024];                                \
        g2l16(a0 + go, la);   g2l16(a0 + go + 512, la + 512);                  \
        g2l16(b0 + go, lb);   g2l16(b0 + go + 512, lb + 512);                  \
    };                                                                         \
    stage(0); stage(1);                                                        \
    asm volatile("s_waitcnt vmcnt(4)" ::: "memory");                           \
    __builtin_amdgcn_s_barrier();                                              \
    for (int kk = 0; kk < nk; ++kk) {                                          \
        const bf16_t* cA = &As2[(kk & 1) * 8192];                              \
        const bf16_t* cB = &Bs2[(kk & 1) * 8192];                              \
        bf16x8 af0[4], af1[4], bq0[2], bq1[2];                                 \
        _Pragma("unroll")                                                      \
        for (int i = 0; i < 4; ++i) {                                          \
            af0[i] = *(const bf16x8*)(cA + (wm * 4 + i) * 1024 + lane * 8);    \
            af1[i] = *(const bf16x8*)(cA + (wm * 4 + i) * 1024 + 512 + lane * 8); \
        }                                                                      \
        _Pragma("unroll")                                                      \
        for (int j = 0; j < 2; ++j) {                                          \
            bq0[j] = *(const bf16x8*)(cB + (wn * 2 + j) * 1024 + lane * 8);    \
            bq1[j] = *(const bf16x8*)(cB + (wn * 2 + j) * 1024 + 512 + lane * 8); \
        }                                                                      \
        asm volatile("s_waitcnt lgkmcnt(0)" ::: "memory");                     \
        __builtin_amdgcn_s_barrier();                                          \
        if (kk + 2 < nk) stage(kk + 2);                                        \
        _Pragma("unroll")                                                      \
        for (int i = 0; i < 4; ++i)                                            \
            _Pragma("unroll")                                                  \
            for (int j = 0; j < 2; ++j)                                        \
                acc[i][j] = mfma16(bq0[j], af0[i], acc[i][j]);                 \
        _Pragma("unroll")                                                      \
        for (int i = 0; i < 4; ++i)                                            \
            _Pragma("unroll")                                                  \
            for (int j = 0; j < 2; ++j)                                        \
                acc[i][j] = mfma16(bq1[j], af1[i], acc[i][j]);                 \
        if (kk + 2 < nk) asm volatile("s_waitcnt vmcnt(4)" ::: "memory");      \
        else             asm volatile("s_waitcnt vmcnt(0)" ::: "memory");      \
        __builtin_amdgcn_s_barrier();                                          \
    }

// GEMM + fused colmix + FUSED INPUT-LAYER RED (layer 3 only).
// R11 insight: Ab2 (mix's output) was consumed ONLY by the red GEMM. Each
// mix block holds its 128x128 bf16 tile at the epilogue -> stash it in LDS
// (As2/Bs2 are dead after the main loop; XOR elem-swizzle c^((r&7)<<3)
// keeps store+frag-read <=2-way) and compute the red partial in-block:
// rows x 896, K = tile cols (128), W1t fragments read directly from global
// (L2-resident, swizzled tile layout = native MFMA fragments, no barriers).
// colmix-ra and red-ra fold into ONE asum/atomicAdd pass (same row mapping).
// Eliminates: Ab2 16MB write + 16MB read + the whole under-occupied red
// launch; adds ~44% MFMA to this kernel.
__global__ __launch_bounds__(512, 4) void k_gemm16_mixred(
        const bf16_t* __restrict__ A, const bf16_t* __restrict__ Bt, int n,
        const float* __restrict__ cus, const float* __restrict__ cui,
        const float* __restrict__ cls, const float* __restrict__ cli,
        const float* __restrict__ bvec,
        const bf16_t* __restrict__ W1t,
        const float* __restrict__ ubn, const float* __restrict__ lbn,
        float* __restrict__ av, int nk) {
    __shared__ __align__(16) bf16_t As2[16384];
    __shared__ __align__(16) bf16_t Bs2[16384];
    __shared__ float asum[4][128];
    int wg = (int)(blockIdx.y * gridDim.x + blockIdx.x);   // 0..511
    int xcd = wg & 7, idx = wg >> 3;                       // 64 blocks/XCD
    int bm = (xcd & 3) * 8 + (idx & 7);                    // 0..31 M-tile
    int bn = (xcd >> 2) * 8 + (idx >> 3);                  // 0..15 N-tile
    int tr0 = bm * 8, tc0 = bn * 8;
    int wtmp = threadIdx.x >> 6, ltmp = threadIdx.x & 63;
    const bf16_t* a0 = A + (((size_t)(tr0 + wtmp) * KTILES) << 9) + ltmp * 8;
    const bf16_t* b0 = Bt + (((size_t)(tc0 + wtmp) * KTILES) << 9) + ltmp * 8;
    GEMM_PIPE8()
    // ---- colmix transform + LDS tile stash ----
    size_t row0 = (size_t)bm * 128;
    size_t col0 = (size_t)bn * 128;
    bool isU = (int)row0 < n;            // whole tile same side (row0 % 128 == 0)
    const float* ps = isU ? cus : cls;
    const float* ns = isU ? cls : cus;
    const float* yi = isU ? cui : cli;
    const float* zi = isU ? cli : cui;
    const float* pb = isU ? ubn : lbn;   // red sign-split bounds
    const float* qb = isU ? lbn : ubn;
    int orow = lane & 15, ocol = (lane >> 4) * 4;
    int sxor = (orow & 7) << 3;          // element-XOR swizzle (16B chunks)
    bf16_t* th = wm ? Bs2 : As2;         // wave's half: rows [wm*64, wm*64+64)
    float rtot[4];
    #pragma unroll
    for (int i = 0; i < 4; ++i) {
        int gr = (int)row0 + wm * 64 + i * 16 + orow;
        int lr = i * 16 + orow;          // row within half (0..63)
        float ra = 0.f;
        #pragma unroll
        for (int j = 0; j < 2; ++j) {
            int gc = (int)col0 + wn * 32 + j * 16 + ocol;
            int lc = wn * 32 + j * 16 + ocol;   // tile-local col (mult of 4)
            f32x4 p0 = *(const f32x4*)(ps + gc);
            f32x4 q0 = *(const f32x4*)(ns + gc);
            f32x4 y0 = *(const f32x4*)(yi + gc);
            f32x4 z0 = *(const f32x4*)(zi + gc);
            f32x4 c0 = *(const f32x4*)(bvec + gc);
            bf16x4 ov;
            #pragma unroll
            for (int rg = 0; rg < 4; ++rg) {
                float v = acc[i][j][rg];
                float pos = fmaxf(v, 0.f), neg = fminf(v, 0.f);
                float mx = pos * p0[rg] + neg * q0[rg];
                ov[rg] = (bf16_t)mx;
                ra += pos * y0[rg] + neg * z0[rg] + mx * c0[rg];
            }
            *(bf16x4*)(th + lr * 128 + (lc ^ sxor)) = ov;
        }
        rtot[i] = ra;
        (void)gr;
    }
    __syncthreads();                     // tile visible to the wn-peers
    // ---- fused red partial: tile(128 rows x 128 K) @ W1t(K x 896) ----
    for (int nc = 0; nc < 7; ++nc) {
        f32x4 acc2[4][2];
        #pragma unroll
        for (int i = 0; i < 4; ++i)
            #pragma unroll
            for (int j = 0; j < 2; ++j) acc2[i][j] = (f32x4){0.f, 0.f, 0.f, 0.f};
        #pragma unroll
        for (int kc = 0; kc < 4; ++kc) {
            bf16x8 bw[2], af2[4];
            #pragma unroll
            for (int j = 0; j < 2; ++j) {
                int nt = nc * 8 + wn * 2 + j;
                bw[j] = *(const bf16x8*)(W1t +
                    (((size_t)nt * KTILES + bn * 4 + kc) << 9) + lane * 8);
            }
            #pragma unroll
            for (int i = 0; i < 4; ++i) {
                int lr = i * 16 + orow;
                int lc = kc * 32 + (lane >> 4) * 8;   // mult of 8
                af2[i] = *(const bf16x8*)(th + lr * 128 + (lc ^ sxor));
            }
            #pragma unroll
            for (int i = 0; i < 4; ++i)
                #pragma unroll
                for (int j = 0; j < 2; ++j)
                    acc2[i][j] = mfma16(bw[j], af2[i], acc2[i][j]);
        }
        // fold with sign-split vs (ubn,lbn)
        #pragma unroll
        for (int i = 0; i < 4; ++i) {
            float ra = 0.f;
            #pragma unroll
            for (int j = 0; j < 2; ++j) {
                int n0 = nc * 128 + (wn * 2 + j) * 16 + (lane >> 4) * 4;
                f32x4 p0 = *(const f32x4*)(pb + n0);
                f32x4 q0 = *(const f32x4*)(qb + n0);
                #pragma unroll
                for (int rg = 0; rg < 4; ++rg) {
                    float v = acc2[i][j][rg];
                    ra += fmaxf(v, 0.f) * p0[rg] + fminf(v, 0.f) * q0[rg];
                }
            }
            rtot[i] += ra;
        }
    }
    // ---- single combined reduction + atomicAdd ----
    #pragma unroll
    for (int i = 0; i < 4; ++i) {
        float ra = rtot[i];
        ra += __shfl_xor(ra, 16, 64);
        ra += __shfl_xor(ra, 32, 64);
        if (lane < 16) asum[wn][wm * 64 + i * 16 + lane] = ra;
    }
    __syncthreads();
    if (tid < 128)
        atomicAdd(&av[row0 + tid],
                  asum[0][tid] + asum[1][tid] + asum[2][tid] + asum[3][tid]);
}

// GEMM + fused final c0-reduce epilogue, 64x64 tile (R11: 896 blocks,
// 3.5/CU, LDS 32KB; layer 2 only).
__global__ __launch_bounds__(256) void k_gemm16_red(
        const bf16_t* __restrict__ A, const bf16_t* __restrict__ Bt, int n,
        const float* __restrict__ ubn, const float* __restrict__ lbn,
        float* __restrict__ av, int nk) {
    __shared__ __align__(16) bf16_t As2[8192];    // 2 buf x 4 row-tiles x 1KB
    __shared__ __align__(16) bf16_t Bs2[8192];    // 2 buf x 4 col-tiles x 1KB
    __shared__ float asum[64];
    int wg = (int)blockIdx.x;                     // 0..895
    int xcd = wg & 7, idx = wg >> 3;              // 112 blocks/XCD
    int bm = xcd * 8 + (idx & 7);                 // 0..63 M-tile (64 rows)
    int bn = idx >> 3;                            // 0..13 N-tile (64 cols)
    int tid = threadIdx.x, lane = tid & 63, w = tid >> 6;
    const bf16_t* aw = A  + (((size_t)(bm * 4 + w) * KTILES) << 9) + lane * 8;
    const bf16_t* bw = Bt + (((size_t)(bn * 4 + w) * KTILES) << 9) + lane * 8;
    f32x4 acc[4];
    #pragma unroll
    for (int j = 0; j < 4; ++j) acc[j] = (f32x4){0.f, 0.f, 0.f, 0.f};
    auto stage = [&](int kk) {
        int b = kk & 1;
        size_t go = (size_t)kk * 1024;
        g2l16(aw + go,       &As2[b * 4096 + w * 1024]);
        g2l16(aw + go + 512, &As2[b * 4096 + w * 1024 + 512]);
        g2l16(bw + go,       &Bs2[b * 4096 + w * 1024]);
        g2l16(bw + go + 512, &Bs2[b * 4096 + w * 1024 + 512]);
    };
    stage(0); stage(1);
    asm volatile("s_waitcnt vmcnt(4)" ::: "memory");
    __builtin_amdgcn_s_barrier();
    for (int kk = 0; kk < nk; ++kk) {
        const bf16_t* cA = &As2[(kk & 1) * 4096];
        const bf16_t* cB = &Bs2[(kk & 1) * 4096];
        bf16x8 af[2], bq[4][2];
        #pragma unroll
        for (int h = 0; h < 2; ++h)
            af[h] = *(const bf16x8*)(cA + w * 1024 + h * 512 + lane * 8);
        #pragma unroll
        for (int j = 0; j < 4; ++j)
            #pragma unroll
            for (int h = 0; h < 2; ++h)
                bq[j][h] = *(const bf16x8*)(cB + j * 1024 + h * 512 + lane * 8);
        asm volatile("s_waitcnt lgkmcnt(0)" ::: "memory");
        __builtin_amdgcn_s_barrier();
        if (kk + 2 < nk) stage(kk + 2);
        #pragma unroll
        for (int h = 0; h < 2; ++h)
            #pragma unroll
            for (int j = 0; j < 4; ++j)
                acc[j] = mfma16(bq[j][h], af[h], acc[j]);
        if (kk + 2 < nk) asm volatile("s_waitcnt vmcnt(4)" ::: "memory");
        else             asm volatile("s_waitcnt vmcnt(0)" ::: "memory");
        __builtin_amdgcn_s_barrier();
    }
    // ---- fused c0-reduce epilogue ----
    size_t row0 = (size_t)bm * 64;
    bool isU = (int)row0 < n;   // row0 multiple of 64; n multiple of 64
    const float* p = isU ? ubn : lbn;
    const float* q = isU ? lbn : ubn;
    int ocol = (lane >> 4) * 4;
    float ra = 0.f;
    #pragma unroll
    for (int j = 0; j < 4; ++j) {
        int gc = bn * 64 + j * 16 + ocol;
        f32x4 p0 = *(const f32x4*)(p + gc);
        f32x4 q0 = *(const f32x4*)(q + gc);
        #pragma unroll
        for (int rg = 0; rg < 4; ++rg) {
            float v = acc[j][rg];
            ra += fmaxf(v, 0.f) * p0[rg] + fminf(v, 0.f) * q0[rg];
        }
    }
    ra += __shfl_xor(ra, 16, 64);
    ra += __shfl_xor(ra, 32, 64);
    if (lane < 16) asum[w * 16 + lane] = ra;
    __syncthreads();
    if (tid < 64) atomicAdd(&av[row0 + tid], asum[tid]);
}

// ---------------- host launch ----------------

extern "C" void kernel_launch(void* const* d_in, const int* in_sizes, int n_in,
                              void* d_out, int out_size, void* d_ws, size_t ws_size,
                              hipStream_t stream) {
    (void)in_sizes; (void)n_in; (void)out_size; (void)ws_size;
    const float* x   = (const float*)d_in[0];
    const float* eps = (const float*)d_in[1];
    const float* W1  = (const float*)d_in[2];
    const float* B1  = (const float*)d_in[3];
    const float* W2  = (const float*)d_in[4];
    const float* B2  = (const float*)d_in[5];
    const float* W3  = (const float*)d_in[6];
    const float* B3  = (const float*)d_in[7];
    const float* W4  = (const float*)d_in[8];
    const float* B4  = (const float*)d_in[9];
    float* out = (float*)d_out;

    const int H = 2048, DIN = 784, DOUT = 10;
    const int NP1 = 896;           // DIN padded to x128
    const int MP4 = 32;            // layer-4 row pad (20 real rows)

    float* ws = (float*)d_ws;
    size_t off = 0;
    auto alloc = [&](size_t nf) -> float* {
        float* p = ws + off;
        off += (nf + 3) & ~(size_t)3;
        return p;
    };
    float* ubn = alloc(NP1);
    float* lbn = alloc(NP1);
    float* us1 = alloc(H); float* ui1 = alloc(H); float* ls1 = alloc(H); float* li1 = alloc(H);
    float* pU1 = alloc(H); float* pL1 = alloc(H);
    float* iU2 = alloc(H); float* iL2 = alloc(H);
    float* us2 = alloc(H); float* ui2 = alloc(H); float* ls2 = alloc(H); float* li2 = alloc(H);
    float* pU2 = alloc(H); float* pL2 = alloc(H);
    float* iU3 = alloc(H); float* iL3 = alloc(H);
    float* us3 = alloc(H); float* ui3 = alloc(H); float* ls3 = alloc(H); float* li3 = alloc(H);
    float* pU3 = alloc(H); float* pL3 = alloc(H);
    float* iU4 = alloc(32); float* iL4 = alloc(32);
    float* av  = alloc(2 * H);
    bf16_t* Ab  = (bf16_t*)alloc((size_t)2 * H * H / 2);       // 4096 x 2048 bf16 swz
    bf16_t* Ab2 = (bf16_t*)alloc((size_t)2 * H * H / 2);       // L4 scratch operand
    bf16_t* W1t = (bf16_t*)alloc((size_t)NP1 * H / 2);
    bf16_t* W2t = (bf16_t*)alloc((size_t)H * H / 2);
    bf16_t* W3t = (bf16_t*)alloc((size_t)H * H / 2);
    bf16_t* Cs  = (bf16_t*)alloc((size_t)16 * MP4 * H / 2);    // L4 split-16 slabs (bf16)

    dim3 blk(256);

    // weight transpose/convert/swizzle (merged) + input bounds side-block
    k_wT3<<<dim3(32, 32, 3), blk, 0, stream>>>(W1, W2, W3, W1t, W2t, W3t,
                                               x, eps, ubn, lbn);

    size_t ss4H = (size_t)MP4 * H;          // layer-4 N=H slab (32 x 2048)
    size_t ss4N = (size_t)MP4 * NP1;        // layer-4 N=NP1 slab (32 x 896)

    // ======== Layer 1 (fused interval + spu) ========
    k_interval_spu<<<dim3(H / 4), blk, 0, stream>>>(W1, B1, ubn, lbn, DIN, H,
        us1, ui1, ls1, li1, pU1, pL1);

    // ======== Layer 2 ========
    k_prep16<<<dim3(2 * H / 16), blk, 0, stream>>>(W2, B2, H,
        us1, ui1, ls1, li1, B1, pU1, pL1, Ab, av, iU2, iL2);
    k_gemm16_red<<<dim3(896), blk, 0, stream>>>(Ab, W1t, H,
        ubn, lbn, av, KTILES / 2);
    k_spu2<<<dim3(H / 64), dim3(64), 0, stream>>>(iU2, iL2, av, H,
        us2, ui2, ls2, li2, pU2, pL2);

    // ======== Layer 3 (mix + input-layer red fused; Ab2 eliminated) ========
    k_prep16<<<dim3(2 * H / 16), blk, 0, stream>>>(W3, B3, H,
        us2, ui2, ls2, li2, B2, pU2, pL2, Ab, av, iU3, iL3);
    k_gemm16_mixred<<<dim3(2 * H / 128, H / 128), dim3(512), 0, stream>>>(Ab, W2t, H,
        us1, ui1, ls1, li1, B1, W1t, ubn, lbn, av, KTILES / 2);
    k_spu2<<<dim3(H / 64), dim3(64), 0, stream>>>(iU3, iL3, av, H,
        us3, ui3, ls3, li3, pU3, pL3);

    // ======== Layer 4 (M = 20 padded to 32, split-K 16, colmix k-split 16) ========
    k_prep16<<<dim3(MP4 / 16), blk, 0, stream>>>(W4, B4, DOUT,
        us3, ui3, ls3, li3, B3, pU3, pL3, Ab, av, iU4, iL4);
    k_gemm16s<<<dim3(H / 128, 1, 16), blk, 0, stream>>>(Ab, W3t, Cs, H, ss4H, 2);
    k_colmix16<<<dim3(MP4 / 16, 16), blk, 0, stream>>>(Cs, H, 16, ss4H, DOUT, KTILES / 16,
        us2, ui2, ls2, li2, B2, Ab2, av);
    k_gemm16s<<<dim3(H / 128, 1, 16), blk, 0, stream>>>(Ab2, W2t, Cs, H, ss4H, 2);
    k_colmix16<<<dim3(MP4 / 16, 16), blk, 0, stream>>>(Cs, H, 16, ss4H, DOUT, KTILES / 16,
        us1, ui1, ls1, li1, B1, Ab, av);
    k_gemm16s<<<dim3(NP1 / 128, 1, 16), blk, 0, stream>>>(Ab, W1t, Cs, NP1, ss4N, 2);
    k_reduce16f<<<dim3(1), dim3(640), 0, stream>>>(Cs, NP1, DIN, DOUT, 16, ss4N,
        av, ubn, lbn, iL4, out);
}